// Round 2
// baseline (917.707 us; speedup 1.0000x reference)
//
#include <hip/hip_runtime.h>

#define Nn 50000
#define En 800000
#define NSLOT 64
#define MGRID 384

typedef __attribute__((ext_vector_type(8))) short short8;
typedef __attribute__((ext_vector_type(4))) float f32x4;

union U8 { uint4 u4; unsigned short us[8]; unsigned int ui[4]; short8 s8; };

static __device__ __forceinline__ float bf2f(unsigned int lo16) {
  return __uint_as_float(lo16 << 16);
}
static __device__ __forceinline__ unsigned short f2bf(float f) {
  unsigned int x = __float_as_uint(f);
  return (unsigned short)((x + 0x7FFFu + ((x >> 16) & 1u)) >> 16);
}
// packed RNE f32x2 -> bf16x2 (lo = a, hi = b) via hardware cvt (gfx950)
static __device__ __forceinline__ unsigned int f2bf2(float a, float b) {
  unsigned int r;
  asm("v_cvt_pk_bf16_f32 %0, %1, %2" : "=v"(r) : "v"(a), "v"(b));
  return r;
}

// ---------------- prep kernels ----------------

__global__ __launch_bounds__(256) void k_prep_h(const float* __restrict__ h,
                                                unsigned short* __restrict__ nodeA) {
  int idx = blockIdx.x * 256 + threadIdx.x;
  if (idx >= Nn * 128) return;
  int n = idx >> 7, k = idx & 127;
  nodeA[(size_t)n * 256 + k] = f2bf(h[idx]);
}

// weight fp32 [128][Ksrc] cols [koff, koff+2^kshift) -> bf16 [128][2^kshift]
__global__ __launch_bounds__(256) void k_prep_w(const float* __restrict__ src,
                                                unsigned short* __restrict__ dst, int Ksrc,
                                                int koff, int kshift, int total) {
  int idx = blockIdx.x * 256 + threadIdx.x;
  if (idx >= total) return;
  int n = idx >> kshift;
  int k = idx & ((1 << kshift) - 1);
  dst[idx] = f2bf(src[n * Ksrc + koff + k]);
}

__global__ void k_wlast(const float* __restrict__ e_w1, float* __restrict__ wlast) {
  int t = threadIdx.x;
  if (t < 128) wlast[t] = e_w1[t * 257 + 256];
}

// ---------------- CSR build (edges sorted by row; node ids fit u16) ----------------

__global__ __launch_bounds__(256) void k_count(const int* __restrict__ row, int* __restrict__ cnt) {
  int e = blockIdx.x * 256 + threadIdx.x;
  atomicAdd(&cnt[row[e]], 1);
}

__global__ __launch_bounds__(256) void k_fill(const int* __restrict__ row,
                                              const int* __restrict__ col,
                                              int* __restrict__ cursor,
                                              unsigned short* __restrict__ rowS,
                                              unsigned short* __restrict__ colS) {
  int e = blockIdx.x * 256 + threadIdx.x;
  int r = row[e];
  int pos = atomicAdd(&cursor[r], 1);
  rowS[pos] = (unsigned short)r;
  colS[pos] = (unsigned short)col[e];
}

__global__ __launch_bounds__(1024) void k_scan(const int* __restrict__ cnt, int* __restrict__ start,
                                               int* __restrict__ cursor, int n) {
  __shared__ int wsum[16];
  __shared__ int carry;
  int tid = threadIdx.x, lane = tid & 63, wid = tid >> 6;
  if (tid == 0) carry = 0;
  __syncthreads();
  for (int base = 0; base < n; base += 1024) {
    int i = base + tid;
    int v = (i < n) ? cnt[i] : 0;
    int x = v;
#pragma unroll
    for (int d = 1; d < 64; d <<= 1) {
      int y = __shfl_up(x, d, 64);
      if (lane >= d) x += y;
    }
    if (lane == 63) wsum[wid] = x;
    __syncthreads();
    if (wid == 0) {
      int s = (lane < 16) ? wsum[lane] : 0;
#pragma unroll
      for (int d = 1; d < 16; d <<= 1) {
        int y = __shfl_up(s, d, 64);
        if (lane >= d) s += y;
      }
      if (lane < 16) wsum[lane] = s;
    }
    __syncthreads();
    int c0 = carry;
    int waveoff = (wid > 0) ? wsum[wid - 1] : 0;
    int incl = c0 + waveoff + x;
    if (i < n) {
      start[i] = incl - v;
      cursor[i] = incl - v;
    }
    __syncthreads();
    if (tid == 1023) carry = incl;
    __syncthreads();
  }
}

// ---------------- BN finalize ----------------

__global__ void k_fin(const float* __restrict__ statS, const float* __restrict__ statQ,
                      const float* __restrict__ g, const float* __restrict__ be, float invR,
                      float* __restrict__ bnS, float* __restrict__ bnSh) {
  int c = threadIdx.x;
  if (c >= 128) return;
  float s = 0.f, q = 0.f;
  for (int k = 0; k < NSLOT; ++k) {
    s += statS[k * 128 + c];
    q += statQ[k * 128 + c];
  }
  float mean = s * invR;
  float var = fmaxf(q * invR - mean * mean, 0.f);
  float rs = rsqrtf(var + 1e-5f);
  float sc = g[c] * rs;
  bnS[c] = sc;
  bnSh[c] = be[c] - mean * sc;
}

// ---------------- generic MFMA GEMM with W in LDS ----------------
template <int KSTEPS, bool BN_A, bool STATS, bool FP32OUT, bool STORE>
__global__ __launch_bounds__(256) void k_gemmW(
    const unsigned short* __restrict__ A, int Astride,
    const unsigned short* __restrict__ W, const float* __restrict__ bias,
    const float* __restrict__ bnS, const float* __restrict__ bnSh,
    unsigned short* __restrict__ outb, float* __restrict__ statS, float* __restrict__ statQ,
    const float* __restrict__ hres, float* __restrict__ outf, int R) {
  constexpr int K = KSTEPS * 32;
  constexpr int WST = K + 8;
  constexpr int SEGS = K / 8;
  __shared__ __align__(16) unsigned short smem[128 * WST];
  __shared__ float ssum[4][128], ssq[4][128];
  int tid = threadIdx.x;
  int w = tid >> 6, lane = tid & 63, m = lane & 15, kq = lane >> 4;
  int rbase = blockIdx.x * 128;
#pragma unroll
  for (int it = 0; it < SEGS / 2; ++it) {
    int idx = it * 256 + tid;
    int n = idx / SEGS, seg = idx % SEGS;
    uint4 v = *(const uint4*)(W + (size_t)n * K + seg * 8);
    *(uint4*)(smem + n * WST + seg * 8) = v;
  }
  __syncthreads();
  int row0 = rbase + w * 32 + m;
  int rc0 = min(row0, R - 1);
  int rc1 = min(row0 + 16, R - 1);
  f32x4 acc[2][8];
#pragma unroll
  for (int rt = 0; rt < 2; ++rt)
#pragma unroll
    for (int c = 0; c < 8; ++c) acc[rt][c] = (f32x4){0.f, 0.f, 0.f, 0.f};
#pragma unroll
  for (int ks = 0; ks < KSTEPS; ++ks) {
    int k0 = ks * 32 + kq * 8;
    U8 ua0, ua1;
    ua0.u4 = *(const uint4*)(A + (size_t)rc0 * Astride + k0);
    ua1.u4 = *(const uint4*)(A + (size_t)rc1 * Astride + k0);
    if (BN_A) {
      const float4* sp = (const float4*)(bnS + k0);
      const float4* hp = (const float4*)(bnSh + k0);
      float4 s0 = sp[0], s1 = sp[1], h0 = hp[0], h1 = hp[1];
      float sv[8] = {s0.x, s0.y, s0.z, s0.w, s1.x, s1.y, s1.z, s1.w};
      float hv[8] = {h0.x, h0.y, h0.z, h0.w, h1.x, h1.y, h1.z, h1.w};
      U8 pa, pb;
#pragma unroll
      for (int jj = 0; jj < 4; ++jj) {
        float a0 = fmaxf(bf2f(ua0.us[2 * jj]) * sv[2 * jj] + hv[2 * jj], 0.f);
        float a1 = fmaxf(bf2f(ua0.us[2 * jj + 1]) * sv[2 * jj + 1] + hv[2 * jj + 1], 0.f);
        float b0 = fmaxf(bf2f(ua1.us[2 * jj]) * sv[2 * jj] + hv[2 * jj], 0.f);
        float b1 = fmaxf(bf2f(ua1.us[2 * jj + 1]) * sv[2 * jj + 1] + hv[2 * jj + 1], 0.f);
        pa.ui[jj] = f2bf2(a0, a1);
        pb.ui[jj] = f2bf2(b0, b1);
      }
      ua0 = pa;
      ua1 = pb;
    }
#pragma unroll
    for (int c = 0; c < 8; ++c) {
      U8 ub;
      ub.u4 = *(const uint4*)(smem + (c * 16 + m) * WST + k0);
      acc[0][c] = __builtin_amdgcn_mfma_f32_16x16x32_bf16(ua0.s8, ub.s8, acc[0][c], 0, 0, 0);
      acc[1][c] = __builtin_amdgcn_mfma_f32_16x16x32_bf16(ua1.s8, ub.s8, acc[1][c], 0, 0, 0);
    }
  }
  if constexpr (FP32OUT) {
#pragma unroll
    for (int rt = 0; rt < 2; ++rt)
#pragma unroll
      for (int c = 0; c < 8; ++c) {
        int n = c * 16 + m;
        float bn_ = bias[n];
#pragma unroll
        for (int j = 0; j < 4; ++j) {
          int rr = rbase + w * 32 + rt * 16 + kq * 4 + j;
          if (rr < R) {
            size_t o = (size_t)rr * 128 + n;
            outf[o] = acc[rt][c][j] + bn_ + hres[o];
          }
        }
      }
  } else {
    if constexpr (STORE) __syncthreads();
    unsigned short* tile = smem;  // reuse as [128][136]
#pragma unroll
    for (int c = 0; c < 8; ++c) {
      int n = c * 16 + m;
      float bn_ = bias ? bias[n] : 0.f;
      float s = 0.f, q = 0.f;
#pragma unroll
      for (int rt = 0; rt < 2; ++rt)
#pragma unroll
        for (int j = 0; j < 4; ++j) {
          int lr = w * 32 + rt * 16 + kq * 4 + j;
          float v = acc[rt][c][j] + bn_;
          if (STORE) tile[lr * 136 + n] = f2bf(v);
          if (STATS) {
            float sv = (rbase + lr < R) ? v : 0.f;
            s += sv;
            q = fmaf(sv, sv, q);
          }
        }
      if (STATS) {
        s += __shfl_xor(s, 16, 64); s += __shfl_xor(s, 32, 64);
        q += __shfl_xor(q, 16, 64); q += __shfl_xor(q, 32, 64);
        if (kq == 0) { ssum[w][n] = s; ssq[w][n] = q; }
      }
    }
    if constexpr (STORE) {
      __syncthreads();
      const uint4* tl = (const uint4*)tile;
#pragma unroll
      for (int u = 0; u < 8; ++u) {
        int idx = u * 256 + tid;
        int rr = idx >> 4, seg = idx & 15;
        if (rbase + rr < R)
          *(uint4*)(outb + (size_t)(rbase + rr) * 128 + seg * 8) = tl[rr * 17 + seg];
      }
    }
    if (STATS) {
      __syncthreads();
      if (tid < 128) {
        float s = ssum[0][tid] + ssum[1][tid] + ssum[2][tid] + ssum[3][tid];
        float q = ssq[0][tid] + ssq[1][tid] + ssq[2][tid] + ssq[3][tid];
        int slot = blockIdx.x & (NSLOT - 1);
        atomicAdd(&statS[slot * 128 + tid], s);
        atomicAdd(&statQ[slot * 128 + tid], q);
      }
    }
  }
}

// ---------------- bn1 stats over virtual t1 (no materialization) + radS ----------------
// per_wave is even and En is even -> every wave's range has even length
__global__ __launch_bounds__(256) void k_stats1(
    const unsigned short* __restrict__ hWr, const unsigned short* __restrict__ hWc,
    const float* __restrict__ coord, const unsigned short* __restrict__ rowS,
    const unsigned short* __restrict__ colS, const float* __restrict__ wlast,
    float* __restrict__ radS, float* __restrict__ statS, float* __restrict__ statQ,
    int per_wave) {
  int tid = threadIdx.x, lane = tid & 63;
  int wid = blockIdx.x * 4 + (tid >> 6);
  int e0 = wid * per_wave;
  int e1 = min(e0 + per_wave, En);
  int c2 = lane * 2;
  float wl0 = wlast[c2], wl1 = wlast[c2 + 1];
  float s0 = 0.f, s1 = 0.f, q0 = 0.f, q1 = 0.f;
  for (int e = e0; e < e1; e += 2) {
    int ra = rowS[e], ca = colS[e];
    int rb = rowS[e + 1], cb = colS[e + 1];
    float ax = coord[ra * 3 + 0] - coord[ca * 3 + 0];
    float ay = coord[ra * 3 + 1] - coord[ca * 3 + 1];
    float az = coord[ra * 3 + 2] - coord[ca * 3 + 2];
    float bx = coord[rb * 3 + 0] - coord[cb * 3 + 0];
    float by = coord[rb * 3 + 1] - coord[cb * 3 + 1];
    float bz = coord[rb * 3 + 2] - coord[cb * 3 + 2];
    float rada = ax * ax + ay * ay + az * az;
    float radb = bx * bx + by * by + bz * bz;
    if (lane == 0) {
      radS[e] = rada;
      radS[e + 1] = radb;
    }
    unsigned int uar = *(const unsigned int*)(hWr + (size_t)ra * 128 + c2);
    unsigned int uac = *(const unsigned int*)(hWc + (size_t)ca * 128 + c2);
    unsigned int ubr = *(const unsigned int*)(hWr + (size_t)rb * 128 + c2);
    unsigned int ubc = *(const unsigned int*)(hWc + (size_t)cb * 128 + c2);
    float va0 = bf2f(uar & 0xFFFFu) + bf2f(uac & 0xFFFFu) + rada * wl0;
    float va1 = bf2f(uar >> 16) + bf2f(uac >> 16) + rada * wl1;
    float vb0 = bf2f(ubr & 0xFFFFu) + bf2f(ubc & 0xFFFFu) + radb * wl0;
    float vb1 = bf2f(ubr >> 16) + bf2f(ubc >> 16) + radb * wl1;
    s0 += va0 + vb0;
    s1 += va1 + vb1;
    q0 = fmaf(va0, va0, q0); q0 = fmaf(vb0, vb0, q0);
    q1 = fmaf(va1, va1, q1); q1 = fmaf(vb1, vb1, q1);
  }
  int slot = wid & (NSLOT - 1);
  atomicAdd(&statS[slot * 128 + c2], s0);
  atomicAdd(&statS[slot * 128 + c2 + 1], s1);
  atomicAdd(&statQ[slot * 128 + c2], q0);
  atomicAdd(&statQ[slot * 128 + c2 + 1], q1);
}

// ---------------- edge layer 2 GEMM, A recomputed from hWr/hWc/radS ----------------
__global__ __launch_bounds__(256) void k_egemm2(
    const unsigned short* __restrict__ hWr, const unsigned short* __restrict__ hWc,
    const float* __restrict__ radS, const unsigned short* __restrict__ rowS,
    const unsigned short* __restrict__ colS, const unsigned short* __restrict__ W,
    const float* __restrict__ bias, const float* __restrict__ wlast,
    const float* __restrict__ bnS1, const float* __restrict__ bnSh1,
    unsigned short* __restrict__ outb, float* __restrict__ statS, float* __restrict__ statQ) {
  constexpr int WST = 136;
  __shared__ __align__(16) unsigned short smem[128 * WST];
  __shared__ float ssum[4][128], ssq[4][128];
  int tid = threadIdx.x;
  int w = tid >> 6, lane = tid & 63, m = lane & 15, kq = lane >> 4;
  int rbase = blockIdx.x * 128;
#pragma unroll
  for (int it = 0; it < 8; ++it) {
    int idx = it * 256 + tid;
    int n = idx >> 4, seg = idx & 15;
    uint4 v = *(const uint4*)(W + (size_t)n * 128 + seg * 8);
    *(uint4*)(smem + n * WST + seg * 8) = v;
  }
  int rc0 = rbase + w * 32 + m, rc1 = rc0 + 16;
  int r0 = rowS[rc0], c0 = colS[rc0];
  int r1 = rowS[rc1], c1 = colS[rc1];
  float rad0 = radS[rc0], rad1 = radS[rc1];
  __syncthreads();
  f32x4 acc[2][8];
#pragma unroll
  for (int rt = 0; rt < 2; ++rt)
#pragma unroll
    for (int c = 0; c < 8; ++c) acc[rt][c] = (f32x4){0.f, 0.f, 0.f, 0.f};
#pragma unroll
  for (int ks = 0; ks < 4; ++ks) {
    int k0 = ks * 32 + kq * 8;
    U8 a0r, a0c, a1r, a1c;
    a0r.u4 = *(const uint4*)(hWr + (size_t)r0 * 128 + k0);
    a0c.u4 = *(const uint4*)(hWc + (size_t)c0 * 128 + k0);
    a1r.u4 = *(const uint4*)(hWr + (size_t)r1 * 128 + k0);
    a1c.u4 = *(const uint4*)(hWc + (size_t)c1 * 128 + k0);
    const float4* wp = (const float4*)(wlast + k0);
    const float4* sp = (const float4*)(bnS1 + k0);
    const float4* hp = (const float4*)(bnSh1 + k0);
    float4 w0 = wp[0], w1 = wp[1], sA = sp[0], sB = sp[1], hA = hp[0], hB = hp[1];
    float wv[8] = {w0.x, w0.y, w0.z, w0.w, w1.x, w1.y, w1.z, w1.w};
    float sv[8] = {sA.x, sA.y, sA.z, sA.w, sB.x, sB.y, sB.z, sB.w};
    float hv[8] = {hA.x, hA.y, hA.z, hA.w, hB.x, hB.y, hB.z, hB.w};
    U8 ua0, ua1;
#pragma unroll
    for (int jj = 0; jj < 4; ++jj) {
      int j0 = 2 * jj, j1 = 2 * jj + 1;
      float v0a = bf2f(a0r.us[j0]) + bf2f(a0c.us[j0]) + rad0 * wv[j0];
      float v0b = bf2f(a0r.us[j1]) + bf2f(a0c.us[j1]) + rad0 * wv[j1];
      float v1a = bf2f(a1r.us[j0]) + bf2f(a1c.us[j0]) + rad1 * wv[j0];
      float v1b = bf2f(a1r.us[j1]) + bf2f(a1c.us[j1]) + rad1 * wv[j1];
      v0a = fmaxf(v0a * sv[j0] + hv[j0], 0.f);
      v0b = fmaxf(v0b * sv[j1] + hv[j1], 0.f);
      v1a = fmaxf(v1a * sv[j0] + hv[j0], 0.f);
      v1b = fmaxf(v1b * sv[j1] + hv[j1], 0.f);
      ua0.ui[jj] = f2bf2(v0a, v0b);
      ua1.ui[jj] = f2bf2(v1a, v1b);
    }
#pragma unroll
    for (int c = 0; c < 8; ++c) {
      U8 ub;
      ub.u4 = *(const uint4*)(smem + (c * 16 + m) * WST + k0);
      acc[0][c] = __builtin_amdgcn_mfma_f32_16x16x32_bf16(ua0.s8, ub.s8, acc[0][c], 0, 0, 0);
      acc[1][c] = __builtin_amdgcn_mfma_f32_16x16x32_bf16(ua1.s8, ub.s8, acc[1][c], 0, 0, 0);
    }
  }
  __syncthreads();
  unsigned short* tile = smem;
#pragma unroll
  for (int c = 0; c < 8; ++c) {
    int n = c * 16 + m;
    float bn_ = bias[n];
    float s = 0.f, q = 0.f;
#pragma unroll
    for (int rt = 0; rt < 2; ++rt)
#pragma unroll
      for (int j = 0; j < 4; ++j) {
        int lr = w * 32 + rt * 16 + kq * 4 + j;
        float v = acc[rt][c][j] + bn_;
        tile[lr * 136 + n] = f2bf(v);
        s += v;
        q = fmaf(v, v, q);
      }
    s += __shfl_xor(s, 16, 64); s += __shfl_xor(s, 32, 64);
    q += __shfl_xor(q, 16, 64); q += __shfl_xor(q, 32, 64);
    if (kq == 0) { ssum[w][n] = s; ssq[w][n] = q; }
  }
  __syncthreads();
  const uint4* tl = (const uint4*)tile;
#pragma unroll
  for (int u = 0; u < 8; ++u) {
    int idx = u * 256 + tid;
    int rr = idx >> 4, seg = idx & 15;
    *(uint4*)(outb + (size_t)(rbase + rr) * 128 + seg * 8) = tl[rr * 17 + seg];
  }
  if (tid < 128) {
    float s = ssum[0][tid] + ssum[1][tid] + ssum[2][tid] + ssum[3][tid];
    float q = ssq[0][tid] + ssq[1][tid] + ssq[2][tid] + ssq[3][tid];
    int slot = blockIdx.x & (NSLOT - 1);
    atomicAdd(&statS[slot * 128 + tid], s);
    atomicAdd(&statQ[slot * 128 + tid], q);
  }
}

// ---------------- node aggregation over contiguous CSR rows (no atomics) ----------------
__global__ __launch_bounds__(256) void k_agg(const unsigned short* __restrict__ t,
                                             const int* __restrict__ start,
                                             const int* __restrict__ cnt,
                                             const float* __restrict__ bnS,
                                             const float* __restrict__ bnSh,
                                             unsigned short* __restrict__ nodeA) {
  int tid = threadIdx.x;
  int lane = tid & 63;
  int n = blockIdx.x * 4 + (tid >> 6);
  if (n >= Nn) return;
  int deg = cnt[n], off = start[n];
  int c2 = lane * 2;
  float s0 = bnS[c2], s1 = bnS[c2 + 1], h0 = bnSh[c2], h1 = bnSh[c2 + 1];
  float a0 = 0.f, a1 = 0.f;
  const unsigned short* p = t + (size_t)off * 128 + c2;
  for (int j = 0; j < deg; ++j) {
    unsigned int u = *(const unsigned int*)(p + (size_t)j * 128);
    a0 += fmaxf(bf2f(u & 0xFFFFu) * s0 + h0, 0.f);
    a1 += fmaxf(bf2f(u >> 16) * s1 + h1, 0.f);
  }
  float inv = 1.f / fmaxf((float)deg, 1.f);
  unsigned int o = (unsigned)f2bf(a0 * inv) | ((unsigned)f2bf(a1 * inv) << 16);
  *(unsigned int*)(nodeA + (size_t)n * 256 + 128 + c2) = o;
}

// ---------------- second-moment of y = relu(bn2(t2)): Mpart[b] = sum y y^T ----------------
// Also accumulates Sy[c] = sum_e y[e][c] (for E[t3] without materializing t3).
// yT tile in LDS is channel-major: yT[c][e] so both MFMA operands read 16B runs.
__global__ __launch_bounds__(256) void k_moment(
    const unsigned short* __restrict__ t,
    const float* __restrict__ bnS2, const float* __restrict__ bnSh2,
    float* __restrict__ Mpart, float* __restrict__ SyG) {
  constexpr int WST = 136;
  __shared__ __align__(16) unsigned short yT[128 * WST];
  __shared__ float s2L[128], h2L[128];
  int tid = threadIdx.x;
  int w = tid >> 6, lane = tid & 63, m = lane & 15, kq = lane >> 4;
  if (tid < 128) { s2L[tid] = bnS2[tid]; h2L[tid] = bnSh2[tid]; }
  f32x4 acc[2][8];
#pragma unroll
  for (int rt = 0; rt < 2; ++rt)
#pragma unroll
    for (int c = 0; c < 8; ++c) acc[rt][c] = (f32x4){0.f, 0.f, 0.f, 0.f};
  float sy[32];
#pragma unroll
  for (int i = 0; i < 32; ++i) sy[i] = 0.f;
  for (int tile = blockIdx.x; tile < En / 128; tile += MGRID) {
    __syncthreads();  // also covers s2L init on first pass; protects yT reuse after
    int e0 = tile * 128 + lane * 2;
    U8 ra[4], rb[4];
#pragma unroll
    for (int q = 0; q < 4; ++q) {
      ra[q].u4 = *(const uint4*)(t + (size_t)e0 * 128 + w * 32 + q * 8);
      rb[q].u4 = *(const uint4*)(t + (size_t)(e0 + 1) * 128 + w * 32 + q * 8);
    }
#pragma unroll
    for (int q = 0; q < 4; ++q)
#pragma unroll
      for (int i = 0; i < 8; ++i) {
        int c = w * 32 + q * 8 + i;
        float s = s2L[c], h = h2L[c];
        float ya = fmaxf(bf2f(ra[q].us[i]) * s + h, 0.f);
        float yb = fmaxf(bf2f(rb[q].us[i]) * s + h, 0.f);
        sy[q * 8 + i] += ya + yb;
        // uniform channel per instruction -> conflict-free u32 LDS writes
        *(unsigned int*)(yT + c * WST + lane * 2) = f2bf2(ya, yb);
      }
    __syncthreads();
#pragma unroll
    for (int ks = 0; ks < 4; ++ks) {
      int k0 = ks * 32 + kq * 8;
      U8 a0, a1;
      a0.u4 = *(const uint4*)(yT + (w * 32 + m) * WST + k0);
      a1.u4 = *(const uint4*)(yT + (w * 32 + 16 + m) * WST + k0);
#pragma unroll
      for (int c = 0; c < 8; ++c) {
        U8 ub;
        ub.u4 = *(const uint4*)(yT + (c * 16 + m) * WST + k0);
        acc[0][c] = __builtin_amdgcn_mfma_f32_16x16x32_bf16(a0.s8, ub.s8, acc[0][c], 0, 0, 0);
        acc[1][c] = __builtin_amdgcn_mfma_f32_16x16x32_bf16(a1.s8, ub.s8, acc[1][c], 0, 0, 0);
      }
    }
  }
  size_t mb = (size_t)blockIdx.x * 16384;
#pragma unroll
  for (int rt = 0; rt < 2; ++rt)
#pragma unroll
    for (int c = 0; c < 8; ++c)
#pragma unroll
      for (int j = 0; j < 4; ++j)
        Mpart[mb + (size_t)(w * 32 + rt * 16 + kq * 4 + j) * 128 + c * 16 + m] = acc[rt][c][j];
#pragma unroll
  for (int i = 0; i < 32; ++i) {
    float s = sy[i];
#pragma unroll
    for (int d = 1; d < 64; d <<= 1) s += __shfl_xor(s, d, 64);
    if (lane == 0) atomicAdd(&SyG[w * 32 + i], s);
  }
}

__global__ __launch_bounds__(256) void k_msum(const float* __restrict__ Mpart,
                                              float* __restrict__ Mg) {
  __shared__ float red[4][64];
  int tid = threadIdx.x;
  int e = blockIdx.x * 64 + (tid & 63);
  int pq = tid >> 6;
  float s = 0.f;
  for (int k = pq * (MGRID / 4); k < (pq + 1) * (MGRID / 4); ++k)
    s += Mpart[(size_t)k * 16384 + e];
  red[pq][tid & 63] = s;
  __syncthreads();
  if (tid < 64) Mg[e] = red[0][tid] + red[1][tid] + red[2][tid] + red[3][tid];
}

// bn3 params from moments: var[c] = (w_c M w_c^T)/E - (w_c . Sy / E)^2  (bias cancels)
// block = channel c; 128 threads each own column j of M.
__global__ __launch_bounds__(128) void k_fin3(
    const float* __restrict__ Mg, const float* __restrict__ Sy,
    const float* __restrict__ w1, const float* __restrict__ g,
    const float* __restrict__ be, float invE,
    float* __restrict__ bnS3, float* __restrict__ bnSh3) {
  __shared__ float sW[128];
  __shared__ float r2[4];
  int c = blockIdx.x, j = threadIdx.x;
  sW[j] = w1[c * 128 + j];
  __syncthreads();
  float a0 = 0.f, a1 = 0.f, a2 = 0.f, a3 = 0.f;
  for (int i = 0; i < 128; i += 4) {
    a0 = fmaf(sW[i], Mg[i * 128 + j], a0);
    a1 = fmaf(sW[i + 1], Mg[(i + 1) * 128 + j], a1);
    a2 = fmaf(sW[i + 2], Mg[(i + 2) * 128 + j], a2);
    a3 = fmaf(sW[i + 3], Mg[(i + 3) * 128 + j], a3);
  }
  float q = sW[j] * ((a0 + a1) + (a2 + a3));
  float dm = sW[j] * Sy[j];
#pragma unroll
  for (int d = 1; d < 64; d <<= 1) {
    q += __shfl_xor(q, d, 64);
    dm += __shfl_xor(dm, d, 64);
  }
  int wv = j >> 6;
  if ((j & 63) == 0) { r2[wv * 2] = q; r2[wv * 2 + 1] = dm; }
  __syncthreads();
  if (j == 0) {
    float quad = r2[0] + r2[2];
    float dmt = r2[1] + r2[3];
    float Eu = dmt * invE;
    float var = fmaxf(quad * invE - Eu * Eu, 0.f);
    float S = g[c] * rsqrtf(var + 1e-5f);
    bnS3[c] = S;
    bnSh3[c] = be[c] - Eu * S;  // GEMM bias c_b1 cancels inside BN
  }
}

// ---------------- coord GEMM with fused bn3+relu+dot(c_w2) epilogue -> scaleE ----------------
__global__ __launch_bounds__(256) void k_cgemm(
    const unsigned short* __restrict__ A,   // t2 [En][128] bf16
    const unsigned short* __restrict__ W,   // c1b bf16 [128][128]
    const float* __restrict__ bnS2, const float* __restrict__ bnSh2,
    const float* __restrict__ bnS3, const float* __restrict__ bnSh3,
    const float* __restrict__ cw2, float* __restrict__ scaleE) {
  constexpr int WST = 136;
  __shared__ __align__(16) unsigned short smem[128 * WST];
  int tid = threadIdx.x;
  int w = tid >> 6, lane = tid & 63, m = lane & 15, kq = lane >> 4;
  int rbase = blockIdx.x * 128;
#pragma unroll
  for (int it = 0; it < 8; ++it) {
    int idx = it * 256 + tid;
    int n = idx >> 4, seg = idx & 15;
    *(uint4*)(smem + n * WST + seg * 8) = *(const uint4*)(W + (size_t)n * 128 + seg * 8);
  }
  __syncthreads();
  int rc0 = rbase + w * 32 + m, rc1 = rc0 + 16;
  f32x4 acc[2][8];
#pragma unroll
  for (int rt = 0; rt < 2; ++rt)
#pragma unroll
    for (int c = 0; c < 8; ++c) acc[rt][c] = (f32x4){0.f, 0.f, 0.f, 0.f};
#pragma unroll
  for (int ks = 0; ks < 4; ++ks) {
    int k0 = ks * 32 + kq * 8;
    U8 ua0, ua1;
    ua0.u4 = *(const uint4*)(A + (size_t)rc0 * 128 + k0);
    ua1.u4 = *(const uint4*)(A + (size_t)rc1 * 128 + k0);
    const float4* sp = (const float4*)(bnS2 + k0);
    const float4* hp = (const float4*)(bnSh2 + k0);
    float4 s0 = sp[0], s1 = sp[1], h0 = hp[0], h1 = hp[1];
    float sv[8] = {s0.x, s0.y, s0.z, s0.w, s1.x, s1.y, s1.z, s1.w};
    float hv[8] = {h0.x, h0.y, h0.z, h0.w, h1.x, h1.y, h1.z, h1.w};
    U8 pa, pb;
#pragma unroll
    for (int jj = 0; jj < 4; ++jj) {
      float v0a = fmaxf(bf2f(ua0.us[2 * jj]) * sv[2 * jj] + hv[2 * jj], 0.f);
      float v0b = fmaxf(bf2f(ua0.us[2 * jj + 1]) * sv[2 * jj + 1] + hv[2 * jj + 1], 0.f);
      float v1a = fmaxf(bf2f(ua1.us[2 * jj]) * sv[2 * jj] + hv[2 * jj], 0.f);
      float v1b = fmaxf(bf2f(ua1.us[2 * jj + 1]) * sv[2 * jj + 1] + hv[2 * jj + 1], 0.f);
      pa.ui[jj] = f2bf2(v0a, v0b);
      pb.ui[jj] = f2bf2(v1a, v1b);
    }
#pragma unroll
    for (int c = 0; c < 8; ++c) {
      U8 ub;
      ub.u4 = *(const uint4*)(smem + (c * 16 + m) * WST + k0);
      acc[0][c] = __builtin_amdgcn_mfma_f32_16x16x32_bf16(pa.s8, ub.s8, acc[0][c], 0, 0, 0);
      acc[1][c] = __builtin_amdgcn_mfma_f32_16x16x32_bf16(pb.s8, ub.s8, acc[1][c], 0, 0, 0);
    }
  }
  // epilogue: scale[e] = sum_n cw2[n] * relu(acc*S3[n] + Sh3[n])
  float s3v[8], h3v[8], wv[8];
#pragma unroll
  for (int c = 0; c < 8; ++c) {
    int n = c * 16 + m;
    s3v[c] = bnS3[n];
    h3v[c] = bnSh3[n];
    wv[c] = cw2[n];
  }
  float p0[4] = {0.f, 0.f, 0.f, 0.f}, p1[4] = {0.f, 0.f, 0.f, 0.f};
#pragma unroll
  for (int c = 0; c < 8; ++c)
#pragma unroll
    for (int j = 0; j < 4; ++j) {
      p0[j] += fmaxf(acc[0][c][j] * s3v[c] + h3v[c], 0.f) * wv[c];
      p1[j] += fmaxf(acc[1][c][j] * s3v[c] + h3v[c], 0.f) * wv[c];
    }
#pragma unroll
  for (int j = 0; j < 4; ++j)
#pragma unroll
    for (int d = 1; d < 16; d <<= 1) {
      p0[j] += __shfl_xor(p0[j], d, 64);
      p1[j] += __shfl_xor(p1[j], d, 64);
    }
  if (m == 0) {
    int r0 = rbase + w * 32 + kq * 4;
    *(float4*)(scaleE + r0) = make_float4(p0[0], p0[1], p0[2], p0[3]);
    *(float4*)(scaleE + r0 + 16) = make_float4(p1[0], p1[1], p1[2], p1[3]);
  }
}

// coord_out: contiguous CSR ranges, coalesced
__global__ __launch_bounds__(256) void k_coord(const float* __restrict__ coord,
                                               const unsigned short* __restrict__ colS,
                                               const int* __restrict__ start,
                                               const int* __restrict__ cnt,
                                               const float* __restrict__ scaleE,
                                               float* __restrict__ cout) {
  int tid = threadIdx.x;
  int lane = tid & 63;
  int n = blockIdx.x * 4 + (tid >> 6);
  if (n >= Nn) return;
  int deg = cnt[n], off = start[n];
  float cx0 = coord[n * 3 + 0], cy0 = coord[n * 3 + 1], cz0 = coord[n * 3 + 2];
  float ax = 0.f, ay = 0.f, az = 0.f;
  for (int j = lane; j < deg; j += 64) {
    int e = off + j;
    int c = colS[e];
    float s = scaleE[e];
    float tx = (cx0 - coord[c * 3 + 0]) * s;
    float ty = (cy0 - coord[c * 3 + 1]) * s;
    float tz = (cz0 - coord[c * 3 + 2]) * s;
    ax += fminf(fmaxf(tx, -100.f), 100.f);
    ay += fminf(fmaxf(ty, -100.f), 100.f);
    az += fminf(fmaxf(tz, -100.f), 100.f);
  }
#pragma unroll
  for (int d = 32; d; d >>= 1) {
    ax += __shfl_xor(ax, d, 64);
    ay += __shfl_xor(ay, d, 64);
    az += __shfl_xor(az, d, 64);
  }
  if (lane == 0) {
    float inv = 1.f / fmaxf((float)deg, 1.f);
    cout[n * 3 + 0] = cx0 + ax * inv;
    cout[n * 3 + 1] = cy0 + ay * inv;
    cout[n * 3 + 2] = cz0 + az * inv;
  }
}

// ---------------- launcher ----------------

extern "C" void kernel_launch(void* const* d_in, const int* in_sizes, int n_in, void* d_out,
                              int out_size, void* d_ws, size_t ws_size, hipStream_t stream) {
  (void)in_sizes; (void)n_in; (void)out_size; (void)ws_size;
  const float* h = (const float*)d_in[0];
  const float* coord = (const float*)d_in[1];
  const int* eidx = (const int*)d_in[2];
  const int* row = eidx;
  const int* col = eidx + En;
  const float* e_w1 = (const float*)d_in[3];
  const float* e_b1 = (const float*)d_in[4];
  const float* e_g1 = (const float*)d_in[5];
  const float* e_be1 = (const float*)d_in[6];
  const float* e_w2 = (const float*)d_in[7];
  const float* e_b2 = (const float*)d_in[8];
  const float* e_g2 = (const float*)d_in[9];
  const float* e_be2 = (const float*)d_in[10];
  const float* n_w1 = (const float*)d_in[11];
  const float* n_b1 = (const float*)d_in[12];
  const float* n_g1 = (const float*)d_in[13];
  const float* n_be1 = (const float*)d_in[14];
  const float* n_w2 = (const float*)d_in[15];
  const float* n_b2 = (const float*)d_in[16];
  const float* c_w1 = (const float*)d_in[17];
  const float* c_b1 = (const float*)d_in[18];
  (void)c_b1;  // bias before BN cancels analytically (k_fin3)
  const float* c_g1 = (const float*)d_in[19];
  const float* c_be1 = (const float*)d_in[20];
  const float* c_w2 = (const float*)d_in[21];

  char* base = (char*)d_ws;
  size_t off = 0;
  auto alloc = [&](size_t bytes) -> void* {
    void* p = base + off;
    off = (off + bytes + 255) & ~(size_t)255;
    return p;
  };
  // Workspace budget: ~260 MB (round-3 proven footprint, unchanged — moment buffers aliased).
  unsigned short* t = (unsigned short*)alloc((size_t)En * 128 * 2);      // t2, then t4
  unsigned short* nodeA = (unsigned short*)alloc((size_t)Nn * 256 * 2);  // [h | agg] bf16
  unsigned short* hWr = (unsigned short*)alloc((size_t)Nn * 128 * 2);
  unsigned short* hWc = (unsigned short*)alloc((size_t)Nn * 128 * 2);
  float* scaleE = (float*)alloc((size_t)En * 4);
  float* radS = scaleE;  // alias: radS dead (after k_egemm2) before scaleE written (k_cgemm)
  unsigned short* rowS = (unsigned short*)alloc((size_t)En * 2);
  unsigned short* colS = (unsigned short*)alloc((size_t)En * 2);
  int* cnt = (int*)alloc((size_t)Nn * 4);
  int* startp = (int*)alloc((size_t)Nn * 4);
  int* cursor = (int*)alloc((size_t)Nn * 4);
  float* statS = (float*)alloc(4 * NSLOT * 128 * 4);
  float* statQ = (float*)alloc(4 * NSLOT * 128 * 4);
  float* bnS = (float*)alloc(4 * 128 * 4);
  float* bnSh = (float*)alloc(4 * 128 * 4);
  unsigned short* w1a = (unsigned short*)alloc(128 * 128 * 2);
  unsigned short* w1b = (unsigned short*)alloc(128 * 128 * 2);
  unsigned short* w2b = (unsigned short*)alloc(128 * 128 * 2);
  unsigned short* c1b = (unsigned short*)alloc(128 * 128 * 2);
  unsigned short* n1b = (unsigned short*)alloc(128 * 256 * 2);
  unsigned short* n2b = (unsigned short*)alloc(128 * 128 * 2);
  float* wlast = (float*)alloc(128 * 4);
  // Moment buffers ALIASED into dead regions (no new workspace):
  //  - Mpart (MGRID*16384 f32 = 25.2 MB) over hWr+hWc (25.6 MB contiguous, dead after k_egemm2)
  //  - Mg (16384 f32) + SyG (128 f32) at head of scaleE region (radS dead after k_egemm2;
  //    scaleE written only later by k_cgemm, after k_fin3 consumed Mg/SyG)
  float* Mpart = (float*)hWr;
  float* Mg = scaleE;
  float* SyG = scaleE + 16384;

  hipMemsetAsync(cnt, 0, (size_t)Nn * 4, stream);
  hipMemsetAsync(statS, 0, 4 * NSLOT * 128 * 4, stream);
  hipMemsetAsync(statQ, 0, 4 * NSLOT * 128 * 4, stream);

  // prep
  k_prep_h<<<(Nn * 128 + 255) / 256, 256, 0, stream>>>(h, nodeA);
  k_prep_w<<<(128 * 128 + 255) / 256, 256, 0, stream>>>(e_w1, w1a, 257, 0, 7, 128 * 128);
  k_prep_w<<<(128 * 128 + 255) / 256, 256, 0, stream>>>(e_w1, w1b, 257, 128, 7, 128 * 128);
  k_prep_w<<<(128 * 128 + 255) / 256, 256, 0, stream>>>(e_w2, w2b, 128, 0, 7, 128 * 128);
  k_prep_w<<<(128 * 128 + 255) / 256, 256, 0, stream>>>(c_w1, c1b, 128, 0, 7, 128 * 128);
  k_prep_w<<<(128 * 256 + 255) / 256, 256, 0, stream>>>(n_w1, n1b, 256, 0, 8, 128 * 256);
  k_prep_w<<<(128 * 128 + 255) / 256, 256, 0, stream>>>(n_w2, n2b, 128, 0, 7, 128 * 128);
  k_wlast<<<1, 128, 0, stream>>>(e_w1, wlast);

  // CSR sort
  k_count<<<En / 256, 256, 0, stream>>>(row, cnt);
  k_scan<<<1, 1024, 0, stream>>>(cnt, startp, cursor, Nn);
  k_fill<<<En / 256, 256, 0, stream>>>(row, col, cursor, rowS, colS);

  // hW partial GEMMs (bias e_b1 folded into hWr)
  const int gridN = (Nn + 127) / 128;
  k_gemmW<4, false, false, false, true><<<gridN, 256, 0, stream>>>(
      nodeA, 256, w1a, e_b1, nullptr, nullptr, hWr, nullptr, nullptr, nullptr, nullptr, Nn);
  k_gemmW<4, false, false, false, true><<<gridN, 256, 0, stream>>>(
      nodeA, 256, w1b, nullptr, nullptr, nullptr, hWc, nullptr, nullptr, nullptr, nullptr, Nn);

  // bn1 stats over virtual t1 + radS (per_wave even for the 2-edge unroll)
  const int per_wave = ((En / 2 + 5119) / 5120) * 2;  // 1280 blocks * 4 waves
  k_stats1<<<1280, 256, 0, stream>>>(hWr, hWc, coord, rowS, colS, wlast, radS,
                                     statS + 0 * NSLOT * 128, statQ + 0 * NSLOT * 128, per_wave);
  k_fin<<<1, 128, 0, stream>>>(statS + 0 * NSLOT * 128, statQ + 0 * NSLOT * 128, e_g1, e_be1,
                               1.f / En, bnS + 0, bnSh + 0);

  // edge layer 2: t2 + bn2 stats (slot 1) — last use of hWr/hWc/radS
  k_egemm2<<<En / 128, 256, 0, stream>>>(hWr, hWc, radS, rowS, colS, w2b, e_b2, wlast, bnS + 0,
                                         bnSh + 0, t, statS + 1 * NSLOT * 128,
                                         statQ + 1 * NSLOT * 128);
  k_fin<<<1, 128, 0, stream>>>(statS + 1 * NSLOT * 128, statQ + 1 * NSLOT * 128, e_g2, e_be2,
                               1.f / En, bnS + 128, bnSh + 128);

  // node aggregation from contiguous t2 rows (no atomics)
  k_agg<<<(Nn + 3) / 4, 256, 0, stream>>>(t, startp, cnt, bnS + 128, bnSh + 128, nodeA);

  // bn3 stats WITHOUT materializing t3: second moment of y = relu(bn2(t2))
  hipMemsetAsync(SyG, 0, 128 * 4, stream);  // after radS is dead, before k_moment
  k_moment<<<MGRID, 256, 0, stream>>>(t, bnS + 128, bnSh + 128, Mpart, SyG);
  k_msum<<<256, 256, 0, stream>>>(Mpart, Mg);
  k_fin3<<<128, 128, 0, stream>>>(Mg, SyG, c_w1, c_g1, c_be1, 1.f / En, bnS + 256, bnSh + 256);

  // coord GEMM with fused bn3+relu+c_w2 epilogue -> per-edge scale (no t3 store, no scale pass)
  k_cgemm<<<En / 128, 256, 0, stream>>>(t, c1b, bnS + 128, bnSh + 128, bnS + 256, bnSh + 256,
                                        c_w2, scaleE);

  float* hout = (float*)d_out;
  float* cout = hout + (size_t)Nn * 128;
  k_coord<<<(Nn + 3) / 4, 256, 0, stream>>>(coord, colS, startp, cnt, scaleE, cout);

  // node MLP: l1 (stats slot 3) -> t4 in t (t2 dead after k_cgemm); l2 fp32 out
  k_gemmW<8, false, true, false, true><<<gridN, 256, 0, stream>>>(
      nodeA, 256, n1b, n_b1, nullptr, nullptr, t, statS + 3 * NSLOT * 128,
      statQ + 3 * NSLOT * 128, nullptr, nullptr, Nn);
  k_fin<<<1, 128, 0, stream>>>(statS + 3 * NSLOT * 128, statQ + 3 * NSLOT * 128, n_g1, n_be1,
                               1.f / Nn, bnS + 384, bnSh + 384);
  k_gemmW<4, true, false, true, true><<<gridN, 256, 0, stream>>>(
      t, 128, n2b, n_b2, bnS + 384, bnSh + 384, nullptr, nullptr, nullptr, h, hout, Nn);
}

// Round 6
// 915.594 us; speedup vs baseline: 1.0023x; 1.0023x over previous
//
#include <hip/hip_runtime.h>

#define Nn 50000
#define En 800000
#define NSLOT 64
#define MGRID 384

typedef __attribute__((ext_vector_type(8))) short short8;
typedef __attribute__((ext_vector_type(4))) float f32x4;

union U8 { uint4 u4; unsigned short us[8]; unsigned int ui[4]; short8 s8; };

static __device__ __forceinline__ float bf2f(unsigned int lo16) {
  return __uint_as_float(lo16 << 16);
}
static __device__ __forceinline__ unsigned short f2bf(float f) {
  unsigned int x = __float_as_uint(f);
  return (unsigned short)((x + 0x7FFFu + ((x >> 16) & 1u)) >> 16);
}
// packed RNE f32x2 -> bf16x2 (lo = a, hi = b) via hardware cvt (gfx950)
static __device__ __forceinline__ unsigned int f2bf2(float a, float b) {
  unsigned int r;
  asm("v_cvt_pk_bf16_f32 %0, %1, %2" : "=v"(r) : "v"(a), "v"(b));
  return r;
}

// ---------------- prep kernels ----------------

__global__ __launch_bounds__(256) void k_prep_h(const float* __restrict__ h,
                                                unsigned short* __restrict__ nodeA) {
  int idx = blockIdx.x * 256 + threadIdx.x;
  if (idx >= Nn * 128) return;
  int n = idx >> 7, k = idx & 127;
  nodeA[(size_t)n * 256 + k] = f2bf(h[idx]);
}

// weight fp32 [128][Ksrc] cols [koff, koff+2^kshift) -> bf16 [128][2^kshift]
__global__ __launch_bounds__(256) void k_prep_w(const float* __restrict__ src,
                                                unsigned short* __restrict__ dst, int Ksrc,
                                                int koff, int kshift, int total) {
  int idx = blockIdx.x * 256 + threadIdx.x;
  if (idx >= total) return;
  int n = idx >> kshift;
  int k = idx & ((1 << kshift) - 1);
  dst[idx] = f2bf(src[n * Ksrc + koff + k]);
}

__global__ void k_wlast(const float* __restrict__ e_w1, float* __restrict__ wlast) {
  int t = threadIdx.x;
  if (t < 128) wlast[t] = e_w1[t * 257 + 256];
}

// ---------------- CSR build (edges sorted by row; node ids fit u16) ----------------

__global__ __launch_bounds__(256) void k_count(const int* __restrict__ row, int* __restrict__ cnt) {
  int e = blockIdx.x * 256 + threadIdx.x;
  atomicAdd(&cnt[row[e]], 1);
}

__global__ __launch_bounds__(256) void k_fill(const int* __restrict__ row,
                                              const int* __restrict__ col,
                                              int* __restrict__ cursor,
                                              unsigned short* __restrict__ rowS,
                                              unsigned short* __restrict__ colS) {
  int e = blockIdx.x * 256 + threadIdx.x;
  int r = row[e];
  int pos = atomicAdd(&cursor[r], 1);
  rowS[pos] = (unsigned short)r;
  colS[pos] = (unsigned short)col[e];
}

__global__ __launch_bounds__(1024) void k_scan(const int* __restrict__ cnt, int* __restrict__ start,
                                               int* __restrict__ cursor, int n) {
  __shared__ int wsum[16];
  __shared__ int carry;
  int tid = threadIdx.x, lane = tid & 63, wid = tid >> 6;
  if (tid == 0) carry = 0;
  __syncthreads();
  for (int base = 0; base < n; base += 1024) {
    int i = base + tid;
    int v = (i < n) ? cnt[i] : 0;
    int x = v;
#pragma unroll
    for (int d = 1; d < 64; d <<= 1) {
      int y = __shfl_up(x, d, 64);
      if (lane >= d) x += y;
    }
    if (lane == 63) wsum[wid] = x;
    __syncthreads();
    if (wid == 0) {
      int s = (lane < 16) ? wsum[lane] : 0;
#pragma unroll
      for (int d = 1; d < 16; d <<= 1) {
        int y = __shfl_up(s, d, 64);
        if (lane >= d) s += y;
      }
      if (lane < 16) wsum[lane] = s;
    }
    __syncthreads();
    int c0 = carry;
    int waveoff = (wid > 0) ? wsum[wid - 1] : 0;
    int incl = c0 + waveoff + x;
    if (i < n) {
      start[i] = incl - v;
      cursor[i] = incl - v;
    }
    __syncthreads();
    if (tid == 1023) carry = incl;
    __syncthreads();
  }
}

// ---------------- BN finalize ----------------

__global__ void k_fin(const float* __restrict__ statS, const float* __restrict__ statQ,
                      const float* __restrict__ g, const float* __restrict__ be, float invR,
                      float* __restrict__ bnS, float* __restrict__ bnSh) {
  int c = threadIdx.x;
  if (c >= 128) return;
  float s = 0.f, q = 0.f;
  for (int k = 0; k < NSLOT; ++k) {
    s += statS[k * 128 + c];
    q += statQ[k * 128 + c];
  }
  float mean = s * invR;
  float var = fmaxf(q * invR - mean * mean, 0.f);
  float rs = rsqrtf(var + 1e-5f);
  float sc = g[c] * rs;
  bnS[c] = sc;
  bnSh[c] = be[c] - mean * sc;
}

// ---------------- generic MFMA GEMM with W in LDS ----------------
template <int KSTEPS, bool BN_A, bool STATS, bool FP32OUT, bool STORE>
__global__ __launch_bounds__(256) void k_gemmW(
    const unsigned short* __restrict__ A, int Astride,
    const unsigned short* __restrict__ W, const float* __restrict__ bias,
    const float* __restrict__ bnS, const float* __restrict__ bnSh,
    unsigned short* __restrict__ outb, float* __restrict__ statS, float* __restrict__ statQ,
    const float* __restrict__ hres, float* __restrict__ outf, int R) {
  constexpr int K = KSTEPS * 32;
  constexpr int WST = K + 8;
  constexpr int SEGS = K / 8;
  __shared__ __align__(16) unsigned short smem[128 * WST];
  __shared__ float ssum[4][128], ssq[4][128];
  int tid = threadIdx.x;
  int w = tid >> 6, lane = tid & 63, m = lane & 15, kq = lane >> 4;
  int rbase = blockIdx.x * 128;
#pragma unroll
  for (int it = 0; it < SEGS / 2; ++it) {
    int idx = it * 256 + tid;
    int n = idx / SEGS, seg = idx % SEGS;
    uint4 v = *(const uint4*)(W + (size_t)n * K + seg * 8);
    *(uint4*)(smem + n * WST + seg * 8) = v;
  }
  __syncthreads();
  int row0 = rbase + w * 32 + m;
  int rc0 = min(row0, R - 1);
  int rc1 = min(row0 + 16, R - 1);
  f32x4 acc[2][8];
#pragma unroll
  for (int rt = 0; rt < 2; ++rt)
#pragma unroll
    for (int c = 0; c < 8; ++c) acc[rt][c] = (f32x4){0.f, 0.f, 0.f, 0.f};
#pragma unroll
  for (int ks = 0; ks < KSTEPS; ++ks) {
    int k0 = ks * 32 + kq * 8;
    U8 ua0, ua1;
    ua0.u4 = *(const uint4*)(A + (size_t)rc0 * Astride + k0);
    ua1.u4 = *(const uint4*)(A + (size_t)rc1 * Astride + k0);
    if (BN_A) {
      const float4* sp = (const float4*)(bnS + k0);
      const float4* hp = (const float4*)(bnSh + k0);
      float4 s0 = sp[0], s1 = sp[1], h0 = hp[0], h1 = hp[1];
      float sv[8] = {s0.x, s0.y, s0.z, s0.w, s1.x, s1.y, s1.z, s1.w};
      float hv[8] = {h0.x, h0.y, h0.z, h0.w, h1.x, h1.y, h1.z, h1.w};
      U8 pa, pb;
#pragma unroll
      for (int jj = 0; jj < 4; ++jj) {
        float a0 = fmaxf(bf2f(ua0.us[2 * jj]) * sv[2 * jj] + hv[2 * jj], 0.f);
        float a1 = fmaxf(bf2f(ua0.us[2 * jj + 1]) * sv[2 * jj + 1] + hv[2 * jj + 1], 0.f);
        float b0 = fmaxf(bf2f(ua1.us[2 * jj]) * sv[2 * jj] + hv[2 * jj], 0.f);
        float b1 = fmaxf(bf2f(ua1.us[2 * jj + 1]) * sv[2 * jj + 1] + hv[2 * jj + 1], 0.f);
        pa.ui[jj] = f2bf2(a0, a1);
        pb.ui[jj] = f2bf2(b0, b1);
      }
      ua0 = pa;
      ua1 = pb;
    }
#pragma unroll
    for (int c = 0; c < 8; ++c) {
      U8 ub;
      ub.u4 = *(const uint4*)(smem + (c * 16 + m) * WST + k0);
      acc[0][c] = __builtin_amdgcn_mfma_f32_16x16x32_bf16(ua0.s8, ub.s8, acc[0][c], 0, 0, 0);
      acc[1][c] = __builtin_amdgcn_mfma_f32_16x16x32_bf16(ua1.s8, ub.s8, acc[1][c], 0, 0, 0);
    }
  }
  if constexpr (FP32OUT) {
#pragma unroll
    for (int rt = 0; rt < 2; ++rt)
#pragma unroll
      for (int c = 0; c < 8; ++c) {
        int n = c * 16 + m;
        float bn_ = bias[n];
#pragma unroll
        for (int j = 0; j < 4; ++j) {
          int rr = rbase + w * 32 + rt * 16 + kq * 4 + j;
          if (rr < R) {
            size_t o = (size_t)rr * 128 + n;
            outf[o] = acc[rt][c][j] + bn_ + hres[o];
          }
        }
      }
  } else {
    if constexpr (STORE) __syncthreads();
    unsigned short* tile = smem;  // reuse as [128][136]
#pragma unroll
    for (int c = 0; c < 8; ++c) {
      int n = c * 16 + m;
      float bn_ = bias ? bias[n] : 0.f;
      float s = 0.f, q = 0.f;
#pragma unroll
      for (int rt = 0; rt < 2; ++rt)
#pragma unroll
        for (int j = 0; j < 4; ++j) {
          int lr = w * 32 + rt * 16 + kq * 4 + j;
          float v = acc[rt][c][j] + bn_;
          if (STORE) tile[lr * 136 + n] = f2bf(v);
          if (STATS) {
            float sv = (rbase + lr < R) ? v : 0.f;
            s += sv;
            q = fmaf(sv, sv, q);
          }
        }
      if (STATS) {
        s += __shfl_xor(s, 16, 64); s += __shfl_xor(s, 32, 64);
        q += __shfl_xor(q, 16, 64); q += __shfl_xor(q, 32, 64);
        if (kq == 0) { ssum[w][n] = s; ssq[w][n] = q; }
      }
    }
    if constexpr (STORE) {
      __syncthreads();
      const uint4* tl = (const uint4*)tile;
#pragma unroll
      for (int u = 0; u < 8; ++u) {
        int idx = u * 256 + tid;
        int rr = idx >> 4, seg = idx & 15;
        if (rbase + rr < R)
          *(uint4*)(outb + (size_t)(rbase + rr) * 128 + seg * 8) = tl[rr * 17 + seg];
      }
    }
    if (STATS) {
      __syncthreads();
      if (tid < 128) {
        float s = ssum[0][tid] + ssum[1][tid] + ssum[2][tid] + ssum[3][tid];
        float q = ssq[0][tid] + ssq[1][tid] + ssq[2][tid] + ssq[3][tid];
        int slot = blockIdx.x & (NSLOT - 1);
        atomicAdd(&statS[slot * 128 + tid], s);
        atomicAdd(&statQ[slot * 128 + tid], q);
      }
    }
  }
}

// ---------------- bn1 stats over virtual t1 (no materialization) + radS ----------------
// per_wave is even and En is even -> every wave's range has even length
__global__ __launch_bounds__(256) void k_stats1(
    const unsigned short* __restrict__ hWr, const unsigned short* __restrict__ hWc,
    const float* __restrict__ coord, const unsigned short* __restrict__ rowS,
    const unsigned short* __restrict__ colS, const float* __restrict__ wlast,
    float* __restrict__ radS, float* __restrict__ statS, float* __restrict__ statQ,
    int per_wave) {
  int tid = threadIdx.x, lane = tid & 63;
  int wid = blockIdx.x * 4 + (tid >> 6);
  int e0 = wid * per_wave;
  int e1 = min(e0 + per_wave, En);
  int c2 = lane * 2;
  float wl0 = wlast[c2], wl1 = wlast[c2 + 1];
  float s0 = 0.f, s1 = 0.f, q0 = 0.f, q1 = 0.f;
  for (int e = e0; e < e1; e += 2) {
    int ra = rowS[e], ca = colS[e];
    int rb = rowS[e + 1], cb = colS[e + 1];
    float ax = coord[ra * 3 + 0] - coord[ca * 3 + 0];
    float ay = coord[ra * 3 + 1] - coord[ca * 3 + 1];
    float az = coord[ra * 3 + 2] - coord[ca * 3 + 2];
    float bx = coord[rb * 3 + 0] - coord[cb * 3 + 0];
    float by = coord[rb * 3 + 1] - coord[cb * 3 + 1];
    float bz = coord[rb * 3 + 2] - coord[cb * 3 + 2];
    float rada = ax * ax + ay * ay + az * az;
    float radb = bx * bx + by * by + bz * bz;
    if (lane == 0) {
      radS[e] = rada;
      radS[e + 1] = radb;
    }
    unsigned int uar = *(const unsigned int*)(hWr + (size_t)ra * 128 + c2);
    unsigned int uac = *(const unsigned int*)(hWc + (size_t)ca * 128 + c2);
    unsigned int ubr = *(const unsigned int*)(hWr + (size_t)rb * 128 + c2);
    unsigned int ubc = *(const unsigned int*)(hWc + (size_t)cb * 128 + c2);
    float va0 = bf2f(uar & 0xFFFFu) + bf2f(uac & 0xFFFFu) + rada * wl0;
    float va1 = bf2f(uar >> 16) + bf2f(uac >> 16) + rada * wl1;
    float vb0 = bf2f(ubr & 0xFFFFu) + bf2f(ubc & 0xFFFFu) + radb * wl0;
    float vb1 = bf2f(ubr >> 16) + bf2f(ubc >> 16) + radb * wl1;
    s0 += va0 + vb0;
    s1 += va1 + vb1;
    q0 = fmaf(va0, va0, q0); q0 = fmaf(vb0, vb0, q0);
    q1 = fmaf(va1, va1, q1); q1 = fmaf(vb1, vb1, q1);
  }
  int slot = wid & (NSLOT - 1);
  atomicAdd(&statS[slot * 128 + c2], s0);
  atomicAdd(&statS[slot * 128 + c2 + 1], s1);
  atomicAdd(&statQ[slot * 128 + c2], q0);
  atomicAdd(&statQ[slot * 128 + c2 + 1], q1);
}

// ---------------- edge layer 2 GEMM, A recomputed from hWr/hWc/radS ----------------
__global__ __launch_bounds__(256) void k_egemm2(
    const unsigned short* __restrict__ hWr, const unsigned short* __restrict__ hWc,
    const float* __restrict__ radS, const unsigned short* __restrict__ rowS,
    const unsigned short* __restrict__ colS, const unsigned short* __restrict__ W,
    const float* __restrict__ bias, const float* __restrict__ wlast,
    const float* __restrict__ bnS1, const float* __restrict__ bnSh1,
    unsigned short* __restrict__ outb, float* __restrict__ statS, float* __restrict__ statQ) {
  constexpr int WST = 136;
  __shared__ __align__(16) unsigned short smem[128 * WST];
  __shared__ float ssum[4][128], ssq[4][128];
  int tid = threadIdx.x;
  int w = tid >> 6, lane = tid & 63, m = lane & 15, kq = lane >> 4;
  int rbase = blockIdx.x * 128;
#pragma unroll
  for (int it = 0; it < 8; ++it) {
    int idx = it * 256 + tid;
    int n = idx >> 4, seg = idx & 15;
    uint4 v = *(const uint4*)(W + (size_t)n * 128 + seg * 8);
    *(uint4*)(smem + n * WST + seg * 8) = v;
  }
  int rc0 = rbase + w * 32 + m, rc1 = rc0 + 16;
  int r0 = rowS[rc0], c0 = colS[rc0];
  int r1 = rowS[rc1], c1 = colS[rc1];
  float rad0 = radS[rc0], rad1 = radS[rc1];
  __syncthreads();
  f32x4 acc[2][8];
#pragma unroll
  for (int rt = 0; rt < 2; ++rt)
#pragma unroll
    for (int c = 0; c < 8; ++c) acc[rt][c] = (f32x4){0.f, 0.f, 0.f, 0.f};
#pragma unroll
  for (int ks = 0; ks < 4; ++ks) {
    int k0 = ks * 32 + kq * 8;
    U8 a0r, a0c, a1r, a1c;
    a0r.u4 = *(const uint4*)(hWr + (size_t)r0 * 128 + k0);
    a0c.u4 = *(const uint4*)(hWc + (size_t)c0 * 128 + k0);
    a1r.u4 = *(const uint4*)(hWr + (size_t)r1 * 128 + k0);
    a1c.u4 = *(const uint4*)(hWc + (size_t)c1 * 128 + k0);
    const float4* wp = (const float4*)(wlast + k0);
    const float4* sp = (const float4*)(bnS1 + k0);
    const float4* hp = (const float4*)(bnSh1 + k0);
    float4 w0 = wp[0], w1 = wp[1], sA = sp[0], sB = sp[1], hA = hp[0], hB = hp[1];
    float wv[8] = {w0.x, w0.y, w0.z, w0.w, w1.x, w1.y, w1.z, w1.w};
    float sv[8] = {sA.x, sA.y, sA.z, sA.w, sB.x, sB.y, sB.z, sB.w};
    float hv[8] = {hA.x, hA.y, hA.z, hA.w, hB.x, hB.y, hB.z, hB.w};
    U8 ua0, ua1;
#pragma unroll
    for (int jj = 0; jj < 4; ++jj) {
      int j0 = 2 * jj, j1 = 2 * jj + 1;
      float v0a = bf2f(a0r.us[j0]) + bf2f(a0c.us[j0]) + rad0 * wv[j0];
      float v0b = bf2f(a0r.us[j1]) + bf2f(a0c.us[j1]) + rad0 * wv[j1];
      float v1a = bf2f(a1r.us[j0]) + bf2f(a1c.us[j0]) + rad1 * wv[j0];
      float v1b = bf2f(a1r.us[j1]) + bf2f(a1c.us[j1]) + rad1 * wv[j1];
      v0a = fmaxf(v0a * sv[j0] + hv[j0], 0.f);
      v0b = fmaxf(v0b * sv[j1] + hv[j1], 0.f);
      v1a = fmaxf(v1a * sv[j0] + hv[j0], 0.f);
      v1b = fmaxf(v1b * sv[j1] + hv[j1], 0.f);
      ua0.ui[jj] = f2bf2(v0a, v0b);
      ua1.ui[jj] = f2bf2(v1a, v1b);
    }
#pragma unroll
    for (int c = 0; c < 8; ++c) {
      U8 ub;
      ub.u4 = *(const uint4*)(smem + (c * 16 + m) * WST + k0);
      acc[0][c] = __builtin_amdgcn_mfma_f32_16x16x32_bf16(ua0.s8, ub.s8, acc[0][c], 0, 0, 0);
      acc[1][c] = __builtin_amdgcn_mfma_f32_16x16x32_bf16(ua1.s8, ub.s8, acc[1][c], 0, 0, 0);
    }
  }
  __syncthreads();
  unsigned short* tile = smem;
#pragma unroll
  for (int c = 0; c < 8; ++c) {
    int n = c * 16 + m;
    float bn_ = bias[n];
    float s = 0.f, q = 0.f;
#pragma unroll
    for (int rt = 0; rt < 2; ++rt)
#pragma unroll
      for (int j = 0; j < 4; ++j) {
        int lr = w * 32 + rt * 16 + kq * 4 + j;
        float v = acc[rt][c][j] + bn_;
        tile[lr * 136 + n] = f2bf(v);
        s += v;
        q = fmaf(v, v, q);
      }
    s += __shfl_xor(s, 16, 64); s += __shfl_xor(s, 32, 64);
    q += __shfl_xor(q, 16, 64); q += __shfl_xor(q, 32, 64);
    if (kq == 0) { ssum[w][n] = s; ssq[w][n] = q; }
  }
  __syncthreads();
  const uint4* tl = (const uint4*)tile;
#pragma unroll
  for (int u = 0; u < 8; ++u) {
    int idx = u * 256 + tid;
    int rr = idx >> 4, seg = idx & 15;
    *(uint4*)(outb + (size_t)(rbase + rr) * 128 + seg * 8) = tl[rr * 17 + seg];
  }
  if (tid < 128) {
    float s = ssum[0][tid] + ssum[1][tid] + ssum[2][tid] + ssum[3][tid];
    float q = ssq[0][tid] + ssq[1][tid] + ssq[2][tid] + ssq[3][tid];
    int slot = blockIdx.x & (NSLOT - 1);
    atomicAdd(&statS[slot * 128 + tid], s);
    atomicAdd(&statQ[slot * 128 + tid], q);
  }
}

// ---------------- node aggregation over contiguous CSR rows (no atomics) ----------------
__global__ __launch_bounds__(256) void k_agg(const unsigned short* __restrict__ t,
                                             const int* __restrict__ start,
                                             const int* __restrict__ cnt,
                                             const float* __restrict__ bnS,
                                             const float* __restrict__ bnSh,
                                             unsigned short* __restrict__ nodeA) {
  int tid = threadIdx.x;
  int lane = tid & 63;
  int n = blockIdx.x * 4 + (tid >> 6);
  if (n >= Nn) return;
  int deg = cnt[n], off = start[n];
  int c2 = lane * 2;
  float s0 = bnS[c2], s1 = bnS[c2 + 1], h0 = bnSh[c2], h1 = bnSh[c2 + 1];
  float a0 = 0.f, a1 = 0.f;
  const unsigned short* p = t + (size_t)off * 128 + c2;
  for (int j = 0; j < deg; ++j) {
    unsigned int u = *(const unsigned int*)(p + (size_t)j * 128);
    a0 += fmaxf(bf2f(u & 0xFFFFu) * s0 + h0, 0.f);
    a1 += fmaxf(bf2f(u >> 16) * s1 + h1, 0.f);
  }
  float inv = 1.f / fmaxf((float)deg, 1.f);
  unsigned int o = (unsigned)f2bf(a0 * inv) | ((unsigned)f2bf(a1 * inv) << 16);
  *(unsigned int*)(nodeA + (size_t)n * 256 + 128 + c2) = o;
}

// ---------------- second-moment of y = relu(bn2(t2)) — pipelined, 8 waves ----------------
// M = sum_e y y^T (full 128x128), Sy[c] = sum_e y[e][c].
// 512 threads: wave w owns channel strip [w*16, w*16+16) for staging AND M-rows strip.
// Next tile's global loads issue BEFORE the barriers so HBM latency hides under MFMA.
__global__ __launch_bounds__(512) void k_moment(
    const unsigned short* __restrict__ t,
    const float* __restrict__ bnS2, const float* __restrict__ bnSh2,
    float* __restrict__ Mpart, float* __restrict__ SyG) {
  constexpr int WST = 136;
  constexpr int NT = En / 128;
  __shared__ __align__(16) unsigned short yT[128 * WST];
  __shared__ float s2L[128], h2L[128];
  int tid = threadIdx.x;
  int w = tid >> 6, lane = tid & 63, m = lane & 15, kq = lane >> 4;
  if (tid < 128) { s2L[tid] = bnS2[tid]; h2L[tid] = bnSh2[tid]; }
  __syncthreads();
  float sA[16], hA[16];
#pragma unroll
  for (int c = 0; c < 16; ++c) { sA[c] = s2L[w * 16 + c]; hA[c] = h2L[w * 16 + c]; }
  f32x4 acc[8];
#pragma unroll
  for (int c = 0; c < 8; ++c) acc[c] = (f32x4){0.f, 0.f, 0.f, 0.f};
  float sy[16];
#pragma unroll
  for (int c = 0; c < 16; ++c) sy[c] = 0.f;
  int tile = blockIdx.x;
  U8 cura0, cura1, curb0, curb1, nxta0, nxta1, nxtb0, nxtb1;
  {
    const unsigned short* p = t + ((size_t)tile * 128 + lane * 2) * 128 + w * 16;
    cura0.u4 = *(const uint4*)(p);
    cura1.u4 = *(const uint4*)(p + 8);
    curb0.u4 = *(const uint4*)(p + 128);
    curb1.u4 = *(const uint4*)(p + 136);
  }
  while (tile < NT) {
    int nxt = tile + MGRID;
    // transform current tile -> packed bf16 pairs (2 edges per u32)
    unsigned int pk[16];
#pragma unroll
    for (int c = 0; c < 16; ++c) {
      float ya = fmaxf(bf2f((c < 8) ? cura0.us[c & 7] : cura1.us[c & 7]) * sA[c] + hA[c], 0.f);
      float yb = fmaxf(bf2f((c < 8) ? curb0.us[c & 7] : curb1.us[c & 7]) * sA[c] + hA[c], 0.f);
      sy[c] += ya + yb;
      pk[c] = f2bf2(ya, yb);
    }
    // prefetch next tile (in flight across barriers + MFMA phase)
    if (nxt < NT) {
      const unsigned short* p = t + ((size_t)nxt * 128 + lane * 2) * 128 + w * 16;
      nxta0.u4 = *(const uint4*)(p);
      nxta1.u4 = *(const uint4*)(p + 8);
      nxtb0.u4 = *(const uint4*)(p + 128);
      nxtb1.u4 = *(const uint4*)(p + 136);
    }
    __syncthreads();  // prior MFMA reads of yT complete
#pragma unroll
    for (int c = 0; c < 16; ++c)
      *(unsigned int*)(yT + (w * 16 + c) * WST + lane * 2) = pk[c];
    __syncthreads();
#pragma unroll
    for (int ks = 0; ks < 4; ++ks) {
      int k0 = ks * 32 + kq * 8;
      U8 a;
      a.u4 = *(const uint4*)(yT + (w * 16 + m) * WST + k0);
#pragma unroll
      for (int c = 0; c < 8; ++c) {
        U8 b;
        b.u4 = *(const uint4*)(yT + (c * 16 + m) * WST + k0);
        acc[c] = __builtin_amdgcn_mfma_f32_16x16x32_bf16(a.s8, b.s8, acc[c], 0, 0, 0);
      }
    }
    cura0 = nxta0; cura1 = nxta1; curb0 = nxtb0; curb1 = nxtb1;
    tile = nxt;
  }
  size_t mb = (size_t)blockIdx.x * 16384;
#pragma unroll
  for (int c = 0; c < 8; ++c)
#pragma unroll
    for (int j = 0; j < 4; ++j)
      Mpart[mb + (size_t)(w * 16 + kq * 4 + j) * 128 + c * 16 + m] = acc[c][j];
#pragma unroll
  for (int c = 0; c < 16; ++c) {
    float s = sy[c];
#pragma unroll
    for (int d = 1; d < 64; d <<= 1) s += __shfl_xor(s, d, 64);
    if (lane == 0) atomicAdd(&SyG[w * 16 + c], s);
  }
}

__global__ __launch_bounds__(256) void k_msum(const float* __restrict__ Mpart,
                                              float* __restrict__ Mg) {
  __shared__ float red[4][64];
  int tid = threadIdx.x;
  int e = blockIdx.x * 64 + (tid & 63);
  int pq = tid >> 6;
  float s = 0.f;
  for (int k = pq * (MGRID / 4); k < (pq + 1) * (MGRID / 4); ++k)
    s += Mpart[(size_t)k * 16384 + e];
  red[pq][tid & 63] = s;
  __syncthreads();
  if (tid < 64) Mg[e] = red[0][tid] + red[1][tid] + red[2][tid] + red[3][tid];
}

// bn3 params from moments: var[c] = (w_c M w_c^T)/E - (w_c . Sy / E)^2  (bias cancels)
// block = channel c; 128 threads each own column j of M.
__global__ __launch_bounds__(128) void k_fin3(
    const float* __restrict__ Mg, const float* __restrict__ Sy,
    const float* __restrict__ w1, const float* __restrict__ g,
    const float* __restrict__ be, float invE,
    float* __restrict__ bnS3, float* __restrict__ bnSh3) {
  __shared__ float sW[128];
  __shared__ float r2[4];
  int c = blockIdx.x, j = threadIdx.x;
  sW[j] = w1[c * 128 + j];
  __syncthreads();
  float a0 = 0.f, a1 = 0.f, a2 = 0.f, a3 = 0.f;
  for (int i = 0; i < 128; i += 4) {
    a0 = fmaf(sW[i], Mg[i * 128 + j], a0);
    a1 = fmaf(sW[i + 1], Mg[(i + 1) * 128 + j], a1);
    a2 = fmaf(sW[i + 2], Mg[(i + 2) * 128 + j], a2);
    a3 = fmaf(sW[i + 3], Mg[(i + 3) * 128 + j], a3);
  }
  float q = sW[j] * ((a0 + a1) + (a2 + a3));
  float dm = sW[j] * Sy[j];
#pragma unroll
  for (int d = 1; d < 64; d <<= 1) {
    q += __shfl_xor(q, d, 64);
    dm += __shfl_xor(dm, d, 64);
  }
  int wv = j >> 6;
  if ((j & 63) == 0) { r2[wv * 2] = q; r2[wv * 2 + 1] = dm; }
  __syncthreads();
  if (j == 0) {
    float quad = r2[0] + r2[2];
    float dmt = r2[1] + r2[3];
    float Eu = dmt * invE;
    float var = fmaxf(quad * invE - Eu * Eu, 0.f);
    float S = g[c] * rsqrtf(var + 1e-5f);
    bnS3[c] = S;
    bnSh3[c] = be[c] - Eu * S;  // GEMM bias c_b1 cancels inside BN
  }
}

// ---------------- coord GEMM with fused bn3+relu+dot(c_w2) epilogue -> scaleE ----------------
__global__ __launch_bounds__(256) void k_cgemm(
    const unsigned short* __restrict__ A,   // t2 [En][128] bf16
    const unsigned short* __restrict__ W,   // c1b bf16 [128][128]
    const float* __restrict__ bnS2, const float* __restrict__ bnSh2,
    const float* __restrict__ bnS3, const float* __restrict__ bnSh3,
    const float* __restrict__ cw2, float* __restrict__ scaleE) {
  constexpr int WST = 136;
  __shared__ __align__(16) unsigned short smem[128 * WST];
  int tid = threadIdx.x;
  int w = tid >> 6, lane = tid & 63, m = lane & 15, kq = lane >> 4;
  int rbase = blockIdx.x * 128;
#pragma unroll
  for (int it = 0; it < 8; ++it) {
    int idx = it * 256 + tid;
    int n = idx >> 4, seg = idx & 15;
    *(uint4*)(smem + n * WST + seg * 8) = *(const uint4*)(W + (size_t)n * 128 + seg * 8);
  }
  __syncthreads();
  int rc0 = rbase + w * 32 + m, rc1 = rc0 + 16;
  f32x4 acc[2][8];
#pragma unroll
  for (int rt = 0; rt < 2; ++rt)
#pragma unroll
    for (int c = 0; c < 8; ++c) acc[rt][c] = (f32x4){0.f, 0.f, 0.f, 0.f};
#pragma unroll
  for (int ks = 0; ks < 4; ++ks) {
    int k0 = ks * 32 + kq * 8;
    U8 ua0, ua1;
    ua0.u4 = *(const uint4*)(A + (size_t)rc0 * 128 + k0);
    ua1.u4 = *(const uint4*)(A + (size_t)rc1 * 128 + k0);
    const float4* sp = (const float4*)(bnS2 + k0);
    const float4* hp = (const float4*)(bnSh2 + k0);
    float4 s0 = sp[0], s1 = sp[1], h0 = hp[0], h1 = hp[1];
    float sv[8] = {s0.x, s0.y, s0.z, s0.w, s1.x, s1.y, s1.z, s1.w};
    float hv[8] = {h0.x, h0.y, h0.z, h0.w, h1.x, h1.y, h1.z, h1.w};
    U8 pa, pb;
#pragma unroll
    for (int jj = 0; jj < 4; ++jj) {
      float v0a = fmaxf(bf2f(ua0.us[2 * jj]) * sv[2 * jj] + hv[2 * jj], 0.f);
      float v0b = fmaxf(bf2f(ua0.us[2 * jj + 1]) * sv[2 * jj + 1] + hv[2 * jj + 1], 0.f);
      float v1a = fmaxf(bf2f(ua1.us[2 * jj]) * sv[2 * jj] + hv[2 * jj], 0.f);
      float v1b = fmaxf(bf2f(ua1.us[2 * jj + 1]) * sv[2 * jj + 1] + hv[2 * jj + 1], 0.f);
      pa.ui[jj] = f2bf2(v0a, v0b);
      pb.ui[jj] = f2bf2(v1a, v1b);
    }
#pragma unroll
    for (int c = 0; c < 8; ++c) {
      U8 ub;
      ub.u4 = *(const uint4*)(smem + (c * 16 + m) * WST + k0);
      acc[0][c] = __builtin_amdgcn_mfma_f32_16x16x32_bf16(pa.s8, ub.s8, acc[0][c], 0, 0, 0);
      acc[1][c] = __builtin_amdgcn_mfma_f32_16x16x32_bf16(pb.s8, ub.s8, acc[1][c], 0, 0, 0);
    }
  }
  // epilogue: scale[e] = sum_n cw2[n] * relu(acc*S3[n] + Sh3[n])
  float s3v[8], h3v[8], wv[8];
#pragma unroll
  for (int c = 0; c < 8; ++c) {
    int n = c * 16 + m;
    s3v[c] = bnS3[n];
    h3v[c] = bnSh3[n];
    wv[c] = cw2[n];
  }
  float p0[4] = {0.f, 0.f, 0.f, 0.f}, p1[4] = {0.f, 0.f, 0.f, 0.f};
#pragma unroll
  for (int c = 0; c < 8; ++c)
#pragma unroll
    for (int j = 0; j < 4; ++j) {
      p0[j] += fmaxf(acc[0][c][j] * s3v[c] + h3v[c], 0.f) * wv[c];
      p1[j] += fmaxf(acc[1][c][j] * s3v[c] + h3v[c], 0.f) * wv[c];
    }
#pragma unroll
  for (int j = 0; j < 4; ++j)
#pragma unroll
    for (int d = 1; d < 16; d <<= 1) {
      p0[j] += __shfl_xor(p0[j], d, 64);
      p1[j] += __shfl_xor(p1[j], d, 64);
    }
  if (m == 0) {
    int r0 = rbase + w * 32 + kq * 4;
    *(float4*)(scaleE + r0) = make_float4(p0[0], p0[1], p0[2], p0[3]);
    *(float4*)(scaleE + r0 + 16) = make_float4(p1[0], p1[1], p1[2], p1[3]);
  }
}

// coord_out: contiguous CSR ranges, coalesced
__global__ __launch_bounds__(256) void k_coord(const float* __restrict__ coord,
                                               const unsigned short* __restrict__ colS,
                                               const int* __restrict__ start,
                                               const int* __restrict__ cnt,
                                               const float* __restrict__ scaleE,
                                               float* __restrict__ cout) {
  int tid = threadIdx.x;
  int lane = tid & 63;
  int n = blockIdx.x * 4 + (tid >> 6);
  if (n >= Nn) return;
  int deg = cnt[n], off = start[n];
  float cx0 = coord[n * 3 + 0], cy0 = coord[n * 3 + 1], cz0 = coord[n * 3 + 2];
  float ax = 0.f, ay = 0.f, az = 0.f;
  for (int j = lane; j < deg; j += 64) {
    int e = off + j;
    int c = colS[e];
    float s = scaleE[e];
    float tx = (cx0 - coord[c * 3 + 0]) * s;
    float ty = (cy0 - coord[c * 3 + 1]) * s;
    float tz = (cz0 - coord[c * 3 + 2]) * s;
    ax += fminf(fmaxf(tx, -100.f), 100.f);
    ay += fminf(fmaxf(ty, -100.f), 100.f);
    az += fminf(fmaxf(tz, -100.f), 100.f);
  }
#pragma unroll
  for (int d = 32; d; d >>= 1) {
    ax += __shfl_xor(ax, d, 64);
    ay += __shfl_xor(ay, d, 64);
    az += __shfl_xor(az, d, 64);
  }
  if (lane == 0) {
    float inv = 1.f / fmaxf((float)deg, 1.f);
    cout[n * 3 + 0] = cx0 + ax * inv;
    cout[n * 3 + 1] = cy0 + ay * inv;
    cout[n * 3 + 2] = cz0 + az * inv;
  }
}

// ---------------- launcher ----------------

extern "C" void kernel_launch(void* const* d_in, const int* in_sizes, int n_in, void* d_out,
                              int out_size, void* d_ws, size_t ws_size, hipStream_t stream) {
  (void)in_sizes; (void)n_in; (void)out_size; (void)ws_size;
  const float* h = (const float*)d_in[0];
  const float* coord = (const float*)d_in[1];
  const int* eidx = (const int*)d_in[2];
  const int* row = eidx;
  const int* col = eidx + En;
  const float* e_w1 = (const float*)d_in[3];
  const float* e_b1 = (const float*)d_in[4];
  const float* e_g1 = (const float*)d_in[5];
  const float* e_be1 = (const float*)d_in[6];
  const float* e_w2 = (const float*)d_in[7];
  const float* e_b2 = (const float*)d_in[8];
  const float* e_g2 = (const float*)d_in[9];
  const float* e_be2 = (const float*)d_in[10];
  const float* n_w1 = (const float*)d_in[11];
  const float* n_b1 = (const float*)d_in[12];
  const float* n_g1 = (const float*)d_in[13];
  const float* n_be1 = (const float*)d_in[14];
  const float* n_w2 = (const float*)d_in[15];
  const float* n_b2 = (const float*)d_in[16];
  const float* c_w1 = (const float*)d_in[17];
  const float* c_b1 = (const float*)d_in[18];
  (void)c_b1;  // bias before BN cancels analytically (k_fin3)
  const float* c_g1 = (const float*)d_in[19];
  const float* c_be1 = (const float*)d_in[20];
  const float* c_w2 = (const float*)d_in[21];

  char* base = (char*)d_ws;
  size_t off = 0;
  auto alloc = [&](size_t bytes) -> void* {
    void* p = base + off;
    off = (off + bytes + 255) & ~(size_t)255;
    return p;
  };
  // Workspace budget: ~260 MB (proven footprint, unchanged — moment buffers aliased).
  unsigned short* t = (unsigned short*)alloc((size_t)En * 128 * 2);      // t2, then t4
  unsigned short* nodeA = (unsigned short*)alloc((size_t)Nn * 256 * 2);  // [h | agg] bf16
  unsigned short* hWr = (unsigned short*)alloc((size_t)Nn * 128 * 2);
  unsigned short* hWc = (unsigned short*)alloc((size_t)Nn * 128 * 2);
  float* scaleE = (float*)alloc((size_t)En * 4);
  float* radS = scaleE;  // alias: radS dead (after k_egemm2) before scaleE written (k_cgemm)
  unsigned short* rowS = (unsigned short*)alloc((size_t)En * 2);
  unsigned short* colS = (unsigned short*)alloc((size_t)En * 2);
  int* cnt = (int*)alloc((size_t)Nn * 4);
  int* startp = (int*)alloc((size_t)Nn * 4);
  int* cursor = (int*)alloc((size_t)Nn * 4);
  float* statS = (float*)alloc(4 * NSLOT * 128 * 4);
  float* statQ = (float*)alloc(4 * NSLOT * 128 * 4);
  float* bnS = (float*)alloc(4 * 128 * 4);
  float* bnSh = (float*)alloc(4 * 128 * 4);
  unsigned short* w1a = (unsigned short*)alloc(128 * 128 * 2);
  unsigned short* w1b = (unsigned short*)alloc(128 * 128 * 2);
  unsigned short* w2b = (unsigned short*)alloc(128 * 128 * 2);
  unsigned short* c1b = (unsigned short*)alloc(128 * 128 * 2);
  unsigned short* n1b = (unsigned short*)alloc(128 * 256 * 2);
  unsigned short* n2b = (unsigned short*)alloc(128 * 128 * 2);
  float* wlast = (float*)alloc(128 * 4);
  // Moment buffers ALIASED into dead regions (no new workspace):
  //  - Mpart (MGRID=384 × 64KB = 25.2 MB) over hWr+hWc (25.6 MB contiguous, dead after k_egemm2)
  //  - Mg (16384 f32) + SyG (128 f32) at head of scaleE region (radS dead after k_egemm2;
  //    scaleE written only later by k_cgemm, after k_fin3 consumed Mg/SyG)
  float* Mpart = (float*)hWr;
  float* Mg = scaleE;
  float* SyG = scaleE + 16384;

  hipMemsetAsync(cnt, 0, (size_t)Nn * 4, stream);
  hipMemsetAsync(statS, 0, 4 * NSLOT * 128 * 4, stream);
  hipMemsetAsync(statQ, 0, 4 * NSLOT * 128 * 4, stream);

  // prep
  k_prep_h<<<(Nn * 128 + 255) / 256, 256, 0, stream>>>(h, nodeA);
  k_prep_w<<<(128 * 128 + 255) / 256, 256, 0, stream>>>(e_w1, w1a, 257, 0, 7, 128 * 128);
  k_prep_w<<<(128 * 128 + 255) / 256, 256, 0, stream>>>(e_w1, w1b, 257, 128, 7, 128 * 128);
  k_prep_w<<<(128 * 128 + 255) / 256, 256, 0, stream>>>(e_w2, w2b, 128, 0, 7, 128 * 128);
  k_prep_w<<<(128 * 128 + 255) / 256, 256, 0, stream>>>(c_w1, c1b, 128, 0, 7, 128 * 128);
  k_prep_w<<<(128 * 256 + 255) / 256, 256, 0, stream>>>(n_w1, n1b, 256, 0, 8, 128 * 256);
  k_prep_w<<<(128 * 128 + 255) / 256, 256, 0, stream>>>(n_w2, n2b, 128, 0, 7, 128 * 128);
  k_wlast<<<1, 128, 0, stream>>>(e_w1, wlast);

  // CSR sort
  k_count<<<En / 256, 256, 0, stream>>>(row, cnt);
  k_scan<<<1, 1024, 0, stream>>>(cnt, startp, cursor, Nn);
  k_fill<<<En / 256, 256, 0, stream>>>(row, col, cursor, rowS, colS);

  // hW partial GEMMs (bias e_b1 folded into hWr)
  const int gridN = (Nn + 127) / 128;
  k_gemmW<4, false, false, false, true><<<gridN, 256, 0, stream>>>(
      nodeA, 256, w1a, e_b1, nullptr, nullptr, hWr, nullptr, nullptr, nullptr, nullptr, Nn);
  k_gemmW<4, false, false, false, true><<<gridN, 256, 0, stream>>>(
      nodeA, 256, w1b, nullptr, nullptr, nullptr, hWc, nullptr, nullptr, nullptr, nullptr, Nn);

  // bn1 stats over virtual t1 + radS (per_wave even for the 2-edge unroll)
  const int per_wave = ((En / 2 + 5119) / 5120) * 2;  // 1280 blocks * 4 waves
  k_stats1<<<1280, 256, 0, stream>>>(hWr, hWc, coord, rowS, colS, wlast, radS,
                                     statS + 0 * NSLOT * 128, statQ + 0 * NSLOT * 128, per_wave);
  k_fin<<<1, 128, 0, stream>>>(statS + 0 * NSLOT * 128, statQ + 0 * NSLOT * 128, e_g1, e_be1,
                               1.f / En, bnS + 0, bnSh + 0);

  // edge layer 2: t2 + bn2 stats (slot 1) — last use of hWr/hWc/radS
  k_egemm2<<<En / 128, 256, 0, stream>>>(hWr, hWc, radS, rowS, colS, w2b, e_b2, wlast, bnS + 0,
                                         bnSh + 0, t, statS + 1 * NSLOT * 128,
                                         statQ + 1 * NSLOT * 128);
  k_fin<<<1, 128, 0, stream>>>(statS + 1 * NSLOT * 128, statQ + 1 * NSLOT * 128, e_g2, e_be2,
                               1.f / En, bnS + 128, bnSh + 128);

  // node aggregation from contiguous t2 rows (no atomics)
  k_agg<<<(Nn + 3) / 4, 256, 0, stream>>>(t, startp, cnt, bnS + 128, bnSh + 128, nodeA);

  // bn3 stats WITHOUT materializing t3: second moment of y = relu(bn2(t2))
  hipMemsetAsync(SyG, 0, 128 * 4, stream);  // after radS is dead, before k_moment
  k_moment<<<MGRID, 512, 0, stream>>>(t, bnS + 128, bnSh + 128, Mpart, SyG);
  k_msum<<<256, 256, 0, stream>>>(Mpart, Mg);
  k_fin3<<<128, 128, 0, stream>>>(Mg, SyG, c_w1, c_g1, c_be1, 1.f / En, bnS + 256, bnSh + 256);

  // coord GEMM with fused bn3+relu+c_w2 epilogue -> per-edge scale (no t3 store, no scale pass)
  k_cgemm<<<En / 128, 256, 0, stream>>>(t, c1b, bnS + 128, bnSh + 128, bnS + 256, bnSh + 256,
                                        c_w2, scaleE);

  float* hout = (float*)d_out;
  float* cout = hout + (size_t)Nn * 128;
  k_coord<<<(Nn + 3) / 4, 256, 0, stream>>>(coord, colS, startp, cnt, scaleE, cout);

  // node MLP: l1 (stats slot 3) -> t4 in t (t2 dead after k_cgemm); l2 fp32 out
  k_gemmW<8, false, true, false, true><<<gridN, 256, 0, stream>>>(
      nodeA, 256, n1b, n_b1, nullptr, nullptr, t, statS + 3 * NSLOT * 128,
      statQ + 3 * NSLOT * 128, nullptr, nullptr, Nn);
  k_fin<<<1, 128, 0, stream>>>(statS + 3 * NSLOT * 128, statQ + 3 * NSLOT * 128, n_g1, n_be1,
                               1.f / Nn, bnS + 384, bnSh + 384);
  k_gemmW<4, true, false, true, true><<<gridN, 256, 0, stream>>>(
      t, 128, n2b, n_b2, bnS + 384, bnSh + 384, nullptr, nullptr, nullptr, h, hout, Nn);
}

// Round 10
// 884.092 us; speedup vs baseline: 1.0380x; 1.0356x over previous
//
#include <hip/hip_runtime.h>

#define Nn 50000
#define En 800000
#define NSLOT 64
#define MGRID 384

typedef __attribute__((ext_vector_type(8))) short short8;
typedef __attribute__((ext_vector_type(4))) float f32x4;

union U8 { uint4 u4; unsigned short us[8]; unsigned int ui[4]; short8 s8; };

static __device__ __forceinline__ float bf2f(unsigned int lo16) {
  return __uint_as_float(lo16 << 16);
}
static __device__ __forceinline__ unsigned short f2bf(float f) {
  unsigned int x = __float_as_uint(f);
  return (unsigned short)((x + 0x7FFFu + ((x >> 16) & 1u)) >> 16);
}
// packed RNE f32x2 -> bf16x2 (lo = a, hi = b) via hardware cvt (gfx950)
static __device__ __forceinline__ unsigned int f2bf2(float a, float b) {
  unsigned int r;
  asm("v_cvt_pk_bf16_f32 %0, %1, %2" : "=v"(r) : "v"(a), "v"(b));
  return r;
}

// ---------------- prep kernels ----------------

__global__ __launch_bounds__(256) void k_prep_h(const float* __restrict__ h,
                                                unsigned short* __restrict__ nodeA) {
  int idx = blockIdx.x * 256 + threadIdx.x;
  if (idx >= Nn * 128) return;
  int n = idx >> 7, k = idx & 127;
  nodeA[(size_t)n * 256 + k] = f2bf(h[idx]);
}

// weight fp32 [128][Ksrc] cols [koff, koff+2^kshift) -> bf16 [128][2^kshift]
__global__ __launch_bounds__(256) void k_prep_w(const float* __restrict__ src,
                                                unsigned short* __restrict__ dst, int Ksrc,
                                                int koff, int kshift, int total) {
  int idx = blockIdx.x * 256 + threadIdx.x;
  if (idx >= total) return;
  int n = idx >> kshift;
  int k = idx & ((1 << kshift) - 1);
  dst[idx] = f2bf(src[n * Ksrc + koff + k]);
}

__global__ void k_wlast(const float* __restrict__ e_w1, float* __restrict__ wlast) {
  int t = threadIdx.x;
  if (t < 128) wlast[t] = e_w1[t * 257 + 256];
}

// ---------------- CSR build (edges sorted by row; node ids fit u16) ----------------

__global__ __launch_bounds__(256) void k_count(const int* __restrict__ row, int* __restrict__ cnt) {
  int e = blockIdx.x * 256 + threadIdx.x;
  atomicAdd(&cnt[row[e]], 1);
}

__global__ __launch_bounds__(256) void k_fill(const int* __restrict__ row,
                                              const int* __restrict__ col,
                                              int* __restrict__ cursor,
                                              unsigned short* __restrict__ rowS,
                                              unsigned short* __restrict__ colS) {
  int e = blockIdx.x * 256 + threadIdx.x;
  int r = row[e];
  int pos = atomicAdd(&cursor[r], 1);
  rowS[pos] = (unsigned short)r;
  colS[pos] = (unsigned short)col[e];
}

__global__ __launch_bounds__(1024) void k_scan(const int* __restrict__ cnt, int* __restrict__ start,
                                               int* __restrict__ cursor, int n) {
  __shared__ int wsum[16];
  __shared__ int carry;
  int tid = threadIdx.x, lane = tid & 63, wid = tid >> 6;
  if (tid == 0) carry = 0;
  __syncthreads();
  for (int base = 0; base < n; base += 1024) {
    int i = base + tid;
    int v = (i < n) ? cnt[i] : 0;
    int x = v;
#pragma unroll
    for (int d = 1; d < 64; d <<= 1) {
      int y = __shfl_up(x, d, 64);
      if (lane >= d) x += y;
    }
    if (lane == 63) wsum[wid] = x;
    __syncthreads();
    if (wid == 0) {
      int s = (lane < 16) ? wsum[lane] : 0;
#pragma unroll
      for (int d = 1; d < 16; d <<= 1) {
        int y = __shfl_up(s, d, 64);
        if (lane >= d) s += y;
      }
      if (lane < 16) wsum[lane] = s;
    }
    __syncthreads();
    int c0 = carry;
    int waveoff = (wid > 0) ? wsum[wid - 1] : 0;
    int incl = c0 + waveoff + x;
    if (i < n) {
      start[i] = incl - v;
      cursor[i] = incl - v;
    }
    __syncthreads();
    if (tid == 1023) carry = incl;
    __syncthreads();
  }
}

// ---------------- BN finalize ----------------

__global__ void k_fin(const float* __restrict__ statS, const float* __restrict__ statQ,
                      const float* __restrict__ g, const float* __restrict__ be, float invR,
                      float* __restrict__ bnS, float* __restrict__ bnSh) {
  int c = threadIdx.x;
  if (c >= 128) return;
  float s = 0.f, q = 0.f;
  for (int k = 0; k < NSLOT; ++k) {
    s += statS[k * 128 + c];
    q += statQ[k * 128 + c];
  }
  float mean = s * invR;
  float var = fmaxf(q * invR - mean * mean, 0.f);
  float rs = rsqrtf(var + 1e-5f);
  float sc = g[c] * rs;
  bnS[c] = sc;
  bnSh[c] = be[c] - mean * sc;
}

// ---------------- generic MFMA GEMM with W in LDS ----------------
template <int KSTEPS, bool BN_A, bool STATS, bool FP32OUT, bool STORE>
__global__ __launch_bounds__(256) void k_gemmW(
    const unsigned short* __restrict__ A, int Astride,
    const unsigned short* __restrict__ W, const float* __restrict__ bias,
    const float* __restrict__ bnS, const float* __restrict__ bnSh,
    unsigned short* __restrict__ outb, float* __restrict__ statS, float* __restrict__ statQ,
    const float* __restrict__ hres, float* __restrict__ outf, int R) {
  constexpr int K = KSTEPS * 32;
  constexpr int WST = K + 8;
  constexpr int SEGS = K / 8;
  __shared__ __align__(16) unsigned short smem[128 * WST];
  __shared__ float ssum[4][128], ssq[4][128];
  int tid = threadIdx.x;
  int w = tid >> 6, lane = tid & 63, m = lane & 15, kq = lane >> 4;
  int rbase = blockIdx.x * 128;
#pragma unroll
  for (int it = 0; it < SEGS / 2; ++it) {
    int idx = it * 256 + tid;
    int n = idx / SEGS, seg = idx % SEGS;
    uint4 v = *(const uint4*)(W + (size_t)n * K + seg * 8);
    *(uint4*)(smem + n * WST + seg * 8) = v;
  }
  __syncthreads();
  int row0 = rbase + w * 32 + m;
  int rc0 = min(row0, R - 1);
  int rc1 = min(row0 + 16, R - 1);
  f32x4 acc[2][8];
#pragma unroll
  for (int rt = 0; rt < 2; ++rt)
#pragma unroll
    for (int c = 0; c < 8; ++c) acc[rt][c] = (f32x4){0.f, 0.f, 0.f, 0.f};
#pragma unroll
  for (int ks = 0; ks < KSTEPS; ++ks) {
    int k0 = ks * 32 + kq * 8;
    U8 ua0, ua1;
    ua0.u4 = *(const uint4*)(A + (size_t)rc0 * Astride + k0);
    ua1.u4 = *(const uint4*)(A + (size_t)rc1 * Astride + k0);
    if (BN_A) {
      const float4* sp = (const float4*)(bnS + k0);
      const float4* hp = (const float4*)(bnSh + k0);
      float4 s0 = sp[0], s1 = sp[1], h0 = hp[0], h1 = hp[1];
      float sv[8] = {s0.x, s0.y, s0.z, s0.w, s1.x, s1.y, s1.z, s1.w};
      float hv[8] = {h0.x, h0.y, h0.z, h0.w, h1.x, h1.y, h1.z, h1.w};
      U8 pa, pb;
#pragma unroll
      for (int jj = 0; jj < 4; ++jj) {
        float a0 = fmaxf(bf2f(ua0.us[2 * jj]) * sv[2 * jj] + hv[2 * jj], 0.f);
        float a1 = fmaxf(bf2f(ua0.us[2 * jj + 1]) * sv[2 * jj + 1] + hv[2 * jj + 1], 0.f);
        float b0 = fmaxf(bf2f(ua1.us[2 * jj]) * sv[2 * jj] + hv[2 * jj], 0.f);
        float b1 = fmaxf(bf2f(ua1.us[2 * jj + 1]) * sv[2 * jj + 1] + hv[2 * jj + 1], 0.f);
        pa.ui[jj] = f2bf2(a0, a1);
        pb.ui[jj] = f2bf2(b0, b1);
      }
      ua0 = pa;
      ua1 = pb;
    }
#pragma unroll
    for (int c = 0; c < 8; ++c) {
      U8 ub;
      ub.u4 = *(const uint4*)(smem + (c * 16 + m) * WST + k0);
      acc[0][c] = __builtin_amdgcn_mfma_f32_16x16x32_bf16(ua0.s8, ub.s8, acc[0][c], 0, 0, 0);
      acc[1][c] = __builtin_amdgcn_mfma_f32_16x16x32_bf16(ua1.s8, ub.s8, acc[1][c], 0, 0, 0);
    }
  }
  if constexpr (FP32OUT) {
#pragma unroll
    for (int rt = 0; rt < 2; ++rt)
#pragma unroll
      for (int c = 0; c < 8; ++c) {
        int n = c * 16 + m;
        float bn_ = bias[n];
#pragma unroll
        for (int j = 0; j < 4; ++j) {
          int rr = rbase + w * 32 + rt * 16 + kq * 4 + j;
          if (rr < R) {
            size_t o = (size_t)rr * 128 + n;
            outf[o] = acc[rt][c][j] + bn_ + hres[o];
          }
        }
      }
  } else {
    if constexpr (STORE) __syncthreads();
    unsigned short* tile = smem;  // reuse as [128][136]
#pragma unroll
    for (int c = 0; c < 8; ++c) {
      int n = c * 16 + m;
      float bn_ = bias ? bias[n] : 0.f;
      float s = 0.f, q = 0.f;
#pragma unroll
      for (int rt = 0; rt < 2; ++rt)
#pragma unroll
        for (int j = 0; j < 4; ++j) {
          int lr = w * 32 + rt * 16 + kq * 4 + j;
          float v = acc[rt][c][j] + bn_;
          if (STORE) tile[lr * 136 + n] = f2bf(v);
          if (STATS) {
            float sv = (rbase + lr < R) ? v : 0.f;
            s += sv;
            q = fmaf(sv, sv, q);
          }
        }
      if (STATS) {
        s += __shfl_xor(s, 16, 64); s += __shfl_xor(s, 32, 64);
        q += __shfl_xor(q, 16, 64); q += __shfl_xor(q, 32, 64);
        if (kq == 0) { ssum[w][n] = s; ssq[w][n] = q; }
      }
    }
    if constexpr (STORE) {
      __syncthreads();
      const uint4* tl = (const uint4*)tile;
#pragma unroll
      for (int u = 0; u < 8; ++u) {
        int idx = u * 256 + tid;
        int rr = idx >> 4, seg = idx & 15;
        if (rbase + rr < R)
          *(uint4*)(outb + (size_t)(rbase + rr) * 128 + seg * 8) = tl[rr * 17 + seg];
      }
    }
    if (STATS) {
      __syncthreads();
      if (tid < 128) {
        float s = ssum[0][tid] + ssum[1][tid] + ssum[2][tid] + ssum[3][tid];
        float q = ssq[0][tid] + ssq[1][tid] + ssq[2][tid] + ssq[3][tid];
        int slot = blockIdx.x & (NSLOT - 1);
        atomicAdd(&statS[slot * 128 + tid], s);
        atomicAdd(&statQ[slot * 128 + tid], q);
      }
    }
  }
}

// ---------------- bn1 stats over virtual t1 (no materialization) + radS ----------------
// per_wave is even and En is even -> every wave's range has even length
__global__ __launch_bounds__(256) void k_stats1(
    const unsigned short* __restrict__ hWr, const unsigned short* __restrict__ hWc,
    const float* __restrict__ coord, const unsigned short* __restrict__ rowS,
    const unsigned short* __restrict__ colS, const float* __restrict__ wlast,
    float* __restrict__ radS, float* __restrict__ statS, float* __restrict__ statQ,
    int per_wave) {
  int tid = threadIdx.x, lane = tid & 63;
  int wid = blockIdx.x * 4 + (tid >> 6);
  int e0 = wid * per_wave;
  int e1 = min(e0 + per_wave, En);
  int c2 = lane * 2;
  float wl0 = wlast[c2], wl1 = wlast[c2 + 1];
  float s0 = 0.f, s1 = 0.f, q0 = 0.f, q1 = 0.f;
  for (int e = e0; e < e1; e += 2) {
    int ra = rowS[e], ca = colS[e];
    int rb = rowS[e + 1], cb = colS[e + 1];
    float ax = coord[ra * 3 + 0] - coord[ca * 3 + 0];
    float ay = coord[ra * 3 + 1] - coord[ca * 3 + 1];
    float az = coord[ra * 3 + 2] - coord[ca * 3 + 2];
    float bx = coord[rb * 3 + 0] - coord[cb * 3 + 0];
    float by = coord[rb * 3 + 1] - coord[cb * 3 + 1];
    float bz = coord[rb * 3 + 2] - coord[cb * 3 + 2];
    float rada = ax * ax + ay * ay + az * az;
    float radb = bx * bx + by * by + bz * bz;
    if (lane == 0) {
      radS[e] = rada;
      radS[e + 1] = radb;
    }
    unsigned int uar = *(const unsigned int*)(hWr + (size_t)ra * 128 + c2);
    unsigned int uac = *(const unsigned int*)(hWc + (size_t)ca * 128 + c2);
    unsigned int ubr = *(const unsigned int*)(hWr + (size_t)rb * 128 + c2);
    unsigned int ubc = *(const unsigned int*)(hWc + (size_t)cb * 128 + c2);
    float va0 = bf2f(uar & 0xFFFFu) + bf2f(uac & 0xFFFFu) + rada * wl0;
    float va1 = bf2f(uar >> 16) + bf2f(uac >> 16) + rada * wl1;
    float vb0 = bf2f(ubr & 0xFFFFu) + bf2f(ubc & 0xFFFFu) + radb * wl0;
    float vb1 = bf2f(ubr >> 16) + bf2f(ubc >> 16) + radb * wl1;
    s0 += va0 + vb0;
    s1 += va1 + vb1;
    q0 = fmaf(va0, va0, q0); q0 = fmaf(vb0, vb0, q0);
    q1 = fmaf(va1, va1, q1); q1 = fmaf(vb1, vb1, q1);
  }
  int slot = wid & (NSLOT - 1);
  atomicAdd(&statS[slot * 128 + c2], s0);
  atomicAdd(&statS[slot * 128 + c2 + 1], s1);
  atomicAdd(&statQ[slot * 128 + c2], q0);
  atomicAdd(&statQ[slot * 128 + c2 + 1], q1);
}

// ---------------- edge layer 2 GEMM, A recomputed from hWr/hWc/radS ----------------
__global__ __launch_bounds__(256) void k_egemm2(
    const unsigned short* __restrict__ hWr, const unsigned short* __restrict__ hWc,
    const float* __restrict__ radS, const unsigned short* __restrict__ rowS,
    const unsigned short* __restrict__ colS, const unsigned short* __restrict__ W,
    const float* __restrict__ bias, const float* __restrict__ wlast,
    const float* __restrict__ bnS1, const float* __restrict__ bnSh1,
    unsigned short* __restrict__ outb, float* __restrict__ statS, float* __restrict__ statQ) {
  constexpr int WST = 136;
  __shared__ __align__(16) unsigned short smem[128 * WST];
  __shared__ float ssum[4][128], ssq[4][128];
  int tid = threadIdx.x;
  int w = tid >> 6, lane = tid & 63, m = lane & 15, kq = lane >> 4;
  int rbase = blockIdx.x * 128;
#pragma unroll
  for (int it = 0; it < 8; ++it) {
    int idx = it * 256 + tid;
    int n = idx >> 4, seg = idx & 15;
    uint4 v = *(const uint4*)(W + (size_t)n * 128 + seg * 8);
    *(uint4*)(smem + n * WST + seg * 8) = v;
  }
  int rc0 = rbase + w * 32 + m, rc1 = rc0 + 16;
  int r0 = rowS[rc0], c0 = colS[rc0];
  int r1 = rowS[rc1], c1 = colS[rc1];
  float rad0 = radS[rc0], rad1 = radS[rc1];
  __syncthreads();
  f32x4 acc[2][8];
#pragma unroll
  for (int rt = 0; rt < 2; ++rt)
#pragma unroll
    for (int c = 0; c < 8; ++c) acc[rt][c] = (f32x4){0.f, 0.f, 0.f, 0.f};
#pragma unroll
  for (int ks = 0; ks < 4; ++ks) {
    int k0 = ks * 32 + kq * 8;
    U8 a0r, a0c, a1r, a1c;
    a0r.u4 = *(const uint4*)(hWr + (size_t)r0 * 128 + k0);
    a0c.u4 = *(const uint4*)(hWc + (size_t)c0 * 128 + k0);
    a1r.u4 = *(const uint4*)(hWr + (size_t)r1 * 128 + k0);
    a1c.u4 = *(const uint4*)(hWc + (size_t)c1 * 128 + k0);
    const float4* wp = (const float4*)(wlast + k0);
    const float4* sp = (const float4*)(bnS1 + k0);
    const float4* hp = (const float4*)(bnSh1 + k0);
    float4 w0 = wp[0], w1 = wp[1], sA = sp[0], sB = sp[1], hA = hp[0], hB = hp[1];
    float wv[8] = {w0.x, w0.y, w0.z, w0.w, w1.x, w1.y, w1.z, w1.w};
    float sv[8] = {sA.x, sA.y, sA.z, sA.w, sB.x, sB.y, sB.z, sB.w};
    float hv[8] = {hA.x, hA.y, hA.z, hA.w, hB.x, hB.y, hB.z, hB.w};
    U8 ua0, ua1;
#pragma unroll
    for (int jj = 0; jj < 4; ++jj) {
      int j0 = 2 * jj, j1 = 2 * jj + 1;
      float v0a = bf2f(a0r.us[j0]) + bf2f(a0c.us[j0]) + rad0 * wv[j0];
      float v0b = bf2f(a0r.us[j1]) + bf2f(a0c.us[j1]) + rad0 * wv[j1];
      float v1a = bf2f(a1r.us[j0]) + bf2f(a1c.us[j0]) + rad1 * wv[j0];
      float v1b = bf2f(a1r.us[j1]) + bf2f(a1c.us[j1]) + rad1 * wv[j1];
      v0a = fmaxf(v0a * sv[j0] + hv[j0], 0.f);
      v0b = fmaxf(v0b * sv[j1] + hv[j1], 0.f);
      v1a = fmaxf(v1a * sv[j0] + hv[j0], 0.f);
      v1b = fmaxf(v1b * sv[j1] + hv[j1], 0.f);
      ua0.ui[jj] = f2bf2(v0a, v0b);
      ua1.ui[jj] = f2bf2(v1a, v1b);
    }
#pragma unroll
    for (int c = 0; c < 8; ++c) {
      U8 ub;
      ub.u4 = *(const uint4*)(smem + (c * 16 + m) * WST + k0);
      acc[0][c] = __builtin_amdgcn_mfma_f32_16x16x32_bf16(ua0.s8, ub.s8, acc[0][c], 0, 0, 0);
      acc[1][c] = __builtin_amdgcn_mfma_f32_16x16x32_bf16(ua1.s8, ub.s8, acc[1][c], 0, 0, 0);
    }
  }
  __syncthreads();
  unsigned short* tile = smem;
#pragma unroll
  for (int c = 0; c < 8; ++c) {
    int n = c * 16 + m;
    float bn_ = bias[n];
    float s = 0.f, q = 0.f;
#pragma unroll
    for (int rt = 0; rt < 2; ++rt)
#pragma unroll
      for (int j = 0; j < 4; ++j) {
        int lr = w * 32 + rt * 16 + kq * 4 + j;
        float v = acc[rt][c][j] + bn_;
        tile[lr * 136 + n] = f2bf(v);
        s += v;
        q = fmaf(v, v, q);
      }
    s += __shfl_xor(s, 16, 64); s += __shfl_xor(s, 32, 64);
    q += __shfl_xor(q, 16, 64); q += __shfl_xor(q, 32, 64);
    if (kq == 0) { ssum[w][n] = s; ssq[w][n] = q; }
  }
  __syncthreads();
  const uint4* tl = (const uint4*)tile;
#pragma unroll
  for (int u = 0; u < 8; ++u) {
    int idx = u * 256 + tid;
    int rr = idx >> 4, seg = idx & 15;
    *(uint4*)(outb + (size_t)(rbase + rr) * 128 + seg * 8) = tl[rr * 17 + seg];
  }
  if (tid < 128) {
    float s = ssum[0][tid] + ssum[1][tid] + ssum[2][tid] + ssum[3][tid];
    float q = ssq[0][tid] + ssq[1][tid] + ssq[2][tid] + ssq[3][tid];
    int slot = blockIdx.x & (NSLOT - 1);
    atomicAdd(&statS[slot * 128 + tid], s);
    atomicAdd(&statQ[slot * 128 + tid], q);
  }
}

// ---------------- node aggregation over contiguous CSR rows (no atomics) ----------------
__global__ __launch_bounds__(256) void k_agg(const unsigned short* __restrict__ t,
                                             const int* __restrict__ start,
                                             const int* __restrict__ cnt,
                                             const float* __restrict__ bnS,
                                             const float* __restrict__ bnSh,
                                             unsigned short* __restrict__ nodeA) {
  int tid = threadIdx.x;
  int lane = tid & 63;
  int n = blockIdx.x * 4 + (tid >> 6);
  if (n >= Nn) return;
  int deg = cnt[n], off = start[n];
  int c2 = lane * 2;
  float s0 = bnS[c2], s1 = bnS[c2 + 1], h0 = bnSh[c2], h1 = bnSh[c2 + 1];
  float a0 = 0.f, a1 = 0.f;
  const unsigned short* p = t + (size_t)off * 128 + c2;
  for (int j = 0; j < deg; ++j) {
    unsigned int u = *(const unsigned int*)(p + (size_t)j * 128);
    a0 += fmaxf(bf2f(u & 0xFFFFu) * s0 + h0, 0.f);
    a1 += fmaxf(bf2f(u >> 16) * s1 + h1, 0.f);
  }
  float inv = 1.f / fmaxf((float)deg, 1.f);
  unsigned int o = (unsigned)f2bf(a0 * inv) | ((unsigned)f2bf(a1 * inv) << 16);
  *(unsigned int*)(nodeA + (size_t)n * 256 + 128 + c2) = o;
}

// ---------------- second-moment of y = relu(bn2(t2)) — coalesced + LDS transpose ----------------
// M = sum_e y y^T (full 128x128), Sy[c] = sum_e y[e][c].
// COALESCED global reads (lane = 16B chunk along a row); transpose into channel-major
// yT[c][e] via swizzled ds_write_b16 (chunk ^= (row>>3)&7); MFMA reads use same swizzle.
__global__ __launch_bounds__(512) void k_moment(
    const unsigned short* __restrict__ t,
    const float* __restrict__ bnS2, const float* __restrict__ bnSh2,
    float* __restrict__ Mpart, float* __restrict__ SyG) {
  constexpr int NT = En / 128;
  __shared__ __align__(16) unsigned short yT[128 * 128];  // channel-major, chunk-XOR swizzled
  __shared__ float s2L[128], h2L[128];
  __shared__ float fred[8][128];
  int tid = threadIdx.x;
  int w = tid >> 6, lane = tid & 63, m = lane & 15, kq = lane >> 4;
  if (tid < 128) { s2L[tid] = bnS2[tid]; h2L[tid] = bnSh2[tid]; }
  __syncthreads();
  int c0 = (tid & 15) * 8;  // channel group this lane transforms
  int erow = tid >> 4;      // 0..31
  float sA[8], hA[8];
#pragma unroll
  for (int j = 0; j < 8; ++j) { sA[j] = s2L[c0 + j]; hA[j] = h2L[c0 + j]; }
  // swizzled write column offsets (in shorts): addr(i,k) = (c0+k)*128 + colOff[i]
  int swz = tid & 7;  // = ((c0+k)>>3)&7 for all k<8
  int colOff[4];
#pragma unroll
  for (int i = 0; i < 4; ++i) {
    int e = i * 32 + erow;
    colOff[i] = (((e >> 3) ^ swz) << 3) + (e & 7);
  }
  int mh = m >> 3;
  f32x4 acc[8];
#pragma unroll
  for (int c = 0; c < 8; ++c) acc[c] = (f32x4){0.f, 0.f, 0.f, 0.f};
  float sy[8];
#pragma unroll
  for (int j = 0; j < 8; ++j) sy[j] = 0.f;
  int tile = blockIdx.x;
  U8 cur[4], nxt[4];
  {
    const unsigned short* p = t + (size_t)tile * 16384 + erow * 128 + c0;
#pragma unroll
    for (int i = 0; i < 4; ++i) cur[i].u4 = *(const uint4*)(p + i * 4096);
  }
  while (tile < NT) {
    int nx = tile + MGRID;
    if (nx < NT) {  // prefetch next tile (coalesced), in flight across barriers+MFMA
      const unsigned short* p = t + (size_t)nx * 16384 + erow * 128 + c0;
#pragma unroll
      for (int i = 0; i < 4; ++i) nxt[i].u4 = *(const uint4*)(p + i * 4096);
    }
    unsigned int pkt[16];
#pragma unroll
    for (int i = 0; i < 4; ++i)
#pragma unroll
      for (int jj = 0; jj < 4; ++jj) {
        float y0 = fmaxf(bf2f(cur[i].us[2 * jj]) * sA[2 * jj] + hA[2 * jj], 0.f);
        float y1 = fmaxf(bf2f(cur[i].us[2 * jj + 1]) * sA[2 * jj + 1] + hA[2 * jj + 1], 0.f);
        sy[2 * jj] += y0;
        sy[2 * jj + 1] += y1;
        pkt[i * 4 + jj] = f2bf2(y0, y1);
      }
    __syncthreads();  // prior MFMA reads of yT done
#pragma unroll
    for (int i = 0; i < 4; ++i)
#pragma unroll
      for (int jj = 0; jj < 4; ++jj) {
        unsigned int v = pkt[i * 4 + jj];
        yT[(c0 + 2 * jj) * 128 + colOff[i]] = (unsigned short)v;
        yT[(c0 + 2 * jj + 1) * 128 + colOff[i]] = (unsigned short)(v >> 16);
      }
    __syncthreads();
#pragma unroll
    for (int ks = 0; ks < 4; ++ks) {
      int ck = ks * 4 + kq;
      U8 a;
      a.u4 = *(const uint4*)(yT + (w * 16 + m) * 128 + ((ck ^ ((2 * w + mh) & 7)) << 3));
#pragma unroll
      for (int c = 0; c < 8; ++c) {
        U8 b;
        b.u4 = *(const uint4*)(yT + (c * 16 + m) * 128 + ((ck ^ ((2 * c + mh) & 7)) << 3));
        acc[c] = __builtin_amdgcn_mfma_f32_16x16x32_bf16(a.s8, b.s8, acc[c], 0, 0, 0);
      }
    }
#pragma unroll
    for (int i = 0; i < 4; ++i) cur[i] = nxt[i];
    tile = nx;
  }
  size_t mb = (size_t)blockIdx.x * 16384;
#pragma unroll
  for (int c = 0; c < 8; ++c)
#pragma unroll
    for (int j = 0; j < 4; ++j)
      Mpart[mb + (size_t)(w * 16 + kq * 4 + j) * 128 + c * 16 + m] = acc[c][j];
  // Sy: reduce the 4 same-channel lanes within wave, then block-reduce via LDS
#pragma unroll
  for (int j = 0; j < 8; ++j) {
    sy[j] += __shfl_xor(sy[j], 16, 64);
    sy[j] += __shfl_xor(sy[j], 32, 64);
  }
  if (lane < 16) {
#pragma unroll
    for (int j = 0; j < 8; ++j) fred[w][lane * 8 + j] = sy[j];
  }
  __syncthreads();
  if (tid < 128) {
    float s = 0.f;
#pragma unroll
    for (int g = 0; g < 8; ++g) s += fred[g][tid];
    atomicAdd(&SyG[tid], s);
  }
}

__global__ __launch_bounds__(256) void k_msum(const float* __restrict__ Mpart,
                                              float* __restrict__ Mg) {
  __shared__ float red[4][64];
  int tid = threadIdx.x;
  int e = blockIdx.x * 64 + (tid & 63);
  int pq = tid >> 6;
  float s = 0.f;
  for (int k = pq * (MGRID / 4); k < (pq + 1) * (MGRID / 4); ++k)
    s += Mpart[(size_t)k * 16384 + e];
  red[pq][tid & 63] = s;
  __syncthreads();
  if (tid < 64) Mg[e] = red[0][tid] + red[1][tid] + red[2][tid] + red[3][tid];
}

// bn3 params from moments: var[c] = (w_c M w_c^T)/E - (w_c . Sy / E)^2  (bias cancels)
// block = channel c; 128 threads each own column j of M.
__global__ __launch_bounds__(128) void k_fin3(
    const float* __restrict__ Mg, const float* __restrict__ Sy,
    const float* __restrict__ w1, const float* __restrict__ g,
    const float* __restrict__ be, float invE,
    float* __restrict__ bnS3, float* __restrict__ bnSh3) {
  __shared__ float sW[128];
  __shared__ float r2[4];
  int c = blockIdx.x, j = threadIdx.x;
  sW[j] = w1[c * 128 + j];
  __syncthreads();
  float a0 = 0.f, a1 = 0.f, a2 = 0.f, a3 = 0.f;
  for (int i = 0; i < 128; i += 4) {
    a0 = fmaf(sW[i], Mg[i * 128 + j], a0);
    a1 = fmaf(sW[i + 1], Mg[(i + 1) * 128 + j], a1);
    a2 = fmaf(sW[i + 2], Mg[(i + 2) * 128 + j], a2);
    a3 = fmaf(sW[i + 3], Mg[(i + 3) * 128 + j], a3);
  }
  float q = sW[j] * ((a0 + a1) + (a2 + a3));
  float dm = sW[j] * Sy[j];
#pragma unroll
  for (int d = 1; d < 64; d <<= 1) {
    q += __shfl_xor(q, d, 64);
    dm += __shfl_xor(dm, d, 64);
  }
  int wv = j >> 6;
  if ((j & 63) == 0) { r2[wv * 2] = q; r2[wv * 2 + 1] = dm; }
  __syncthreads();
  if (j == 0) {
    float quad = r2[0] + r2[2];
    float dmt = r2[1] + r2[3];
    float Eu = dmt * invE;
    float var = fmaxf(quad * invE - Eu * Eu, 0.f);
    float S = g[c] * rsqrtf(var + 1e-5f);
    bnS3[c] = S;
    bnSh3[c] = be[c] - Eu * S;  // GEMM bias c_b1 cancels inside BN
  }
}

// ---------------- coord GEMM with fused bn3+relu+dot(c_w2) epilogue -> scaleE ----------------
__global__ __launch_bounds__(256) void k_cgemm(
    const unsigned short* __restrict__ A,   // t2 [En][128] bf16
    const unsigned short* __restrict__ W,   // c1b bf16 [128][128]
    const float* __restrict__ bnS2, const float* __restrict__ bnSh2,
    const float* __restrict__ bnS3, const float* __restrict__ bnSh3,
    const float* __restrict__ cw2, float* __restrict__ scaleE) {
  constexpr int WST = 136;
  __shared__ __align__(16) unsigned short smem[128 * WST];
  int tid = threadIdx.x;
  int w = tid >> 6, lane = tid & 63, m = lane & 15, kq = lane >> 4;
  int rbase = blockIdx.x * 128;
#pragma unroll
  for (int it = 0; it < 8; ++it) {
    int idx = it * 256 + tid;
    int n = idx >> 4, seg = idx & 15;
    *(uint4*)(smem + n * WST + seg * 8) = *(const uint4*)(W + (size_t)n * 128 + seg * 8);
  }
  __syncthreads();
  int rc0 = rbase + w * 32 + m, rc1 = rc0 + 16;
  f32x4 acc[2][8];
#pragma unroll
  for (int rt = 0; rt < 2; ++rt)
#pragma unroll
    for (int c = 0; c < 8; ++c) acc[rt][c] = (f32x4){0.f, 0.f, 0.f, 0.f};
#pragma unroll
  for (int ks = 0; ks < 4; ++ks) {
    int k0 = ks * 32 + kq * 8;
    U8 ua0, ua1;
    ua0.u4 = *(const uint4*)(A + (size_t)rc0 * 128 + k0);
    ua1.u4 = *(const uint4*)(A + (size_t)rc1 * 128 + k0);
    const float4* sp = (const float4*)(bnS2 + k0);
    const float4* hp = (const float4*)(bnSh2 + k0);
    float4 s0 = sp[0], s1 = sp[1], h0 = hp[0], h1 = hp[1];
    float sv[8] = {s0.x, s0.y, s0.z, s0.w, s1.x, s1.y, s1.z, s1.w};
    float hv[8] = {h0.x, h0.y, h0.z, h0.w, h1.x, h1.y, h1.z, h1.w};
    U8 pa, pb;
#pragma unroll
    for (int jj = 0; jj < 4; ++jj) {
      float v0a = fmaxf(bf2f(ua0.us[2 * jj]) * sv[2 * jj] + hv[2 * jj], 0.f);
      float v0b = fmaxf(bf2f(ua0.us[2 * jj + 1]) * sv[2 * jj + 1] + hv[2 * jj + 1], 0.f);
      float v1a = fmaxf(bf2f(ua1.us[2 * jj]) * sv[2 * jj] + hv[2 * jj], 0.f);
      float v1b = fmaxf(bf2f(ua1.us[2 * jj + 1]) * sv[2 * jj + 1] + hv[2 * jj + 1], 0.f);
      pa.ui[jj] = f2bf2(v0a, v0b);
      pb.ui[jj] = f2bf2(v1a, v1b);
    }
#pragma unroll
    for (int c = 0; c < 8; ++c) {
      U8 ub;
      ub.u4 = *(const uint4*)(smem + (c * 16 + m) * WST + k0);
      acc[0][c] = __builtin_amdgcn_mfma_f32_16x16x32_bf16(pa.s8, ub.s8, acc[0][c], 0, 0, 0);
      acc[1][c] = __builtin_amdgcn_mfma_f32_16x16x32_bf16(pb.s8, ub.s8, acc[1][c], 0, 0, 0);
    }
  }
  // epilogue: scale[e] = sum_n cw2[n] * relu(acc*S3[n] + Sh3[n])
  float s3v[8], h3v[8], wv[8];
#pragma unroll
  for (int c = 0; c < 8; ++c) {
    int n = c * 16 + m;
    s3v[c] = bnS3[n];
    h3v[c] = bnSh3[n];
    wv[c] = cw2[n];
  }
  float p0[4] = {0.f, 0.f, 0.f, 0.f}, p1[4] = {0.f, 0.f, 0.f, 0.f};
#pragma unroll
  for (int c = 0; c < 8; ++c)
#pragma unroll
    for (int j = 0; j < 4; ++j) {
      p0[j] += fmaxf(acc[0][c][j] * s3v[c] + h3v[c], 0.f) * wv[c];
      p1[j] += fmaxf(acc[1][c][j] * s3v[c] + h3v[c], 0.f) * wv[c];
    }
#pragma unroll
  for (int j = 0; j < 4; ++j)
#pragma unroll
    for (int d = 1; d < 16; d <<= 1) {
      p0[j] += __shfl_xor(p0[j], d, 64);
      p1[j] += __shfl_xor(p1[j], d, 64);
    }
  if (m == 0) {
    int r0 = rbase + w * 32 + kq * 4;
    *(float4*)(scaleE + r0) = make_float4(p0[0], p0[1], p0[2], p0[3]);
    *(float4*)(scaleE + r0 + 16) = make_float4(p1[0], p1[1], p1[2], p1[3]);
  }
}

// coord_out: contiguous CSR ranges, coalesced
__global__ __launch_bounds__(256) void k_coord(const float* __restrict__ coord,
                                               const unsigned short* __restrict__ colS,
                                               const int* __restrict__ start,
                                               const int* __restrict__ cnt,
                                               const float* __restrict__ scaleE,
                                               float* __restrict__ cout) {
  int tid = threadIdx.x;
  int lane = tid & 63;
  int n = blockIdx.x * 4 + (tid >> 6);
  if (n >= Nn) return;
  int deg = cnt[n], off = start[n];
  float cx0 = coord[n * 3 + 0], cy0 = coord[n * 3 + 1], cz0 = coord[n * 3 + 2];
  float ax = 0.f, ay = 0.f, az = 0.f;
  for (int j = lane; j < deg; j += 64) {
    int e = off + j;
    int c = colS[e];
    float s = scaleE[e];
    float tx = (cx0 - coord[c * 3 + 0]) * s;
    float ty = (cy0 - coord[c * 3 + 1]) * s;
    float tz = (cz0 - coord[c * 3 + 2]) * s;
    ax += fminf(fmaxf(tx, -100.f), 100.f);
    ay += fminf(fmaxf(ty, -100.f), 100.f);
    az += fminf(fmaxf(tz, -100.f), 100.f);
  }
#pragma unroll
  for (int d = 32; d; d >>= 1) {
    ax += __shfl_xor(ax, d, 64);
    ay += __shfl_xor(ay, d, 64);
    az += __shfl_xor(az, d, 64);
  }
  if (lane == 0) {
    float inv = 1.f / fmaxf((float)deg, 1.f);
    cout[n * 3 + 0] = cx0 + ax * inv;
    cout[n * 3 + 1] = cy0 + ay * inv;
    cout[n * 3 + 2] = cz0 + az * inv;
  }
}

// ---------------- launcher ----------------

extern "C" void kernel_launch(void* const* d_in, const int* in_sizes, int n_in, void* d_out,
                              int out_size, void* d_ws, size_t ws_size, hipStream_t stream) {
  (void)in_sizes; (void)n_in; (void)out_size; (void)ws_size;
  const float* h = (const float*)d_in[0];
  const float* coord = (const float*)d_in[1];
  const int* eidx = (const int*)d_in[2];
  const int* row = eidx;
  const int* col = eidx + En;
  const float* e_w1 = (const float*)d_in[3];
  const float* e_b1 = (const float*)d_in[4];
  const float* e_g1 = (const float*)d_in[5];
  const float* e_be1 = (const float*)d_in[6];
  const float* e_w2 = (const float*)d_in[7];
  const float* e_b2 = (const float*)d_in[8];
  const float* e_g2 = (const float*)d_in[9];
  const float* e_be2 = (const float*)d_in[10];
  const float* n_w1 = (const float*)d_in[11];
  const float* n_b1 = (const float*)d_in[12];
  const float* n_g1 = (const float*)d_in[13];
  const float* n_be1 = (const float*)d_in[14];
  const float* n_w2 = (const float*)d_in[15];
  const float* n_b2 = (const float*)d_in[16];
  const float* c_w1 = (const float*)d_in[17];
  const float* c_b1 = (const float*)d_in[18];
  (void)c_b1;  // bias before BN cancels analytically (k_fin3)
  const float* c_g1 = (const float*)d_in[19];
  const float* c_be1 = (const float*)d_in[20];
  const float* c_w2 = (const float*)d_in[21];

  char* base = (char*)d_ws;
  size_t off = 0;
  auto alloc = [&](size_t bytes) -> void* {
    void* p = base + off;
    off = (off + bytes + 255) & ~(size_t)255;
    return p;
  };
  // Workspace budget: ~260 MB (proven footprint, unchanged — moment buffers aliased).
  unsigned short* t = (unsigned short*)alloc((size_t)En * 128 * 2);      // t2, then t4
  unsigned short* nodeA = (unsigned short*)alloc((size_t)Nn * 256 * 2);  // [h | agg] bf16
  unsigned short* hWr = (unsigned short*)alloc((size_t)Nn * 128 * 2);
  unsigned short* hWc = (unsigned short*)alloc((size_t)Nn * 128 * 2);
  float* scaleE = (float*)alloc((size_t)En * 4);
  float* radS = scaleE;  // alias: radS dead (after k_egemm2) before scaleE written (k_cgemm)
  unsigned short* rowS = (unsigned short*)alloc((size_t)En * 2);
  unsigned short* colS = (unsigned short*)alloc((size_t)En * 2);
  int* cnt = (int*)alloc((size_t)Nn * 4);
  int* startp = (int*)alloc((size_t)Nn * 4);
  int* cursor = (int*)alloc((size_t)Nn * 4);
  float* statS = (float*)alloc(4 * NSLOT * 128 * 4);
  float* statQ = (float*)alloc(4 * NSLOT * 128 * 4);
  float* bnS = (float*)alloc(4 * 128 * 4);
  float* bnSh = (float*)alloc(4 * 128 * 4);
  unsigned short* w1a = (unsigned short*)alloc(128 * 128 * 2);
  unsigned short* w1b = (unsigned short*)alloc(128 * 128 * 2);
  unsigned short* w2b = (unsigned short*)alloc(128 * 128 * 2);
  unsigned short* c1b = (unsigned short*)alloc(128 * 128 * 2);
  unsigned short* n1b = (unsigned short*)alloc(128 * 256 * 2);
  unsigned short* n2b = (unsigned short*)alloc(128 * 128 * 2);
  float* wlast = (float*)alloc(128 * 4);
  // Moment buffers ALIASED into dead regions (no new workspace):
  //  - Mpart (MGRID=384 × 64KB = 25.2 MB) over hWr+hWc (25.6 MB contiguous, dead after k_egemm2)
  //  - Mg (16384 f32) + SyG (128 f32) at head of scaleE region (radS dead after k_egemm2;
  //    scaleE written only later by k_cgemm, after k_fin3 consumed Mg/SyG)
  float* Mpart = (float*)hWr;
  float* Mg = scaleE;
  float* SyG = scaleE + 16384;

  hipMemsetAsync(cnt, 0, (size_t)Nn * 4, stream);
  hipMemsetAsync(statS, 0, 4 * NSLOT * 128 * 4, stream);
  hipMemsetAsync(statQ, 0, 4 * NSLOT * 128 * 4, stream);

  // prep
  k_prep_h<<<(Nn * 128 + 255) / 256, 256, 0, stream>>>(h, nodeA);
  k_prep_w<<<(128 * 128 + 255) / 256, 256, 0, stream>>>(e_w1, w1a, 257, 0, 7, 128 * 128);
  k_prep_w<<<(128 * 128 + 255) / 256, 256, 0, stream>>>(e_w1, w1b, 257, 128, 7, 128 * 128);
  k_prep_w<<<(128 * 128 + 255) / 256, 256, 0, stream>>>(e_w2, w2b, 128, 0, 7, 128 * 128);
  k_prep_w<<<(128 * 128 + 255) / 256, 256, 0, stream>>>(c_w1, c1b, 128, 0, 7, 128 * 128);
  k_prep_w<<<(128 * 256 + 255) / 256, 256, 0, stream>>>(n_w1, n1b, 256, 0, 8, 128 * 256);
  k_prep_w<<<(128 * 128 + 255) / 256, 256, 0, stream>>>(n_w2, n2b, 128, 0, 7, 128 * 128);
  k_wlast<<<1, 128, 0, stream>>>(e_w1, wlast);

  // CSR sort
  k_count<<<En / 256, 256, 0, stream>>>(row, cnt);
  k_scan<<<1, 1024, 0, stream>>>(cnt, startp, cursor, Nn);
  k_fill<<<En / 256, 256, 0, stream>>>(row, col, cursor, rowS, colS);

  // hW partial GEMMs (bias e_b1 folded into hWr)
  const int gridN = (Nn + 127) / 128;
  k_gemmW<4, false, false, false, true><<<gridN, 256, 0, stream>>>(
      nodeA, 256, w1a, e_b1, nullptr, nullptr, hWr, nullptr, nullptr, nullptr, nullptr, Nn);
  k_gemmW<4, false, false, false, true><<<gridN, 256, 0, stream>>>(
      nodeA, 256, w1b, nullptr, nullptr, nullptr, hWc, nullptr, nullptr, nullptr, nullptr, Nn);

  // bn1 stats over virtual t1 + radS (per_wave even for the 2-edge unroll)
  const int per_wave = ((En / 2 + 5119) / 5120) * 2;  // 1280 blocks * 4 waves
  k_stats1<<<1280, 256, 0, stream>>>(hWr, hWc, coord, rowS, colS, wlast, radS,
                                     statS + 0 * NSLOT * 128, statQ + 0 * NSLOT * 128, per_wave);
  k_fin<<<1, 128, 0, stream>>>(statS + 0 * NSLOT * 128, statQ + 0 * NSLOT * 128, e_g1, e_be1,
                               1.f / En, bnS + 0, bnSh + 0);

  // edge layer 2: t2 + bn2 stats (slot 1) — last use of hWr/hWc/radS
  k_egemm2<<<En / 128, 256, 0, stream>>>(hWr, hWc, radS, rowS, colS, w2b, e_b2, wlast, bnS + 0,
                                         bnSh + 0, t, statS + 1 * NSLOT * 128,
                                         statQ + 1 * NSLOT * 128);
  k_fin<<<1, 128, 0, stream>>>(statS + 1 * NSLOT * 128, statQ + 1 * NSLOT * 128, e_g2, e_be2,
                               1.f / En, bnS + 128, bnSh + 128);

  // node aggregation from contiguous t2 rows (no atomics)
  k_agg<<<(Nn + 3) / 4, 256, 0, stream>>>(t, startp, cnt, bnS + 128, bnSh + 128, nodeA);

  // bn3 stats WITHOUT materializing t3: second moment of y = relu(bn2(t2))
  hipMemsetAsync(SyG, 0, 128 * 4, stream);  // after radS is dead, before k_moment
  k_moment<<<MGRID, 512, 0, stream>>>(t, bnS + 128, bnSh + 128, Mpart, SyG);
  k_msum<<<256, 256, 0, stream>>>(Mpart, Mg);
  k_fin3<<<128, 128, 0, stream>>>(Mg, SyG, c_w1, c_g1, c_be1, 1.f / En, bnS + 256, bnSh + 256);

  // coord GEMM with fused bn3+relu+c_w2 epilogue -> per-edge scale (no t3 store, no scale pass)
  k_cgemm<<<En / 128, 256, 0, stream>>>(t, c1b, bnS + 128, bnSh + 128, bnS + 256, bnSh + 256,
                                        c_w2, scaleE);

  float* hout = (float*)d_out;
  float* cout = hout + (size_t)Nn * 128;
  k_coord<<<(Nn + 3) / 4, 256, 0, stream>>>(coord, colS, startp, cnt, scaleE, cout);

  // node MLP: l1 (stats slot 3) -> t4 in t (t2 dead after k_cgemm); l2 fp32 out
  k_gemmW<8, false, true, false, true><<<gridN, 256, 0, stream>>>(
      nodeA, 256, n1b, n_b1, nullptr, nullptr, t, statS + 3 * NSLOT * 128,
      statQ + 3 * NSLOT * 128, nullptr, nullptr, Nn);
  k_fin<<<1, 128, 0, stream>>>(statS + 3 * NSLOT * 128, statQ + 3 * NSLOT * 128, n_g1, n_be1,
                               1.f / Nn, bnS + 384, bnSh + 384);
  k_gemmW<4, true, false, true, true><<<gridN, 256, 0, stream>>>(
      t, 128, n2b, n_b2, bnS + 384, bnSh + 384, nullptr, nullptr, nullptr, h, hout, Nn);
}

// Round 12
// 829.507 us; speedup vs baseline: 1.1063x; 1.0658x over previous
//
#include <hip/hip_runtime.h>

#define Nn 50000
#define En 800000
#define NSLOT 64
#define MGRID 384

typedef __attribute__((ext_vector_type(8))) short short8;
typedef __attribute__((ext_vector_type(4))) float f32x4;

union U8 { uint4 u4; unsigned short us[8]; unsigned int ui[4]; short8 s8; };

static __device__ __forceinline__ float bf2f(unsigned int lo16) {
  return __uint_as_float(lo16 << 16);
}
static __device__ __forceinline__ unsigned short f2bf(float f) {
  unsigned int x = __float_as_uint(f);
  return (unsigned short)((x + 0x7FFFu + ((x >> 16) & 1u)) >> 16);
}
// packed RNE f32x2 -> bf16x2 (lo = a, hi = b) via hardware cvt (gfx950)
static __device__ __forceinline__ unsigned int f2bf2(float a, float b) {
  unsigned int r;
  asm("v_cvt_pk_bf16_f32 %0, %1, %2" : "=v"(r) : "v"(a), "v"(b));
  return r;
}

// ---------------- prep kernels ----------------

__global__ __launch_bounds__(256) void k_prep_h(const float* __restrict__ h,
                                                unsigned short* __restrict__ nodeA) {
  int idx = blockIdx.x * 256 + threadIdx.x;
  if (idx >= Nn * 128) return;
  int n = idx >> 7, k = idx & 127;
  nodeA[(size_t)n * 256 + k] = f2bf(h[idx]);
}

// weight fp32 [128][Ksrc] cols [koff, koff+2^kshift) -> bf16 [128][2^kshift]
__global__ __launch_bounds__(256) void k_prep_w(const float* __restrict__ src,
                                                unsigned short* __restrict__ dst, int Ksrc,
                                                int koff, int kshift, int total) {
  int idx = blockIdx.x * 256 + threadIdx.x;
  if (idx >= total) return;
  int n = idx >> kshift;
  int k = idx & ((1 << kshift) - 1);
  dst[idx] = f2bf(src[n * Ksrc + koff + k]);
}

__global__ void k_wlast(const float* __restrict__ e_w1, float* __restrict__ wlast) {
  int t = threadIdx.x;
  if (t < 128) wlast[t] = e_w1[t * 257 + 256];
}

// ---------------- CSR build (edges sorted by row; node ids fit u16) ----------------

__global__ __launch_bounds__(256) void k_count(const int* __restrict__ row, int* __restrict__ cnt) {
  int e = blockIdx.x * 256 + threadIdx.x;
  atomicAdd(&cnt[row[e]], 1);
}

__global__ __launch_bounds__(256) void k_fill(const int* __restrict__ row,
                                              const int* __restrict__ col,
                                              int* __restrict__ cursor,
                                              unsigned short* __restrict__ rowS,
                                              unsigned short* __restrict__ colS) {
  int e = blockIdx.x * 256 + threadIdx.x;
  int r = row[e];
  int pos = atomicAdd(&cursor[r], 1);
  rowS[pos] = (unsigned short)r;
  colS[pos] = (unsigned short)col[e];
}

__global__ __launch_bounds__(1024) void k_scan(const int* __restrict__ cnt, int* __restrict__ start,
                                               int* __restrict__ cursor, int n) {
  __shared__ int wsum[16];
  __shared__ int carry;
  int tid = threadIdx.x, lane = tid & 63, wid = tid >> 6;
  if (tid == 0) carry = 0;
  __syncthreads();
  for (int base = 0; base < n; base += 1024) {
    int i = base + tid;
    int v = (i < n) ? cnt[i] : 0;
    int x = v;
#pragma unroll
    for (int d = 1; d < 64; d <<= 1) {
      int y = __shfl_up(x, d, 64);
      if (lane >= d) x += y;
    }
    if (lane == 63) wsum[wid] = x;
    __syncthreads();
    if (wid == 0) {
      int s = (lane < 16) ? wsum[lane] : 0;
#pragma unroll
      for (int d = 1; d < 16; d <<= 1) {
        int y = __shfl_up(s, d, 64);
        if (lane >= d) s += y;
      }
      if (lane < 16) wsum[lane] = s;
    }
    __syncthreads();
    int c0 = carry;
    int waveoff = (wid > 0) ? wsum[wid - 1] : 0;
    int incl = c0 + waveoff + x;
    if (i < n) {
      start[i] = incl - v;
      cursor[i] = incl - v;
    }
    __syncthreads();
    if (tid == 1023) carry = incl;
    __syncthreads();
  }
}

// ---------------- BN finalize ----------------

__global__ void k_fin(const float* __restrict__ statS, const float* __restrict__ statQ,
                      const float* __restrict__ g, const float* __restrict__ be, float invR,
                      float* __restrict__ bnS, float* __restrict__ bnSh) {
  int c = threadIdx.x;
  if (c >= 128) return;
  float s = 0.f, q = 0.f;
  for (int k = 0; k < NSLOT; ++k) {
    s += statS[k * 128 + c];
    q += statQ[k * 128 + c];
  }
  float mean = s * invR;
  float var = fmaxf(q * invR - mean * mean, 0.f);
  float rs = rsqrtf(var + 1e-5f);
  float sc = g[c] * rs;
  bnS[c] = sc;
  bnSh[c] = be[c] - mean * sc;
}

// ---------------- generic MFMA GEMM with W in LDS ----------------
template <int KSTEPS, bool BN_A, bool STATS, bool FP32OUT, bool STORE>
__global__ __launch_bounds__(256) void k_gemmW(
    const unsigned short* __restrict__ A, int Astride,
    const unsigned short* __restrict__ W, const float* __restrict__ bias,
    const float* __restrict__ bnS, const float* __restrict__ bnSh,
    unsigned short* __restrict__ outb, float* __restrict__ statS, float* __restrict__ statQ,
    const float* __restrict__ hres, float* __restrict__ outf, int R) {
  constexpr int K = KSTEPS * 32;
  constexpr int WST = K + 8;
  constexpr int SEGS = K / 8;
  __shared__ __align__(16) unsigned short smem[128 * WST];
  __shared__ float ssum[4][128], ssq[4][128];
  int tid = threadIdx.x;
  int w = tid >> 6, lane = tid & 63, m = lane & 15, kq = lane >> 4;
  int rbase = blockIdx.x * 128;
#pragma unroll
  for (int it = 0; it < SEGS / 2; ++it) {
    int idx = it * 256 + tid;
    int n = idx / SEGS, seg = idx % SEGS;
    uint4 v = *(const uint4*)(W + (size_t)n * K + seg * 8);
    *(uint4*)(smem + n * WST + seg * 8) = v;
  }
  __syncthreads();
  int row0 = rbase + w * 32 + m;
  int rc0 = min(row0, R - 1);
  int rc1 = min(row0 + 16, R - 1);
  f32x4 acc[2][8];
#pragma unroll
  for (int rt = 0; rt < 2; ++rt)
#pragma unroll
    for (int c = 0; c < 8; ++c) acc[rt][c] = (f32x4){0.f, 0.f, 0.f, 0.f};
#pragma unroll
  for (int ks = 0; ks < KSTEPS; ++ks) {
    int k0 = ks * 32 + kq * 8;
    U8 ua0, ua1;
    ua0.u4 = *(const uint4*)(A + (size_t)rc0 * Astride + k0);
    ua1.u4 = *(const uint4*)(A + (size_t)rc1 * Astride + k0);
    if (BN_A) {
      const float4* sp = (const float4*)(bnS + k0);
      const float4* hp = (const float4*)(bnSh + k0);
      float4 s0 = sp[0], s1 = sp[1], h0 = hp[0], h1 = hp[1];
      float sv[8] = {s0.x, s0.y, s0.z, s0.w, s1.x, s1.y, s1.z, s1.w};
      float hv[8] = {h0.x, h0.y, h0.z, h0.w, h1.x, h1.y, h1.z, h1.w};
      U8 pa, pb;
#pragma unroll
      for (int jj = 0; jj < 4; ++jj) {
        float a0 = fmaxf(bf2f(ua0.us[2 * jj]) * sv[2 * jj] + hv[2 * jj], 0.f);
        float a1 = fmaxf(bf2f(ua0.us[2 * jj + 1]) * sv[2 * jj + 1] + hv[2 * jj + 1], 0.f);
        float b0 = fmaxf(bf2f(ua1.us[2 * jj]) * sv[2 * jj] + hv[2 * jj], 0.f);
        float b1 = fmaxf(bf2f(ua1.us[2 * jj + 1]) * sv[2 * jj + 1] + hv[2 * jj + 1], 0.f);
        pa.ui[jj] = f2bf2(a0, a1);
        pb.ui[jj] = f2bf2(b0, b1);
      }
      ua0 = pa;
      ua1 = pb;
    }
#pragma unroll
    for (int c = 0; c < 8; ++c) {
      U8 ub;
      ub.u4 = *(const uint4*)(smem + (c * 16 + m) * WST + k0);
      acc[0][c] = __builtin_amdgcn_mfma_f32_16x16x32_bf16(ua0.s8, ub.s8, acc[0][c], 0, 0, 0);
      acc[1][c] = __builtin_amdgcn_mfma_f32_16x16x32_bf16(ua1.s8, ub.s8, acc[1][c], 0, 0, 0);
    }
  }
  if constexpr (FP32OUT) {
#pragma unroll
    for (int rt = 0; rt < 2; ++rt)
#pragma unroll
      for (int c = 0; c < 8; ++c) {
        int n = c * 16 + m;
        float bn_ = bias[n];
#pragma unroll
        for (int j = 0; j < 4; ++j) {
          int rr = rbase + w * 32 + rt * 16 + kq * 4 + j;
          if (rr < R) {
            size_t o = (size_t)rr * 128 + n;
            outf[o] = acc[rt][c][j] + bn_ + hres[o];
          }
        }
      }
  } else {
    if constexpr (STORE) __syncthreads();
    unsigned short* tile = smem;  // reuse as [128][136]
#pragma unroll
    for (int c = 0; c < 8; ++c) {
      int n = c * 16 + m;
      float bn_ = bias ? bias[n] : 0.f;
      float s = 0.f, q = 0.f;
#pragma unroll
      for (int rt = 0; rt < 2; ++rt)
#pragma unroll
        for (int j = 0; j < 4; ++j) {
          int lr = w * 32 + rt * 16 + kq * 4 + j;
          float v = acc[rt][c][j] + bn_;
          if (STORE) tile[lr * 136 + n] = f2bf(v);
          if (STATS) {
            float sv = (rbase + lr < R) ? v : 0.f;
            s += sv;
            q = fmaf(sv, sv, q);
          }
        }
      if (STATS) {
        s += __shfl_xor(s, 16, 64); s += __shfl_xor(s, 32, 64);
        q += __shfl_xor(q, 16, 64); q += __shfl_xor(q, 32, 64);
        if (kq == 0) { ssum[w][n] = s; ssq[w][n] = q; }
      }
    }
    if constexpr (STORE) {
      __syncthreads();
      const uint4* tl = (const uint4*)tile;
#pragma unroll
      for (int u = 0; u < 8; ++u) {
        int idx = u * 256 + tid;
        int rr = idx >> 4, seg = idx & 15;
        if (rbase + rr < R)
          *(uint4*)(outb + (size_t)(rbase + rr) * 128 + seg * 8) = tl[rr * 17 + seg];
      }
    }
    if (STATS) {
      __syncthreads();
      if (tid < 128) {
        float s = ssum[0][tid] + ssum[1][tid] + ssum[2][tid] + ssum[3][tid];
        float q = ssq[0][tid] + ssq[1][tid] + ssq[2][tid] + ssq[3][tid];
        int slot = blockIdx.x & (NSLOT - 1);
        atomicAdd(&statS[slot * 128 + tid], s);
        atomicAdd(&statQ[slot * 128 + tid], q);
      }
    }
  }
}

// ---------------- bn1 stats over virtual t1 (no materialization) + radS ----------------
// per_wave is even and En is even -> every wave's range has even length
__global__ __launch_bounds__(256) void k_stats1(
    const unsigned short* __restrict__ hWr, const unsigned short* __restrict__ hWc,
    const float* __restrict__ coord, const unsigned short* __restrict__ rowS,
    const unsigned short* __restrict__ colS, const float* __restrict__ wlast,
    float* __restrict__ radS, float* __restrict__ statS, float* __restrict__ statQ,
    int per_wave) {
  int tid = threadIdx.x, lane = tid & 63;
  int wid = blockIdx.x * 4 + (tid >> 6);
  int e0 = wid * per_wave;
  int e1 = min(e0 + per_wave, En);
  int c2 = lane * 2;
  float wl0 = wlast[c2], wl1 = wlast[c2 + 1];
  float s0 = 0.f, s1 = 0.f, q0 = 0.f, q1 = 0.f;
  for (int e = e0; e < e1; e += 2) {
    int ra = rowS[e], ca = colS[e];
    int rb = rowS[e + 1], cb = colS[e + 1];
    float ax = coord[ra * 3 + 0] - coord[ca * 3 + 0];
    float ay = coord[ra * 3 + 1] - coord[ca * 3 + 1];
    float az = coord[ra * 3 + 2] - coord[ca * 3 + 2];
    float bx = coord[rb * 3 + 0] - coord[cb * 3 + 0];
    float by = coord[rb * 3 + 1] - coord[cb * 3 + 1];
    float bz = coord[rb * 3 + 2] - coord[cb * 3 + 2];
    float rada = ax * ax + ay * ay + az * az;
    float radb = bx * bx + by * by + bz * bz;
    if (lane == 0) {
      radS[e] = rada;
      radS[e + 1] = radb;
    }
    unsigned int uar = *(const unsigned int*)(hWr + (size_t)ra * 128 + c2);
    unsigned int uac = *(const unsigned int*)(hWc + (size_t)ca * 128 + c2);
    unsigned int ubr = *(const unsigned int*)(hWr + (size_t)rb * 128 + c2);
    unsigned int ubc = *(const unsigned int*)(hWc + (size_t)cb * 128 + c2);
    float va0 = bf2f(uar & 0xFFFFu) + bf2f(uac & 0xFFFFu) + rada * wl0;
    float va1 = bf2f(uar >> 16) + bf2f(uac >> 16) + rada * wl1;
    float vb0 = bf2f(ubr & 0xFFFFu) + bf2f(ubc & 0xFFFFu) + radb * wl0;
    float vb1 = bf2f(ubr >> 16) + bf2f(ubc >> 16) + radb * wl1;
    s0 += va0 + vb0;
    s1 += va1 + vb1;
    q0 = fmaf(va0, va0, q0); q0 = fmaf(vb0, vb0, q0);
    q1 = fmaf(va1, va1, q1); q1 = fmaf(vb1, vb1, q1);
  }
  int slot = wid & (NSLOT - 1);
  atomicAdd(&statS[slot * 128 + c2], s0);
  atomicAdd(&statS[slot * 128 + c2 + 1], s1);
  atomicAdd(&statQ[slot * 128 + c2], q0);
  atomicAdd(&statQ[slot * 128 + c2 + 1], q1);
}

// ---------------- edge layer 2 GEMM, A recomputed from hWr/hWc/radS ----------------
__global__ __launch_bounds__(256) void k_egemm2(
    const unsigned short* __restrict__ hWr, const unsigned short* __restrict__ hWc,
    const float* __restrict__ radS, const unsigned short* __restrict__ rowS,
    const unsigned short* __restrict__ colS, const unsigned short* __restrict__ W,
    const float* __restrict__ bias, const float* __restrict__ wlast,
    const float* __restrict__ bnS1, const float* __restrict__ bnSh1,
    unsigned short* __restrict__ outb, float* __restrict__ statS, float* __restrict__ statQ) {
  constexpr int WST = 136;
  __shared__ __align__(16) unsigned short smem[128 * WST];
  __shared__ float ssum[4][128], ssq[4][128];
  int tid = threadIdx.x;
  int w = tid >> 6, lane = tid & 63, m = lane & 15, kq = lane >> 4;
  int rbase = blockIdx.x * 128;
#pragma unroll
  for (int it = 0; it < 8; ++it) {
    int idx = it * 256 + tid;
    int n = idx >> 4, seg = idx & 15;
    uint4 v = *(const uint4*)(W + (size_t)n * 128 + seg * 8);
    *(uint4*)(smem + n * WST + seg * 8) = v;
  }
  int rc0 = rbase + w * 32 + m, rc1 = rc0 + 16;
  int r0 = rowS[rc0], c0 = colS[rc0];
  int r1 = rowS[rc1], c1 = colS[rc1];
  float rad0 = radS[rc0], rad1 = radS[rc1];
  __syncthreads();
  f32x4 acc[2][8];
#pragma unroll
  for (int rt = 0; rt < 2; ++rt)
#pragma unroll
    for (int c = 0; c < 8; ++c) acc[rt][c] = (f32x4){0.f, 0.f, 0.f, 0.f};
#pragma unroll
  for (int ks = 0; ks < 4; ++ks) {
    int k0 = ks * 32 + kq * 8;
    U8 a0r, a0c, a1r, a1c;
    a0r.u4 = *(const uint4*)(hWr + (size_t)r0 * 128 + k0);
    a0c.u4 = *(const uint4*)(hWc + (size_t)c0 * 128 + k0);
    a1r.u4 = *(const uint4*)(hWr + (size_t)r1 * 128 + k0);
    a1c.u4 = *(const uint4*)(hWc + (size_t)c1 * 128 + k0);
    const float4* wp = (const float4*)(wlast + k0);
    const float4* sp = (const float4*)(bnS1 + k0);
    const float4* hp = (const float4*)(bnSh1 + k0);
    float4 w0 = wp[0], w1 = wp[1], sA = sp[0], sB = sp[1], hA = hp[0], hB = hp[1];
    float wv[8] = {w0.x, w0.y, w0.z, w0.w, w1.x, w1.y, w1.z, w1.w};
    float sv[8] = {sA.x, sA.y, sA.z, sA.w, sB.x, sB.y, sB.z, sB.w};
    float hv[8] = {hA.x, hA.y, hA.z, hA.w, hB.x, hB.y, hB.z, hB.w};
    U8 ua0, ua1;
#pragma unroll
    for (int jj = 0; jj < 4; ++jj) {
      int j0 = 2 * jj, j1 = 2 * jj + 1;
      float v0a = bf2f(a0r.us[j0]) + bf2f(a0c.us[j0]) + rad0 * wv[j0];
      float v0b = bf2f(a0r.us[j1]) + bf2f(a0c.us[j1]) + rad0 * wv[j1];
      float v1a = bf2f(a1r.us[j0]) + bf2f(a1c.us[j0]) + rad1 * wv[j0];
      float v1b = bf2f(a1r.us[j1]) + bf2f(a1c.us[j1]) + rad1 * wv[j1];
      v0a = fmaxf(v0a * sv[j0] + hv[j0], 0.f);
      v0b = fmaxf(v0b * sv[j1] + hv[j1], 0.f);
      v1a = fmaxf(v1a * sv[j0] + hv[j0], 0.f);
      v1b = fmaxf(v1b * sv[j1] + hv[j1], 0.f);
      ua0.ui[jj] = f2bf2(v0a, v0b);
      ua1.ui[jj] = f2bf2(v1a, v1b);
    }
#pragma unroll
    for (int c = 0; c < 8; ++c) {
      U8 ub;
      ub.u4 = *(const uint4*)(smem + (c * 16 + m) * WST + k0);
      acc[0][c] = __builtin_amdgcn_mfma_f32_16x16x32_bf16(ua0.s8, ub.s8, acc[0][c], 0, 0, 0);
      acc[1][c] = __builtin_amdgcn_mfma_f32_16x16x32_bf16(ua1.s8, ub.s8, acc[1][c], 0, 0, 0);
    }
  }
  __syncthreads();
  unsigned short* tile = smem;
#pragma unroll
  for (int c = 0; c < 8; ++c) {
    int n = c * 16 + m;
    float bn_ = bias[n];
    float s = 0.f, q = 0.f;
#pragma unroll
    for (int rt = 0; rt < 2; ++rt)
#pragma unroll
      for (int j = 0; j < 4; ++j) {
        int lr = w * 32 + rt * 16 + kq * 4 + j;
        float v = acc[rt][c][j] + bn_;
        tile[lr * 136 + n] = f2bf(v);
        s += v;
        q = fmaf(v, v, q);
      }
    s += __shfl_xor(s, 16, 64); s += __shfl_xor(s, 32, 64);
    q += __shfl_xor(q, 16, 64); q += __shfl_xor(q, 32, 64);
    if (kq == 0) { ssum[w][n] = s; ssq[w][n] = q; }
  }
  __syncthreads();
  const uint4* tl = (const uint4*)tile;
#pragma unroll
  for (int u = 0; u < 8; ++u) {
    int idx = u * 256 + tid;
    int rr = idx >> 4, seg = idx & 15;
    *(uint4*)(outb + (size_t)(rbase + rr) * 128 + seg * 8) = tl[rr * 17 + seg];
  }
  if (tid < 128) {
    float s = ssum[0][tid] + ssum[1][tid] + ssum[2][tid] + ssum[3][tid];
    float q = ssq[0][tid] + ssq[1][tid] + ssq[2][tid] + ssq[3][tid];
    int slot = blockIdx.x & (NSLOT - 1);
    atomicAdd(&statS[slot * 128 + tid], s);
    atomicAdd(&statQ[slot * 128 + tid], q);
  }
}

// ---------------- node aggregation over contiguous CSR rows (no atomics) ----------------
__global__ __launch_bounds__(256) void k_agg(const unsigned short* __restrict__ t,
                                             const int* __restrict__ start,
                                             const int* __restrict__ cnt,
                                             const float* __restrict__ bnS,
                                             const float* __restrict__ bnSh,
                                             unsigned short* __restrict__ nodeA) {
  int tid = threadIdx.x;
  int lane = tid & 63;
  int n = blockIdx.x * 4 + (tid >> 6);
  if (n >= Nn) return;
  int deg = cnt[n], off = start[n];
  int c2 = lane * 2;
  float s0 = bnS[c2], s1 = bnS[c2 + 1], h0 = bnSh[c2], h1 = bnSh[c2 + 1];
  float a0 = 0.f, a1 = 0.f;
  const unsigned short* p = t + (size_t)off * 128 + c2;
  for (int j = 0; j < deg; ++j) {
    unsigned int u = *(const unsigned int*)(p + (size_t)j * 128);
    a0 += fmaxf(bf2f(u & 0xFFFFu) * s0 + h0, 0.f);
    a1 += fmaxf(bf2f(u >> 16) * s1 + h1, 0.f);
  }
  float inv = 1.f / fmaxf((float)deg, 1.f);
  unsigned int o = (unsigned)f2bf(a0 * inv) | ((unsigned)f2bf(a1 * inv) << 16);
  *(unsigned int*)(nodeA + (size_t)n * 256 + 128 + c2) = o;
}

// ---------------- second-moment of y = relu(bn2(t2)) — adjacent-edge b64 transpose ----------------
// M = sum_e y y^T, Sy[c] = sum_e y[e][c].  Lane owns 4 ADJACENT edges (e0..e0+3) × 8 channels.
// LDS channel-major yT[c][e'] with e' = e ^ (s(c)<<3), s(c) = (2*(c>>4) + 4*((c>>3)&1)) & 7.
// b64 writes and b128 fragment reads are both bank-OPTIMAL under this swizzle (derived).
// M = Y^T Y: A-fragment == B-fragment layout (lane holds Y[k][m-col]) so one load serves both.
__global__ __launch_bounds__(512) void k_moment(
    const unsigned short* __restrict__ t,
    const float* __restrict__ bnS2, const float* __restrict__ bnSh2,
    float* __restrict__ Mpart, float* __restrict__ SyG) {
  constexpr int NT = En / 128;
  __shared__ __align__(16) unsigned short yT[128 * 128];
  __shared__ float s2L[128], h2L[128];
  __shared__ float fred[8][128];
  int tid = threadIdx.x;
  int w = tid >> 6, lane = tid & 63, m = lane & 15, kq = lane >> 4;
  if (tid < 128) { s2L[tid] = bnS2[tid]; h2L[tid] = bnSh2[tid]; }
  __syncthreads();
  int p = tid & 15;
  int erow = tid >> 4;       // 0..31
  int c0 = p * 8;            // 8 contiguous channels
  int e0 = erow * 4;         // 4 adjacent edges
  float sA[8], hA[8];
#pragma unroll
  for (int j = 0; j < 8; ++j) { sA[j] = s2L[c0 + j]; hA[j] = h2L[c0 + j]; }
  // write swizzle: s(c) same for all 8 channels of this lane (c>>3 == p, c>>4 == p>>1)
  int sw = (2 * (p >> 1) + 4 * (p & 1)) & 7;
  int wcol = e0 ^ (sw << 3);  // multiple of 4 shorts -> 8B aligned b64 writes
  int m3 = m >> 3;
  f32x4 acc[8];
#pragma unroll
  for (int c = 0; c < 8; ++c) acc[c] = (f32x4){0.f, 0.f, 0.f, 0.f};
  float sy[8];
#pragma unroll
  for (int j = 0; j < 8; ++j) sy[j] = 0.f;
  int tile = blockIdx.x;
  U8 cur[4], nxt[4];
  {
    const unsigned short* pp = t + (size_t)tile * 16384 + (size_t)e0 * 128 + c0;
#pragma unroll
    for (int i = 0; i < 4; ++i) cur[i].u4 = *(const uint4*)(pp + i * 128);
  }
  while (tile < NT) {
    int nx = tile + MGRID;
    if (nx < NT) {  // prefetch next tile (coalesced), in flight across barriers+MFMA
      const unsigned short* pp = t + (size_t)nx * 16384 + (size_t)e0 * 128 + c0;
#pragma unroll
      for (int i = 0; i < 4; ++i) nxt[i].u4 = *(const uint4*)(pp + i * 128);
    }
    unsigned int plo[8], phi[8];
#pragma unroll
    for (int j = 0; j < 8; ++j) {
      float y0 = fmaxf(bf2f(cur[0].us[j]) * sA[j] + hA[j], 0.f);
      float y1 = fmaxf(bf2f(cur[1].us[j]) * sA[j] + hA[j], 0.f);
      float y2 = fmaxf(bf2f(cur[2].us[j]) * sA[j] + hA[j], 0.f);
      float y3 = fmaxf(bf2f(cur[3].us[j]) * sA[j] + hA[j], 0.f);
      sy[j] += (y0 + y1) + (y2 + y3);
      plo[j] = f2bf2(y0, y1);
      phi[j] = f2bf2(y2, y3);
    }
    __syncthreads();  // prior MFMA reads of yT done
#pragma unroll
    for (int j = 0; j < 8; ++j) {
      uint2 v;
      v.x = plo[j];
      v.y = phi[j];
      *(uint2*)(yT + (c0 + j) * 128 + wcol) = v;
    }
    __syncthreads();
#pragma unroll
    for (int ks = 0; ks < 4; ++ks) {
      int eb = ks * 32 + kq * 8;
      U8 fa;
      {
        int s = (2 * w + 4 * m3) & 7;
        fa.u4 = *(const uint4*)(yT + (w * 16 + m) * 128 + (eb ^ (s << 3)));
      }
#pragma unroll
      for (int cb = 0; cb < 8; ++cb) {
        int s = (2 * cb + 4 * m3) & 7;
        U8 fb;
        fb.u4 = *(const uint4*)(yT + (cb * 16 + m) * 128 + (eb ^ (s << 3)));
        acc[cb] = __builtin_amdgcn_mfma_f32_16x16x32_bf16(fa.s8, fb.s8, acc[cb], 0, 0, 0);
      }
    }
#pragma unroll
    for (int i = 0; i < 4; ++i) cur[i] = nxt[i];
    tile = nx;
  }
  size_t mb = (size_t)blockIdx.x * 16384;
#pragma unroll
  for (int c = 0; c < 8; ++c)
#pragma unroll
    for (int j = 0; j < 4; ++j)
      Mpart[mb + (size_t)(w * 16 + kq * 4 + j) * 128 + c * 16 + m] = acc[c][j];
  // Sy: reduce the 4 same-channel lanes within wave, then block-reduce via LDS
#pragma unroll
  for (int j = 0; j < 8; ++j) {
    sy[j] += __shfl_xor(sy[j], 16, 64);
    sy[j] += __shfl_xor(sy[j], 32, 64);
  }
  if (lane < 16) {
#pragma unroll
    for (int j = 0; j < 8; ++j) fred[w][lane * 8 + j] = sy[j];
  }
  __syncthreads();
  if (tid < 128) {
    float s = 0.f;
#pragma unroll
    for (int g = 0; g < 8; ++g) s += fred[g][tid];
    atomicAdd(&SyG[tid], s);
  }
}

__global__ __launch_bounds__(256) void k_msum(const float* __restrict__ Mpart,
                                              float* __restrict__ Mg) {
  __shared__ float red[4][64];
  int tid = threadIdx.x;
  int e = blockIdx.x * 64 + (tid & 63);
  int pq = tid >> 6;
  float s = 0.f;
  for (int k = pq * (MGRID / 4); k < (pq + 1) * (MGRID / 4); ++k)
    s += Mpart[(size_t)k * 16384 + e];
  red[pq][tid & 63] = s;
  __syncthreads();
  if (tid < 64) Mg[e] = red[0][tid] + red[1][tid] + red[2][tid] + red[3][tid];
}

// bn3 params from moments: var[c] = (w_c M w_c^T)/E - (w_c . Sy / E)^2  (bias cancels)
// block = channel c; 128 threads each own column j of M.
__global__ __launch_bounds__(128) void k_fin3(
    const float* __restrict__ Mg, const float* __restrict__ Sy,
    const float* __restrict__ w1, const float* __restrict__ g,
    const float* __restrict__ be, float invE,
    float* __restrict__ bnS3, float* __restrict__ bnSh3) {
  __shared__ float sW[128];
  __shared__ float r2[4];
  int c = blockIdx.x, j = threadIdx.x;
  sW[j] = w1[c * 128 + j];
  __syncthreads();
  float a0 = 0.f, a1 = 0.f, a2 = 0.f, a3 = 0.f;
  for (int i = 0; i < 128; i += 4) {
    a0 = fmaf(sW[i], Mg[i * 128 + j], a0);
    a1 = fmaf(sW[i + 1], Mg[(i + 1) * 128 + j], a1);
    a2 = fmaf(sW[i + 2], Mg[(i + 2) * 128 + j], a2);
    a3 = fmaf(sW[i + 3], Mg[(i + 3) * 128 + j], a3);
  }
  float q = sW[j] * ((a0 + a1) + (a2 + a3));
  float dm = sW[j] * Sy[j];
#pragma unroll
  for (int d = 1; d < 64; d <<= 1) {
    q += __shfl_xor(q, d, 64);
    dm += __shfl_xor(dm, d, 64);
  }
  int wv = j >> 6;
  if ((j & 63) == 0) { r2[wv * 2] = q; r2[wv * 2 + 1] = dm; }
  __syncthreads();
  if (j == 0) {
    float quad = r2[0] + r2[2];
    float dmt = r2[1] + r2[3];
    float Eu = dmt * invE;
    float var = fmaxf(quad * invE - Eu * Eu, 0.f);
    float S = g[c] * rsqrtf(var + 1e-5f);
    bnS3[c] = S;
    bnSh3[c] = be[c] - Eu * S;  // GEMM bias c_b1 cancels inside BN
  }
}

// ---------------- coord GEMM with fused bn3+relu+dot(c_w2) epilogue -> scaleE ----------------
__global__ __launch_bounds__(256) void k_cgemm(
    const unsigned short* __restrict__ A,   // t2 [En][128] bf16
    const unsigned short* __restrict__ W,   // c1b bf16 [128][128]
    const float* __restrict__ bnS2, const float* __restrict__ bnSh2,
    const float* __restrict__ bnS3, const float* __restrict__ bnSh3,
    const float* __restrict__ cw2, float* __restrict__ scaleE) {
  constexpr int WST = 136;
  __shared__ __align__(16) unsigned short smem[128 * WST];
  int tid = threadIdx.x;
  int w = tid >> 6, lane = tid & 63, m = lane & 15, kq = lane >> 4;
  int rbase = blockIdx.x * 128;
#pragma unroll
  for (int it = 0; it < 8; ++it) {
    int idx = it * 256 + tid;
    int n = idx >> 4, seg = idx & 15;
    *(uint4*)(smem + n * WST + seg * 8) = *(const uint4*)(W + (size_t)n * 128 + seg * 8);
  }
  __syncthreads();
  int rc0 = rbase + w * 32 + m, rc1 = rc0 + 16;
  f32x4 acc[2][8];
#pragma unroll
  for (int rt = 0; rt < 2; ++rt)
#pragma unroll
    for (int c = 0; c < 8; ++c) acc[rt][c] = (f32x4){0.f, 0.f, 0.f, 0.f};
#pragma unroll
  for (int ks = 0; ks < 4; ++ks) {
    int k0 = ks * 32 + kq * 8;
    U8 ua0, ua1;
    ua0.u4 = *(const uint4*)(A + (size_t)rc0 * 128 + k0);
    ua1.u4 = *(const uint4*)(A + (size_t)rc1 * 128 + k0);
    const float4* sp = (const float4*)(bnS2 + k0);
    const float4* hp = (const float4*)(bnSh2 + k0);
    float4 s0 = sp[0], s1 = sp[1], h0 = hp[0], h1 = hp[1];
    float sv[8] = {s0.x, s0.y, s0.z, s0.w, s1.x, s1.y, s1.z, s1.w};
    float hv[8] = {h0.x, h0.y, h0.z, h0.w, h1.x, h1.y, h1.z, h1.w};
    U8 pa, pb;
#pragma unroll
    for (int jj = 0; jj < 4; ++jj) {
      float v0a = fmaxf(bf2f(ua0.us[2 * jj]) * sv[2 * jj] + hv[2 * jj], 0.f);
      float v0b = fmaxf(bf2f(ua0.us[2 * jj + 1]) * sv[2 * jj + 1] + hv[2 * jj + 1], 0.f);
      float v1a = fmaxf(bf2f(ua1.us[2 * jj]) * sv[2 * jj] + hv[2 * jj], 0.f);
      float v1b = fmaxf(bf2f(ua1.us[2 * jj + 1]) * sv[2 * jj + 1] + hv[2 * jj + 1], 0.f);
      pa.ui[jj] = f2bf2(v0a, v0b);
      pb.ui[jj] = f2bf2(v1a, v1b);
    }
#pragma unroll
    for (int c = 0; c < 8; ++c) {
      U8 ub;
      ub.u4 = *(const uint4*)(smem + (c * 16 + m) * WST + k0);
      acc[0][c] = __builtin_amdgcn_mfma_f32_16x16x32_bf16(pa.s8, ub.s8, acc[0][c], 0, 0, 0);
      acc[1][c] = __builtin_amdgcn_mfma_f32_16x16x32_bf16(pb.s8, ub.s8, acc[1][c], 0, 0, 0);
    }
  }
  // epilogue: scale[e] = sum_n cw2[n] * relu(acc*S3[n] + Sh3[n])
  float s3v[8], h3v[8], wv[8];
#pragma unroll
  for (int c = 0; c < 8; ++c) {
    int n = c * 16 + m;
    s3v[c] = bnS3[n];
    h3v[c] = bnSh3[n];
    wv[c] = cw2[n];
  }
  float p0[4] = {0.f, 0.f, 0.f, 0.f}, p1[4] = {0.f, 0.f, 0.f, 0.f};
#pragma unroll
  for (int c = 0; c < 8; ++c)
#pragma unroll
    for (int j = 0; j < 4; ++j) {
      p0[j] += fmaxf(acc[0][c][j] * s3v[c] + h3v[c], 0.f) * wv[c];
      p1[j] += fmaxf(acc[1][c][j] * s3v[c] + h3v[c], 0.f) * wv[c];
    }
#pragma unroll
  for (int j = 0; j < 4; ++j)
#pragma unroll
    for (int d = 1; d < 16; d <<= 1) {
      p0[j] += __shfl_xor(p0[j], d, 64);
      p1[j] += __shfl_xor(p1[j], d, 64);
    }
  if (m == 0) {
    int r0 = rbase + w * 32 + kq * 4;
    *(float4*)(scaleE + r0) = make_float4(p0[0], p0[1], p0[2], p0[3]);
    *(float4*)(scaleE + r0 + 16) = make_float4(p1[0], p1[1], p1[2], p1[3]);
  }
}

// coord_out: contiguous CSR ranges, coalesced
__global__ __launch_bounds__(256) void k_coord(const float* __restrict__ coord,
                                               const unsigned short* __restrict__ colS,
                                               const int* __restrict__ start,
                                               const int* __restrict__ cnt,
                                               const float* __restrict__ scaleE,
                                               float* __restrict__ cout) {
  int tid = threadIdx.x;
  int lane = tid & 63;
  int n = blockIdx.x * 4 + (tid >> 6);
  if (n >= Nn) return;
  int deg = cnt[n], off = start[n];
  float cx0 = coord[n * 3 + 0], cy0 = coord[n * 3 + 1], cz0 = coord[n * 3 + 2];
  float ax = 0.f, ay = 0.f, az = 0.f;
  for (int j = lane; j < deg; j += 64) {
    int e = off + j;
    int c = colS[e];
    float s = scaleE[e];
    float tx = (cx0 - coord[c * 3 + 0]) * s;
    float ty = (cy0 - coord[c * 3 + 1]) * s;
    float tz = (cz0 - coord[c * 3 + 2]) * s;
    ax += fminf(fmaxf(tx, -100.f), 100.f);
    ay += fminf(fmaxf(ty, -100.f), 100.f);
    az += fminf(fmaxf(tz, -100.f), 100.f);
  }
#pragma unroll
  for (int d = 32; d; d >>= 1) {
    ax += __shfl_xor(ax, d, 64);
    ay += __shfl_xor(ay, d, 64);
    az += __shfl_xor(az, d, 64);
  }
  if (lane == 0) {
    float inv = 1.f / fmaxf((float)deg, 1.f);
    cout[n * 3 + 0] = cx0 + ax * inv;
    cout[n * 3 + 1] = cy0 + ay * inv;
    cout[n * 3 + 2] = cz0 + az * inv;
  }
}

// ---------------- launcher ----------------

extern "C" void kernel_launch(void* const* d_in, const int* in_sizes, int n_in, void* d_out,
                              int out_size, void* d_ws, size_t ws_size, hipStream_t stream) {
  (void)in_sizes; (void)n_in; (void)out_size; (void)ws_size;
  const float* h = (const float*)d_in[0];
  const float* coord = (const float*)d_in[1];
  const int* eidx = (const int*)d_in[2];
  const int* row = eidx;
  const int* col = eidx + En;
  const float* e_w1 = (const float*)d_in[3];
  const float* e_b1 = (const float*)d_in[4];
  const float* e_g1 = (const float*)d_in[5];
  const float* e_be1 = (const float*)d_in[6];
  const float* e_w2 = (const float*)d_in[7];
  const float* e_b2 = (const float*)d_in[8];
  const float* e_g2 = (const float*)d_in[9];
  const float* e_be2 = (const float*)d_in[10];
  const float* n_w1 = (const float*)d_in[11];
  const float* n_b1 = (const float*)d_in[12];
  const float* n_g1 = (const float*)d_in[13];
  const float* n_be1 = (const float*)d_in[14];
  const float* n_w2 = (const float*)d_in[15];
  const float* n_b2 = (const float*)d_in[16];
  const float* c_w1 = (const float*)d_in[17];
  const float* c_b1 = (const float*)d_in[18];
  (void)c_b1;  // bias before BN cancels analytically (k_fin3)
  const float* c_g1 = (const float*)d_in[19];
  const float* c_be1 = (const float*)d_in[20];
  const float* c_w2 = (const float*)d_in[21];

  char* base = (char*)d_ws;
  size_t off = 0;
  auto alloc = [&](size_t bytes) -> void* {
    void* p = base + off;
    off = (off + bytes + 255) & ~(size_t)255;
    return p;
  };
  // Workspace budget: ~260 MB (proven footprint, unchanged — moment buffers aliased).
  unsigned short* t = (unsigned short*)alloc((size_t)En * 128 * 2);      // t2, then t4
  unsigned short* nodeA = (unsigned short*)alloc((size_t)Nn * 256 * 2);  // [h | agg] bf16
  unsigned short* hWr = (unsigned short*)alloc((size_t)Nn * 128 * 2);
  unsigned short* hWc = (unsigned short*)alloc((size_t)Nn * 128 * 2);
  float* scaleE = (float*)alloc((size_t)En * 4);
  float* radS = scaleE;  // alias: radS dead (after k_egemm2) before scaleE written (k_cgemm)
  unsigned short* rowS = (unsigned short*)alloc((size_t)En * 2);
  unsigned short* colS = (unsigned short*)alloc((size_t)En * 2);
  int* cnt = (int*)alloc((size_t)Nn * 4);
  int* startp = (int*)alloc((size_t)Nn * 4);
  int* cursor = (int*)alloc((size_t)Nn * 4);
  float* statS = (float*)alloc(4 * NSLOT * 128 * 4);
  float* statQ = (float*)alloc(4 * NSLOT * 128 * 4);
  float* bnS = (float*)alloc(4 * 128 * 4);
  float* bnSh = (float*)alloc(4 * 128 * 4);
  unsigned short* w1a = (unsigned short*)alloc(128 * 128 * 2);
  unsigned short* w1b = (unsigned short*)alloc(128 * 128 * 2);
  unsigned short* w2b = (unsigned short*)alloc(128 * 128 * 2);
  unsigned short* c1b = (unsigned short*)alloc(128 * 128 * 2);
  unsigned short* n1b = (unsigned short*)alloc(128 * 256 * 2);
  unsigned short* n2b = (unsigned short*)alloc(128 * 128 * 2);
  float* wlast = (float*)alloc(128 * 4);
  // Moment buffers ALIASED into dead regions (no new workspace):
  //  - Mpart (MGRID=384 × 64KB = 25.2 MB) over hWr+hWc (25.6 MB contiguous, dead after k_egemm2)
  //  - Mg (16384 f32) + SyG (128 f32) at head of scaleE region (radS dead after k_egemm2;
  //    scaleE written only later by k_cgemm, after k_fin3 consumed Mg/SyG)
  float* Mpart = (float*)hWr;
  float* Mg = scaleE;
  float* SyG = scaleE + 16384;

  hipMemsetAsync(cnt, 0, (size_t)Nn * 4, stream);
  hipMemsetAsync(statS, 0, 4 * NSLOT * 128 * 4, stream);
  hipMemsetAsync(statQ, 0, 4 * NSLOT * 128 * 4, stream);

  // prep
  k_prep_h<<<(Nn * 128 + 255) / 256, 256, 0, stream>>>(h, nodeA);
  k_prep_w<<<(128 * 128 + 255) / 256, 256, 0, stream>>>(e_w1, w1a, 257, 0, 7, 128 * 128);
  k_prep_w<<<(128 * 128 + 255) / 256, 256, 0, stream>>>(e_w1, w1b, 257, 128, 7, 128 * 128);
  k_prep_w<<<(128 * 128 + 255) / 256, 256, 0, stream>>>(e_w2, w2b, 128, 0, 7, 128 * 128);
  k_prep_w<<<(128 * 128 + 255) / 256, 256, 0, stream>>>(c_w1, c1b, 128, 0, 7, 128 * 128);
  k_prep_w<<<(128 * 256 + 255) / 256, 256, 0, stream>>>(n_w1, n1b, 256, 0, 8, 128 * 256);
  k_prep_w<<<(128 * 128 + 255) / 256, 256, 0, stream>>>(n_w2, n2b, 128, 0, 7, 128 * 128);
  k_wlast<<<1, 128, 0, stream>>>(e_w1, wlast);

  // CSR sort
  k_count<<<En / 256, 256, 0, stream>>>(row, cnt);
  k_scan<<<1, 1024, 0, stream>>>(cnt, startp, cursor, Nn);
  k_fill<<<En / 256, 256, 0, stream>>>(row, col, cursor, rowS, colS);

  // hW partial GEMMs (bias e_b1 folded into hWr)
  const int gridN = (Nn + 127) / 128;
  k_gemmW<4, false, false, false, true><<<gridN, 256, 0, stream>>>(
      nodeA, 256, w1a, e_b1, nullptr, nullptr, hWr, nullptr, nullptr, nullptr, nullptr, Nn);
  k_gemmW<4, false, false, false, true><<<gridN, 256, 0, stream>>>(
      nodeA, 256, w1b, nullptr, nullptr, nullptr, hWc, nullptr, nullptr, nullptr, nullptr, Nn);

  // bn1 stats over virtual t1 + radS (per_wave even for the 2-edge unroll)
  const int per_wave = ((En / 2 + 5119) / 5120) * 2;  // 1280 blocks * 4 waves
  k_stats1<<<1280, 256, 0, stream>>>(hWr, hWc, coord, rowS, colS, wlast, radS,
                                     statS + 0 * NSLOT * 128, statQ + 0 * NSLOT * 128, per_wave);
  k_fin<<<1, 128, 0, stream>>>(statS + 0 * NSLOT * 128, statQ + 0 * NSLOT * 128, e_g1, e_be1,
                               1.f / En, bnS + 0, bnSh + 0);

  // edge layer 2: t2 + bn2 stats (slot 1) — last use of hWr/hWc/radS
  k_egemm2<<<En / 128, 256, 0, stream>>>(hWr, hWc, radS, rowS, colS, w2b, e_b2, wlast, bnS + 0,
                                         bnSh + 0, t, statS + 1 * NSLOT * 128,
                                         statQ + 1 * NSLOT * 128);
  k_fin<<<1, 128, 0, stream>>>(statS + 1 * NSLOT * 128, statQ + 1 * NSLOT * 128, e_g2, e_be2,
                               1.f / En, bnS + 128, bnSh + 128);

  // node aggregation from contiguous t2 rows (no atomics)
  k_agg<<<(Nn + 3) / 4, 256, 0, stream>>>(t, startp, cnt, bnS + 128, bnSh + 128, nodeA);

  // bn3 stats WITHOUT materializing t3: second moment of y = relu(bn2(t2))
  hipMemsetAsync(SyG, 0, 128 * 4, stream);  // after radS is dead, before k_moment
  k_moment<<<MGRID, 512, 0, stream>>>(t, bnS + 128, bnSh + 128, Mpart, SyG);
  k_msum<<<256, 256, 0, stream>>>(Mpart, Mg);
  k_fin3<<<128, 128, 0, stream>>>(Mg, SyG, c_w1, c_g1, c_be1, 1.f / En, bnS + 256, bnSh + 256);

  // coord GEMM with fused bn3+relu+c_w2 epilogue -> per-edge scale (no t3 store, no scale pass)
  k_cgemm<<<En / 128, 256, 0, stream>>>(t, c1b, bnS + 128, bnSh + 128, bnS + 256, bnSh + 256,
                                        c_w2, scaleE);

  float* hout = (float*)d_out;
  float* cout = hout + (size_t)Nn * 128;
  k_coord<<<(Nn + 3) / 4, 256, 0, stream>>>(coord, colS, startp, cnt, scaleE, cout);

  // node MLP: l1 (stats slot 3) -> t4 in t (t2 dead after k_cgemm); l2 fp32 out
  k_gemmW<8, false, true, false, true><<<gridN, 256, 0, stream>>>(
      nodeA, 256, n1b, n_b1, nullptr, nullptr, t, statS + 3 * NSLOT * 128,
      statQ + 3 * NSLOT * 128, nullptr, nullptr, Nn);
  k_fin<<<1, 128, 0, stream>>>(statS + 3 * NSLOT * 128, statQ + 3 * NSLOT * 128, n_g1, n_be1,
                               1.f / Nn, bnS + 384, bnSh + 384);
  k_gemmW<4, true, false, true, true><<<gridN, 256, 0, stream>>>(
      t, 128, n2b, n_b2, bnS + 384, bnSh + 384, nullptr, nullptr, nullptr, h, hout, Nn);
}

// Round 17
// 785.426 us; speedup vs baseline: 1.1684x; 1.0561x over previous
//
#include <hip/hip_runtime.h>

#define Nn 50000
#define En 800000
#define NSLOT 64
#define MGRID 256

typedef __attribute__((ext_vector_type(8))) short short8;
typedef __attribute__((ext_vector_type(4))) float f32x4;

union U8 { uint4 u4; unsigned short us[8]; unsigned int ui[4]; short8 s8; };

static __device__ __forceinline__ float bf2f(unsigned int lo16) {
  return __uint_as_float(lo16 << 16);
}
static __device__ __forceinline__ unsigned short f2bf(float f) {
  unsigned int x = __float_as_uint(f);
  return (unsigned short)((x + 0x7FFFu + ((x >> 16) & 1u)) >> 16);
}
// packed RNE f32x2 -> bf16x2 (lo = a, hi = b) via hardware cvt (gfx950)
static __device__ __forceinline__ unsigned int f2bf2(float a, float b) {
  unsigned int r;
  asm("v_cvt_pk_bf16_f32 %0, %1, %2" : "=v"(r) : "v"(a), "v"(b));
  return r;
}

// ---------------- prep kernels ----------------

__global__ __launch_bounds__(256) void k_prep_h(const float* __restrict__ h,
                                                unsigned short* __restrict__ nodeA) {
  int idx = blockIdx.x * 256 + threadIdx.x;
  if (idx >= Nn * 128) return;
  int n = idx >> 7, k = idx & 127;
  nodeA[(size_t)n * 256 + k] = f2bf(h[idx]);
}

// weight fp32 [128][Ksrc] cols [koff, koff+2^kshift) -> bf16 [128][2^kshift]
__global__ __launch_bounds__(256) void k_prep_w(const float* __restrict__ src,
                                                unsigned short* __restrict__ dst, int Ksrc,
                                                int koff, int kshift, int total) {
  int idx = blockIdx.x * 256 + threadIdx.x;
  if (idx >= total) return;
  int n = idx >> kshift;
  int k = idx & ((1 << kshift) - 1);
  dst[idx] = f2bf(src[n * Ksrc + koff + k]);
}

__global__ void k_wlast(const float* __restrict__ e_w1, float* __restrict__ wlast) {
  int t = threadIdx.x;
  if (t < 128) wlast[t] = e_w1[t * 257 + 256];
}

// ---------------- CSR build (edges sorted by row; node ids fit u16) ----------------

__global__ __launch_bounds__(256) void k_count(const int* __restrict__ row, int* __restrict__ cnt) {
  int e = blockIdx.x * 256 + threadIdx.x;
  atomicAdd(&cnt[row[e]], 1);
}

__global__ __launch_bounds__(256) void k_fill(const int* __restrict__ row,
                                              const int* __restrict__ col,
                                              int* __restrict__ cursor,
                                              unsigned short* __restrict__ rowS,
                                              unsigned short* __restrict__ colS) {
  int e = blockIdx.x * 256 + threadIdx.x;
  int r = row[e];
  int pos = atomicAdd(&cursor[r], 1);
  rowS[pos] = (unsigned short)r;
  colS[pos] = (unsigned short)col[e];
}

__global__ __launch_bounds__(1024) void k_scan(const int* __restrict__ cnt, int* __restrict__ start,
                                               int* __restrict__ cursor, int n) {
  __shared__ int wsum[16];
  __shared__ int carry;
  int tid = threadIdx.x, lane = tid & 63, wid = tid >> 6;
  if (tid == 0) carry = 0;
  __syncthreads();
  for (int base = 0; base < n; base += 1024) {
    int i = base + tid;
    int v = (i < n) ? cnt[i] : 0;
    int x = v;
#pragma unroll
    for (int d = 1; d < 64; d <<= 1) {
      int y = __shfl_up(x, d, 64);
      if (lane >= d) x += y;
    }
    if (lane == 63) wsum[wid] = x;
    __syncthreads();
    if (wid == 0) {
      int s = (lane < 16) ? wsum[lane] : 0;
#pragma unroll
      for (int d = 1; d < 16; d <<= 1) {
        int y = __shfl_up(s, d, 64);
        if (lane >= d) s += y;
      }
      if (lane < 16) wsum[lane] = s;
    }
    __syncthreads();
    int c0 = carry;
    int waveoff = (wid > 0) ? wsum[wid - 1] : 0;
    int incl = c0 + waveoff + x;
    if (i < n) {
      start[i] = incl - v;
      cursor[i] = incl - v;
    }
    __syncthreads();
    if (tid == 1023) carry = incl;
    __syncthreads();
  }
}

// ---------------- BN finalize ----------------

__global__ void k_fin(const float* __restrict__ statS, const float* __restrict__ statQ,
                      const float* __restrict__ g, const float* __restrict__ be, float invR,
                      float* __restrict__ bnS, float* __restrict__ bnSh) {
  int c = threadIdx.x;
  if (c >= 128) return;
  float s = 0.f, q = 0.f;
  for (int k = 0; k < NSLOT; ++k) {
    s += statS[k * 128 + c];
    q += statQ[k * 128 + c];
  }
  float mean = s * invR;
  float var = fmaxf(q * invR - mean * mean, 0.f);
  float rs = rsqrtf(var + 1e-5f);
  float sc = g[c] * rs;
  bnS[c] = sc;
  bnSh[c] = be[c] - mean * sc;
}

// ---------------- generic MFMA GEMM with W in LDS ----------------
template <int KSTEPS, bool BN_A, bool STATS, bool FP32OUT, bool STORE>
__global__ __launch_bounds__(256) void k_gemmW(
    const unsigned short* __restrict__ A, int Astride,
    const unsigned short* __restrict__ W, const float* __restrict__ bias,
    const float* __restrict__ bnS, const float* __restrict__ bnSh,
    unsigned short* __restrict__ outb, float* __restrict__ statS, float* __restrict__ statQ,
    const float* __restrict__ hres, float* __restrict__ outf, int R) {
  constexpr int K = KSTEPS * 32;
  constexpr int WST = K + 8;
  constexpr int SEGS = K / 8;
  __shared__ __align__(16) unsigned short smem[128 * WST];
  __shared__ float ssum[4][128], ssq[4][128];
  int tid = threadIdx.x;
  int w = tid >> 6, lane = tid & 63, m = lane & 15, kq = lane >> 4;
  int rbase = blockIdx.x * 128;
#pragma unroll
  for (int it = 0; it < SEGS / 2; ++it) {
    int idx = it * 256 + tid;
    int n = idx / SEGS, seg = idx % SEGS;
    uint4 v = *(const uint4*)(W + (size_t)n * K + seg * 8);
    *(uint4*)(smem + n * WST + seg * 8) = v;
  }
  __syncthreads();
  int row0 = rbase + w * 32 + m;
  int rc0 = min(row0, R - 1);
  int rc1 = min(row0 + 16, R - 1);
  f32x4 acc[2][8];
#pragma unroll
  for (int rt = 0; rt < 2; ++rt)
#pragma unroll
    for (int c = 0; c < 8; ++c) acc[rt][c] = (f32x4){0.f, 0.f, 0.f, 0.f};
#pragma unroll
  for (int ks = 0; ks < KSTEPS; ++ks) {
    int k0 = ks * 32 + kq * 8;
    U8 ua0, ua1;
    ua0.u4 = *(const uint4*)(A + (size_t)rc0 * Astride + k0);
    ua1.u4 = *(const uint4*)(A + (size_t)rc1 * Astride + k0);
    if (BN_A) {
      const float4* sp = (const float4*)(bnS + k0);
      const float4* hp = (const float4*)(bnSh + k0);
      float4 s0 = sp[0], s1 = sp[1], h0 = hp[0], h1 = hp[1];
      float sv[8] = {s0.x, s0.y, s0.z, s0.w, s1.x, s1.y, s1.z, s1.w};
      float hv[8] = {h0.x, h0.y, h0.z, h0.w, h1.x, h1.y, h1.z, h1.w};
      U8 pa, pb;
#pragma unroll
      for (int jj = 0; jj < 4; ++jj) {
        float a0 = fmaxf(bf2f(ua0.us[2 * jj]) * sv[2 * jj] + hv[2 * jj], 0.f);
        float a1 = fmaxf(bf2f(ua0.us[2 * jj + 1]) * sv[2 * jj + 1] + hv[2 * jj + 1], 0.f);
        float b0 = fmaxf(bf2f(ua1.us[2 * jj]) * sv[2 * jj] + hv[2 * jj], 0.f);
        float b1 = fmaxf(bf2f(ua1.us[2 * jj + 1]) * sv[2 * jj + 1] + hv[2 * jj + 1], 0.f);
        pa.ui[jj] = f2bf2(a0, a1);
        pb.ui[jj] = f2bf2(b0, b1);
      }
      ua0 = pa;
      ua1 = pb;
    }
#pragma unroll
    for (int c = 0; c < 8; ++c) {
      U8 ub;
      ub.u4 = *(const uint4*)(smem + (c * 16 + m) * WST + k0);
      acc[0][c] = __builtin_amdgcn_mfma_f32_16x16x32_bf16(ua0.s8, ub.s8, acc[0][c], 0, 0, 0);
      acc[1][c] = __builtin_amdgcn_mfma_f32_16x16x32_bf16(ua1.s8, ub.s8, acc[1][c], 0, 0, 0);
    }
  }
  if constexpr (FP32OUT) {
#pragma unroll
    for (int rt = 0; rt < 2; ++rt)
#pragma unroll
      for (int c = 0; c < 8; ++c) {
        int n = c * 16 + m;
        float bn_ = bias[n];
#pragma unroll
        for (int j = 0; j < 4; ++j) {
          int rr = rbase + w * 32 + rt * 16 + kq * 4 + j;
          if (rr < R) {
            size_t o = (size_t)rr * 128 + n;
            outf[o] = acc[rt][c][j] + bn_ + hres[o];
          }
        }
      }
  } else {
    if constexpr (STORE) __syncthreads();
    unsigned short* tile = smem;  // reuse as [128][136]
#pragma unroll
    for (int c = 0; c < 8; ++c) {
      int n = c * 16 + m;
      float bn_ = bias ? bias[n] : 0.f;
      float s = 0.f, q = 0.f;
#pragma unroll
      for (int rt = 0; rt < 2; ++rt)
#pragma unroll
        for (int j = 0; j < 4; ++j) {
          int lr = w * 32 + rt * 16 + kq * 4 + j;
          float v = acc[rt][c][j] + bn_;
          if (STORE) tile[lr * 136 + n] = f2bf(v);
          if (STATS) {
            float sv = (rbase + lr < R) ? v : 0.f;
            s += sv;
            q = fmaf(sv, sv, q);
          }
        }
      if (STATS) {
        s += __shfl_xor(s, 16, 64); s += __shfl_xor(s, 32, 64);
        q += __shfl_xor(q, 16, 64); q += __shfl_xor(q, 32, 64);
        if (kq == 0) { ssum[w][n] = s; ssq[w][n] = q; }
      }
    }
    if constexpr (STORE) {
      __syncthreads();
      const uint4* tl = (const uint4*)tile;
#pragma unroll
      for (int u = 0; u < 8; ++u) {
        int idx = u * 256 + tid;
        int rr = idx >> 4, seg = idx & 15;
        if (rbase + rr < R)
          *(uint4*)(outb + (size_t)(rbase + rr) * 128 + seg * 8) = tl[rr * 17 + seg];
      }
    }
    if (STATS) {
      __syncthreads();
      if (tid < 128) {
        float s = ssum[0][tid] + ssum[1][tid] + ssum[2][tid] + ssum[3][tid];
        float q = ssq[0][tid] + ssq[1][tid] + ssq[2][tid] + ssq[3][tid];
        int slot = blockIdx.x & (NSLOT - 1);
        atomicAdd(&statS[slot * 128 + tid], s);
        atomicAdd(&statQ[slot * 128 + tid], q);
      }
    }
  }
}

// ---------------- bn1 stats over virtual t1 (no materialization) + radS ----------------
// per_wave is even and En is even -> every wave's range has even length
__global__ __launch_bounds__(256) void k_stats1(
    const unsigned short* __restrict__ hWr, const unsigned short* __restrict__ hWc,
    const float* __restrict__ coord, const unsigned short* __restrict__ rowS,
    const unsigned short* __restrict__ colS, const float* __restrict__ wlast,
    float* __restrict__ radS, float* __restrict__ statS, float* __restrict__ statQ,
    int per_wave) {
  int tid = threadIdx.x, lane = tid & 63;
  int wid = blockIdx.x * 4 + (tid >> 6);
  int e0 = wid * per_wave;
  int e1 = min(e0 + per_wave, En);
  int c2 = lane * 2;
  float wl0 = wlast[c2], wl1 = wlast[c2 + 1];
  float s0 = 0.f, s1 = 0.f, q0 = 0.f, q1 = 0.f;
  for (int e = e0; e < e1; e += 2) {
    int ra = rowS[e], ca = colS[e];
    int rb = rowS[e + 1], cb = colS[e + 1];
    float ax = coord[ra * 3 + 0] - coord[ca * 3 + 0];
    float ay = coord[ra * 3 + 1] - coord[ca * 3 + 1];
    float az = coord[ra * 3 + 2] - coord[ca * 3 + 2];
    float bx = coord[rb * 3 + 0] - coord[cb * 3 + 0];
    float by = coord[rb * 3 + 1] - coord[cb * 3 + 1];
    float bz = coord[rb * 3 + 2] - coord[cb * 3 + 2];
    float rada = ax * ax + ay * ay + az * az;
    float radb = bx * bx + by * by + bz * bz;
    if (lane == 0) {
      radS[e] = rada;
      radS[e + 1] = radb;
    }
    unsigned int uar = *(const unsigned int*)(hWr + (size_t)ra * 128 + c2);
    unsigned int uac = *(const unsigned int*)(hWc + (size_t)ca * 128 + c2);
    unsigned int ubr = *(const unsigned int*)(hWr + (size_t)rb * 128 + c2);
    unsigned int ubc = *(const unsigned int*)(hWc + (size_t)cb * 128 + c2);
    float va0 = bf2f(uar & 0xFFFFu) + bf2f(uac & 0xFFFFu) + rada * wl0;
    float va1 = bf2f(uar >> 16) + bf2f(uac >> 16) + rada * wl1;
    float vb0 = bf2f(ubr & 0xFFFFu) + bf2f(ubc & 0xFFFFu) + radb * wl0;
    float vb1 = bf2f(ubr >> 16) + bf2f(ubc >> 16) + radb * wl1;
    s0 += va0 + vb0;
    s1 += va1 + vb1;
    q0 = fmaf(va0, va0, q0); q0 = fmaf(vb0, vb0, q0);
    q1 = fmaf(va1, va1, q1); q1 = fmaf(vb1, vb1, q1);
  }
  int slot = wid & (NSLOT - 1);
  atomicAdd(&statS[slot * 128 + c2], s0);
  atomicAdd(&statS[slot * 128 + c2 + 1], s1);
  atomicAdd(&statQ[slot * 128 + c2], q0);
  atomicAdd(&statQ[slot * 128 + c2 + 1], q1);
}

// ---------------- edge layer 2 GEMM, A recomputed from hWr/hWc/radS ----------------
__global__ __launch_bounds__(256) void k_egemm2(
    const unsigned short* __restrict__ hWr, const unsigned short* __restrict__ hWc,
    const float* __restrict__ radS, const unsigned short* __restrict__ rowS,
    const unsigned short* __restrict__ colS, const unsigned short* __restrict__ W,
    const float* __restrict__ bias, const float* __restrict__ wlast,
    const float* __restrict__ bnS1, const float* __restrict__ bnSh1,
    unsigned short* __restrict__ outb, float* __restrict__ statS, float* __restrict__ statQ) {
  constexpr int WST = 136;
  __shared__ __align__(16) unsigned short smem[128 * WST];
  __shared__ float ssum[4][128], ssq[4][128];
  int tid = threadIdx.x;
  int w = tid >> 6, lane = tid & 63, m = lane & 15, kq = lane >> 4;
  int rbase = blockIdx.x * 128;
#pragma unroll
  for (int it = 0; it < 8; ++it) {
    int idx = it * 256 + tid;
    int n = idx >> 4, seg = idx & 15;
    uint4 v = *(const uint4*)(W + (size_t)n * 128 + seg * 8);
    *(uint4*)(smem + n * WST + seg * 8) = v;
  }
  int rc0 = rbase + w * 32 + m, rc1 = rc0 + 16;
  int r0 = rowS[rc0], c0 = colS[rc0];
  int r1 = rowS[rc1], c1 = colS[rc1];
  float rad0 = radS[rc0], rad1 = radS[rc1];
  __syncthreads();
  f32x4 acc[2][8];
#pragma unroll
  for (int rt = 0; rt < 2; ++rt)
#pragma unroll
    for (int c = 0; c < 8; ++c) acc[rt][c] = (f32x4){0.f, 0.f, 0.f, 0.f};
#pragma unroll
  for (int ks = 0; ks < 4; ++ks) {
    int k0 = ks * 32 + kq * 8;
    U8 a0r, a0c, a1r, a1c;
    a0r.u4 = *(const uint4*)(hWr + (size_t)r0 * 128 + k0);
    a0c.u4 = *(const uint4*)(hWc + (size_t)c0 * 128 + k0);
    a1r.u4 = *(const uint4*)(hWr + (size_t)r1 * 128 + k0);
    a1c.u4 = *(const uint4*)(hWc + (size_t)c1 * 128 + k0);
    const float4* wp = (const float4*)(wlast + k0);
    const float4* sp = (const float4*)(bnS1 + k0);
    const float4* hp = (const float4*)(bnSh1 + k0);
    float4 w0 = wp[0], w1 = wp[1], sA = sp[0], sB = sp[1], hA = hp[0], hB = hp[1];
    float wv[8] = {w0.x, w0.y, w0.z, w0.w, w1.x, w1.y, w1.z, w1.w};
    float sv[8] = {sA.x, sA.y, sA.z, sA.w, sB.x, sB.y, sB.z, sB.w};
    float hv[8] = {hA.x, hA.y, hA.z, hA.w, hB.x, hB.y, hB.z, hB.w};
    U8 ua0, ua1;
#pragma unroll
    for (int jj = 0; jj < 4; ++jj) {
      int j0 = 2 * jj, j1 = 2 * jj + 1;
      float v0a = bf2f(a0r.us[j0]) + bf2f(a0c.us[j0]) + rad0 * wv[j0];
      float v0b = bf2f(a0r.us[j1]) + bf2f(a0c.us[j1]) + rad0 * wv[j1];
      float v1a = bf2f(a1r.us[j0]) + bf2f(a1c.us[j0]) + rad1 * wv[j0];
      float v1b = bf2f(a1r.us[j1]) + bf2f(a1c.us[j1]) + rad1 * wv[j1];
      v0a = fmaxf(v0a * sv[j0] + hv[j0], 0.f);
      v0b = fmaxf(v0b * sv[j1] + hv[j1], 0.f);
      v1a = fmaxf(v1a * sv[j0] + hv[j0], 0.f);
      v1b = fmaxf(v1b * sv[j1] + hv[j1], 0.f);
      ua0.ui[jj] = f2bf2(v0a, v0b);
      ua1.ui[jj] = f2bf2(v1a, v1b);
    }
#pragma unroll
    for (int c = 0; c < 8; ++c) {
      U8 ub;
      ub.u4 = *(const uint4*)(smem + (c * 16 + m) * WST + k0);
      acc[0][c] = __builtin_amdgcn_mfma_f32_16x16x32_bf16(ua0.s8, ub.s8, acc[0][c], 0, 0, 0);
      acc[1][c] = __builtin_amdgcn_mfma_f32_16x16x32_bf16(ua1.s8, ub.s8, acc[1][c], 0, 0, 0);
    }
  }
  __syncthreads();
  unsigned short* tile = smem;
#pragma unroll
  for (int c = 0; c < 8; ++c) {
    int n = c * 16 + m;
    float bn_ = bias[n];
    float s = 0.f, q = 0.f;
#pragma unroll
    for (int rt = 0; rt < 2; ++rt)
#pragma unroll
      for (int j = 0; j < 4; ++j) {
        int lr = w * 32 + rt * 16 + kq * 4 + j;
        float v = acc[rt][c][j] + bn_;
        tile[lr * 136 + n] = f2bf(v);
        s += v;
        q = fmaf(v, v, q);
      }
    s += __shfl_xor(s, 16, 64); s += __shfl_xor(s, 32, 64);
    q += __shfl_xor(q, 16, 64); q += __shfl_xor(q, 32, 64);
    if (kq == 0) { ssum[w][n] = s; ssq[w][n] = q; }
  }
  __syncthreads();
  const uint4* tl = (const uint4*)tile;
#pragma unroll
  for (int u = 0; u < 8; ++u) {
    int idx = u * 256 + tid;
    int rr = idx >> 4, seg = idx & 15;
    *(uint4*)(outb + (size_t)(rbase + rr) * 128 + seg * 8) = tl[rr * 17 + seg];
  }
  if (tid < 128) {
    float s = ssum[0][tid] + ssum[1][tid] + ssum[2][tid] + ssum[3][tid];
    float q = ssq[0][tid] + ssq[1][tid] + ssq[2][tid] + ssq[3][tid];
    int slot = blockIdx.x & (NSLOT - 1);
    atomicAdd(&statS[slot * 128 + tid], s);
    atomicAdd(&statQ[slot * 128 + tid], q);
  }
}

// ---------------- node aggregation over contiguous CSR rows (no atomics) ----------------
__global__ __launch_bounds__(256) void k_agg(const unsigned short* __restrict__ t,
                                             const int* __restrict__ start,
                                             const int* __restrict__ cnt,
                                             const float* __restrict__ bnS,
                                             const float* __restrict__ bnSh,
                                             unsigned short* __restrict__ nodeA) {
  int tid = threadIdx.x;
  int lane = tid & 63;
  int n = blockIdx.x * 4 + (tid >> 6);
  if (n >= Nn) return;
  int deg = cnt[n], off = start[n];
  int c2 = lane * 2;
  float s0 = bnS[c2], s1 = bnS[c2 + 1], h0 = bnSh[c2], h1 = bnSh[c2 + 1];
  float a0 = 0.f, a1 = 0.f;
  const unsigned short* p = t + (size_t)off * 128 + c2;
  for (int j = 0; j < deg; ++j) {
    unsigned int u = *(const unsigned int*)(p + (size_t)j * 128);
    a0 += fmaxf(bf2f(u & 0xFFFFu) * s0 + h0, 0.f);
    a1 += fmaxf(bf2f(u >> 16) * s1 + h1, 0.f);
  }
  float inv = 1.f / fmaxf((float)deg, 1.f);
  unsigned int o = (unsigned)f2bf(a0 * inv) | ((unsigned)f2bf(a1 * inv) << 16);
  *(unsigned int*)(nodeA + (size_t)n * 256 + 128 + c2) = o;
}

// ---------------- second-moment of y = relu(bn2(t2)) — dbuf LDS, 1 barrier/tile ----------------
// M = sum_e y y^T, Sy[c] = sum_e y[e][c].  Lane owns 4 ADJACENT edges (e0..e0+3) × 8 channels.
// LDS channel-major yT[buf][row][e'] with e' = e ^ (s(row)<<3), s(row) = (row ^ (row>>3)) & 7
// (phase-conflict-free: s varies with row&7 across each 8-lane LDS phase).
// DOUBLE-BUFFERED: write tile k into yT[b] while prior MFMA read yT[b^1]; one barrier/tile
// (barrier collectivity guarantees all waves finished MFMA on yT[b] two iterations ago).
__global__ __launch_bounds__(512) void k_moment(
    const unsigned short* __restrict__ t,
    const float* __restrict__ bnS2, const float* __restrict__ bnSh2,
    float* __restrict__ Mpart, float* __restrict__ SyG) {
  constexpr int NT = En / 128;
  __shared__ __align__(16) unsigned short yT[2][128 * 128];
  __shared__ float s2L[128], h2L[128];
  __shared__ float fred[8][128];
  int tid = threadIdx.x;
  int w = tid >> 6, lane = tid & 63, m = lane & 15, kq = lane >> 4;
  if (tid < 128) { s2L[tid] = bnS2[tid]; h2L[tid] = bnSh2[tid]; }
  __syncthreads();
  int p = tid & 15;
  int erow = tid >> 4;       // 0..31
  int c0 = p * 8;            // 8 contiguous channels (rows p*8+j)
  int e0 = erow * 4;         // 4 adjacent edges
  float sA[8], hA[8];
#pragma unroll
  for (int j = 0; j < 8; ++j) { sA[j] = s2L[c0 + j]; hA[j] = h2L[c0 + j]; }
  int p7 = p & 7;
  int m7 = m & 7, m3 = m >> 3;
  f32x4 acc[8];
#pragma unroll
  for (int c = 0; c < 8; ++c) acc[c] = (f32x4){0.f, 0.f, 0.f, 0.f};
  float sy[8];
#pragma unroll
  for (int j = 0; j < 8; ++j) sy[j] = 0.f;
  int tile = blockIdx.x;
  int b = 0;
  U8 cur[4], nxt[4];
  {
    const unsigned short* pp = t + (size_t)tile * 16384 + (size_t)e0 * 128 + c0;
#pragma unroll
    for (int i = 0; i < 4; ++i) cur[i].u4 = *(const uint4*)(pp + i * 128);
  }
  while (tile < NT) {
    int nx = tile + MGRID;
    if (nx < NT) {  // prefetch next tile (coalesced), in flight across barrier+MFMA
      const unsigned short* pp = t + (size_t)nx * 16384 + (size_t)e0 * 128 + c0;
#pragma unroll
      for (int i = 0; i < 4; ++i) nxt[i].u4 = *(const uint4*)(pp + i * 128);
    }
    unsigned int plo[8], phi[8];
#pragma unroll
    for (int j = 0; j < 8; ++j) {
      float y0 = fmaxf(bf2f(cur[0].us[j]) * sA[j] + hA[j], 0.f);
      float y1 = fmaxf(bf2f(cur[1].us[j]) * sA[j] + hA[j], 0.f);
      float y2 = fmaxf(bf2f(cur[2].us[j]) * sA[j] + hA[j], 0.f);
      float y3 = fmaxf(bf2f(cur[3].us[j]) * sA[j] + hA[j], 0.f);
      sy[j] += (y0 + y1) + (y2 + y3);
      plo[j] = f2bf2(y0, y1);
      phi[j] = f2bf2(y2, y3);
    }
    // write into buffer b; prior iteration's MFMA read b^1 — no pre-write barrier needed
    unsigned short* yb = yT[b];
#pragma unroll
    for (int j = 0; j < 8; ++j) {
      uint2 v;
      v.x = plo[j];
      v.y = phi[j];
      *(uint2*)(yb + (c0 + j) * 128 + (e0 ^ ((p7 ^ j) << 3))) = v;
    }
    __syncthreads();  // all writes to b visible; safe to MFMA-read b
#pragma unroll
    for (int ks = 0; ks < 4; ++ks) {
      int eb = ks * 32 + kq * 8;
      U8 fa;
      {
        int s = (m7 ^ ((2 * w + m3) & 7)) << 3;
        fa.u4 = *(const uint4*)(yb + (w * 16 + m) * 128 + (eb ^ s));
      }
#pragma unroll
      for (int cb = 0; cb < 8; ++cb) {
        int s = (m7 ^ ((2 * cb + m3) & 7)) << 3;
        U8 fb;
        fb.u4 = *(const uint4*)(yb + (cb * 16 + m) * 128 + (eb ^ s));
        acc[cb] = __builtin_amdgcn_mfma_f32_16x16x32_bf16(fa.s8, fb.s8, acc[cb], 0, 0, 0);
      }
    }
#pragma unroll
    for (int i = 0; i < 4; ++i) cur[i] = nxt[i];
    tile = nx;
    b ^= 1;
  }
  size_t mb = (size_t)blockIdx.x * 16384;
#pragma unroll
  for (int c = 0; c < 8; ++c)
#pragma unroll
    for (int j = 0; j < 4; ++j)
      Mpart[mb + (size_t)(w * 16 + kq * 4 + j) * 128 + c * 16 + m] = acc[c][j];
  // Sy: reduce the 4 same-channel lanes within wave, then block-reduce via LDS
#pragma unroll
  for (int j = 0; j < 8; ++j) {
    sy[j] += __shfl_xor(sy[j], 16, 64);
    sy[j] += __shfl_xor(sy[j], 32, 64);
  }
  __syncthreads();  // re-purpose fred region safely after loop
  if (lane < 16) {
#pragma unroll
    for (int j = 0; j < 8; ++j) fred[w][lane * 8 + j] = sy[j];
  }
  __syncthreads();
  if (tid < 128) {
    float s = 0.f;
#pragma unroll
    for (int g = 0; g < 8; ++g) s += fred[g][tid];
    atomicAdd(&SyG[tid], s);
  }
}

__global__ __launch_bounds__(256) void k_msum(const float* __restrict__ Mpart,
                                              float* __restrict__ Mg) {
  __shared__ float red[4][64];
  int tid = threadIdx.x;
  int e = blockIdx.x * 64 + (tid & 63);
  int pq = tid >> 6;
  float s = 0.f;
  for (int k = pq * (MGRID / 4); k < (pq + 1) * (MGRID / 4); ++k)
    s += Mpart[(size_t)k * 16384 + e];
  red[pq][tid & 63] = s;
  __syncthreads();
  if (tid < 64) Mg[e] = red[0][tid] + red[1][tid] + red[2][tid] + red[3][tid];
}

// bn3 params from moments: var[c] = (w_c M w_c^T)/E - (w_c . Sy / E)^2  (bias cancels)
// block = channel c; 128 threads each own column j of M.
__global__ __launch_bounds__(128) void k_fin3(
    const float* __restrict__ Mg, const float* __restrict__ Sy,
    const float* __restrict__ w1, const float* __restrict__ g,
    const float* __restrict__ be, float invE,
    float* __restrict__ bnS3, float* __restrict__ bnSh3) {
  __shared__ float sW[128];
  __shared__ float r2[4];
  int c = blockIdx.x, j = threadIdx.x;
  sW[j] = w1[c * 128 + j];
  __syncthreads();
  float a0 = 0.f, a1 = 0.f, a2 = 0.f, a3 = 0.f;
  for (int i = 0; i < 128; i += 4) {
    a0 = fmaf(sW[i], Mg[i * 128 + j], a0);
    a1 = fmaf(sW[i + 1], Mg[(i + 1) * 128 + j], a1);
    a2 = fmaf(sW[i + 2], Mg[(i + 2) * 128 + j], a2);
    a3 = fmaf(sW[i + 3], Mg[(i + 3) * 128 + j], a3);
  }
  float q = sW[j] * ((a0 + a1) + (a2 + a3));
  float dm = sW[j] * Sy[j];
#pragma unroll
  for (int d = 1; d < 64; d <<= 1) {
    q += __shfl_xor(q, d, 64);
    dm += __shfl_xor(dm, d, 64);
  }
  int wv = j >> 6;
  if ((j & 63) == 0) { r2[wv * 2] = q; r2[wv * 2 + 1] = dm; }
  __syncthreads();
  if (j == 0) {
    float quad = r2[0] + r2[2];
    float dmt = r2[1] + r2[3];
    float Eu = dmt * invE;
    float var = fmaxf(quad * invE - Eu * Eu, 0.f);
    float S = g[c] * rsqrtf(var + 1e-5f);
    bnS3[c] = S;
    bnSh3[c] = be[c] - Eu * S;  // GEMM bias c_b1 cancels inside BN
  }
}

// ---------------- coord GEMM with fused bn3+relu+dot(c_w2) epilogue -> scaleE ----------------
__global__ __launch_bounds__(256) void k_cgemm(
    const unsigned short* __restrict__ A,   // t2 [En][128] bf16
    const unsigned short* __restrict__ W,   // c1b bf16 [128][128]
    const float* __restrict__ bnS2, const float* __restrict__ bnSh2,
    const float* __restrict__ bnS3, const float* __restrict__ bnSh3,
    const float* __restrict__ cw2, float* __restrict__ scaleE) {
  constexpr int WST = 136;
  __shared__ __align__(16) unsigned short smem[128 * WST];
  int tid = threadIdx.x;
  int w = tid >> 6, lane = tid & 63, m = lane & 15, kq = lane >> 4;
  int rbase = blockIdx.x * 128;
#pragma unroll
  for (int it = 0; it < 8; ++it) {
    int idx = it * 256 + tid;
    int n = idx >> 4, seg = idx & 15;
    *(uint4*)(smem + n * WST + seg * 8) = *(const uint4*)(W + (size_t)n * 128 + seg * 8);
  }
  __syncthreads();
  int rc0 = rbase + w * 32 + m, rc1 = rc0 + 16;
  f32x4 acc[2][8];
#pragma unroll
  for (int rt = 0; rt < 2; ++rt)
#pragma unroll
    for (int c = 0; c < 8; ++c) acc[rt][c] = (f32x4){0.f, 0.f, 0.f, 0.f};
#pragma unroll
  for (int ks = 0; ks < 4; ++ks) {
    int k0 = ks * 32 + kq * 8;
    U8 ua0, ua1;
    ua0.u4 = *(const uint4*)(A + (size_t)rc0 * 128 + k0);
    ua1.u4 = *(const uint4*)(A + (size_t)rc1 * 128 + k0);
    const float4* sp = (const float4*)(bnS2 + k0);
    const float4* hp = (const float4*)(bnSh2 + k0);
    float4 s0 = sp[0], s1 = sp[1], h0 = hp[0], h1 = hp[1];
    float sv[8] = {s0.x, s0.y, s0.z, s0.w, s1.x, s1.y, s1.z, s1.w};
    float hv[8] = {h0.x, h0.y, h0.z, h0.w, h1.x, h1.y, h1.z, h1.w};
    U8 pa, pb;
#pragma unroll
    for (int jj = 0; jj < 4; ++jj) {
      float v0a = fmaxf(bf2f(ua0.us[2 * jj]) * sv[2 * jj] + hv[2 * jj], 0.f);
      float v0b = fmaxf(bf2f(ua0.us[2 * jj + 1]) * sv[2 * jj + 1] + hv[2 * jj + 1], 0.f);
      float v1a = fmaxf(bf2f(ua1.us[2 * jj]) * sv[2 * jj] + hv[2 * jj], 0.f);
      float v1b = fmaxf(bf2f(ua1.us[2 * jj + 1]) * sv[2 * jj + 1] + hv[2 * jj + 1], 0.f);
      pa.ui[jj] = f2bf2(v0a, v0b);
      pb.ui[jj] = f2bf2(v1a, v1b);
    }
#pragma unroll
    for (int c = 0; c < 8; ++c) {
      U8 ub;
      ub.u4 = *(const uint4*)(smem + (c * 16 + m) * WST + k0);
      acc[0][c] = __builtin_amdgcn_mfma_f32_16x16x32_bf16(pa.s8, ub.s8, acc[0][c], 0, 0, 0);
      acc[1][c] = __builtin_amdgcn_mfma_f32_16x16x32_bf16(pb.s8, ub.s8, acc[1][c], 0, 0, 0);
    }
  }
  // epilogue: scale[e] = sum_n cw2[n] * relu(acc*S3[n] + Sh3[n])
  float s3v[8], h3v[8], wv[8];
#pragma unroll
  for (int c = 0; c < 8; ++c) {
    int n = c * 16 + m;
    s3v[c] = bnS3[n];
    h3v[c] = bnSh3[n];
    wv[c] = cw2[n];
  }
  float p0[4] = {0.f, 0.f, 0.f, 0.f}, p1[4] = {0.f, 0.f, 0.f, 0.f};
#pragma unroll
  for (int c = 0; c < 8; ++c)
#pragma unroll
    for (int j = 0; j < 4; ++j) {
      p0[j] += fmaxf(acc[0][c][j] * s3v[c] + h3v[c], 0.f) * wv[c];
      p1[j] += fmaxf(acc[1][c][j] * s3v[c] + h3v[c], 0.f) * wv[c];
    }
#pragma unroll
  for (int j = 0; j < 4; ++j)
#pragma unroll
    for (int d = 1; d < 16; d <<= 1) {
      p0[j] += __shfl_xor(p0[j], d, 64);
      p1[j] += __shfl_xor(p1[j], d, 64);
    }
  if (m == 0) {
    int r0 = rbase + w * 32 + kq * 4;
    *(float4*)(scaleE + r0) = make_float4(p0[0], p0[1], p0[2], p0[3]);
    *(float4*)(scaleE + r0 + 16) = make_float4(p1[0], p1[1], p1[2], p1[3]);
  }
}

// coord_out: contiguous CSR ranges, coalesced
__global__ __launch_bounds__(256) void k_coord(const float* __restrict__ coord,
                                               const unsigned short* __restrict__ colS,
                                               const int* __restrict__ start,
                                               const int* __restrict__ cnt,
                                               const float* __restrict__ scaleE,
                                               float* __restrict__ cout) {
  int tid = threadIdx.x;
  int lane = tid & 63;
  int n = blockIdx.x * 4 + (tid >> 6);
  if (n >= Nn) return;
  int deg = cnt[n], off = start[n];
  float cx0 = coord[n * 3 + 0], cy0 = coord[n * 3 + 1], cz0 = coord[n * 3 + 2];
  float ax = 0.f, ay = 0.f, az = 0.f;
  for (int j = lane; j < deg; j += 64) {
    int e = off + j;
    int c = colS[e];
    float s = scaleE[e];
    float tx = (cx0 - coord[c * 3 + 0]) * s;
    float ty = (cy0 - coord[c * 3 + 1]) * s;
    float tz = (cz0 - coord[c * 3 + 2]) * s;
    ax += fminf(fmaxf(tx, -100.f), 100.f);
    ay += fminf(fmaxf(ty, -100.f), 100.f);
    az += fminf(fmaxf(tz, -100.f), 100.f);
  }
#pragma unroll
  for (int d = 32; d; d >>= 1) {
    ax += __shfl_xor(ax, d, 64);
    ay += __shfl_xor(ay, d, 64);
    az += __shfl_xor(az, d, 64);
  }
  if (lane == 0) {
    float inv = 1.f / fmaxf((float)deg, 1.f);
    cout[n * 3 + 0] = cx0 + ax * inv;
    cout[n * 3 + 1] = cy0 + ay * inv;
    cout[n * 3 + 2] = cz0 + az * inv;
  }
}

// ---------------- launcher ----------------

extern "C" void kernel_launch(void* const* d_in, const int* in_sizes, int n_in, void* d_out,
                              int out_size, void* d_ws, size_t ws_size, hipStream_t stream) {
  (void)in_sizes; (void)n_in; (void)out_size; (void)ws_size;
  const float* h = (const float*)d_in[0];
  const float* coord = (const float*)d_in[1];
  const int* eidx = (const int*)d_in[2];
  const int* row = eidx;
  const int* col = eidx + En;
  const float* e_w1 = (const float*)d_in[3];
  const float* e_b1 = (const float*)d_in[4];
  const float* e_g1 = (const float*)d_in[5];
  const float* e_be1 = (const float*)d_in[6];
  const float* e_w2 = (const float*)d_in[7];
  const float* e_b2 = (const float*)d_in[8];
  const float* e_g2 = (const float*)d_in[9];
  const float* e_be2 = (const float*)d_in[10];
  const float* n_w1 = (const float*)d_in[11];
  const float* n_b1 = (const float*)d_in[12];
  const float* n_g1 = (const float*)d_in[13];
  const float* n_be1 = (const float*)d_in[14];
  const float* n_w2 = (const float*)d_in[15];
  const float* n_b2 = (const float*)d_in[16];
  const float* c_w1 = (const float*)d_in[17];
  const float* c_b1 = (const float*)d_in[18];
  (void)c_b1;  // bias before BN cancels analytically (k_fin3)
  const float* c_g1 = (const float*)d_in[19];
  const float* c_be1 = (const float*)d_in[20];
  const float* c_w2 = (const float*)d_in[21];

  char* base = (char*)d_ws;
  size_t off = 0;
  auto alloc = [&](size_t bytes) -> void* {
    void* p = base + off;
    off = (off + bytes + 255) & ~(size_t)255;
    return p;
  };
  // Workspace budget: ~260 MB (proven footprint, unchanged — moment buffers aliased).
  unsigned short* t = (unsigned short*)alloc((size_t)En * 128 * 2);      // t2, then t4
  unsigned short* nodeA = (unsigned short*)alloc((size_t)Nn * 256 * 2);  // [h | agg] bf16
  unsigned short* hWr = (unsigned short*)alloc((size_t)Nn * 128 * 2);
  unsigned short* hWc = (unsigned short*)alloc((size_t)Nn * 128 * 2);
  float* scaleE = (float*)alloc((size_t)En * 4);
  float* radS = scaleE;  // alias: radS dead (after k_egemm2) before scaleE written (k_cgemm)
  unsigned short* rowS = (unsigned short*)alloc((size_t)En * 2);
  unsigned short* colS = (unsigned short*)alloc((size_t)En * 2);
  int* cnt = (int*)alloc((size_t)Nn * 4);
  int* startp = (int*)alloc((size_t)Nn * 4);
  int* cursor = (int*)alloc((size_t)Nn * 4);
  float* statS = (float*)alloc(4 * NSLOT * 128 * 4);
  float* statQ = (float*)alloc(4 * NSLOT * 128 * 4);
  float* bnS = (float*)alloc(4 * 128 * 4);
  float* bnSh = (float*)alloc(4 * 128 * 4);
  unsigned short* w1a = (unsigned short*)alloc(128 * 128 * 2);
  unsigned short* w1b = (unsigned short*)alloc(128 * 128 * 2);
  unsigned short* w2b = (unsigned short*)alloc(128 * 128 * 2);
  unsigned short* c1b = (unsigned short*)alloc(128 * 128 * 2);
  unsigned short* n1b = (unsigned short*)alloc(128 * 256 * 2);
  unsigned short* n2b = (unsigned short*)alloc(128 * 128 * 2);
  float* wlast = (float*)alloc(128 * 4);
  // Moment buffers ALIASED into dead regions (no new workspace):
  //  - Mpart (MGRID=256 × 64KB = 16.8 MB) over hWr+hWc (25.6 MB contiguous, dead after k_egemm2)
  //  - Mg (16384 f32) + SyG (128 f32) at head of scaleE region (radS dead after k_egemm2;
  //    scaleE written only later by k_cgemm, after k_fin3 consumed Mg/SyG)
  float* Mpart = (float*)hWr;
  float* Mg = scaleE;
  float* SyG = scaleE + 16384;

  hipMemsetAsync(cnt, 0, (size_t)Nn * 4, stream);
  hipMemsetAsync(statS, 0, 4 * NSLOT * 128 * 4, stream);
  hipMemsetAsync(statQ, 0, 4 * NSLOT * 128 * 4, stream);

  // prep
  k_prep_h<<<(Nn * 128 + 255) / 256, 256, 0, stream>>>(h, nodeA);
  k_prep_w<<<(128 * 128 + 255) / 256, 256, 0, stream>>>(e_w1, w1a, 257, 0, 7, 128 * 128);
  k_prep_w<<<(128 * 128 + 255) / 256, 256, 0, stream>>>(e_w1, w1b, 257, 128, 7, 128 * 128);
  k_prep_w<<<(128 * 128 + 255) / 256, 256, 0, stream>>>(e_w2, w2b, 128, 0, 7, 128 * 128);
  k_prep_w<<<(128 * 128 + 255) / 256, 256, 0, stream>>>(c_w1, c1b, 128, 0, 7, 128 * 128);
  k_prep_w<<<(128 * 256 + 255) / 256, 256, 0, stream>>>(n_w1, n1b, 256, 0, 8, 128 * 256);
  k_prep_w<<<(128 * 128 + 255) / 256, 256, 0, stream>>>(n_w2, n2b, 128, 0, 7, 128 * 128);
  k_wlast<<<1, 128, 0, stream>>>(e_w1, wlast);

  // CSR sort
  k_count<<<En / 256, 256, 0, stream>>>(row, cnt);
  k_scan<<<1, 1024, 0, stream>>>(cnt, startp, cursor, Nn);
  k_fill<<<En / 256, 256, 0, stream>>>(row, col, cursor, rowS, colS);

  // hW partial GEMMs (bias e_b1 folded into hWr)
  const int gridN = (Nn + 127) / 128;
  k_gemmW<4, false, false, false, true><<<gridN, 256, 0, stream>>>(
      nodeA, 256, w1a, e_b1, nullptr, nullptr, hWr, nullptr, nullptr, nullptr, nullptr, Nn);
  k_gemmW<4, false, false, false, true><<<gridN, 256, 0, stream>>>(
      nodeA, 256, w1b, nullptr, nullptr, nullptr, hWc, nullptr, nullptr, nullptr, nullptr, Nn);

  // bn1 stats over virtual t1 + radS (per_wave even for the 2-edge unroll)
  const int per_wave = ((En / 2 + 5119) / 5120) * 2;  // 1280 blocks * 4 waves
  k_stats1<<<1280, 256, 0, stream>>>(hWr, hWc, coord, rowS, colS, wlast, radS,
                                     statS + 0 * NSLOT * 128, statQ + 0 * NSLOT * 128, per_wave);
  k_fin<<<1, 128, 0, stream>>>(statS + 0 * NSLOT * 128, statQ + 0 * NSLOT * 128, e_g1, e_be1,
                               1.f / En, bnS + 0, bnSh + 0);

  // edge layer 2: t2 + bn2 stats (slot 1) — last use of hWr/hWc/radS
  k_egemm2<<<En / 128, 256, 0, stream>>>(hWr, hWc, radS, rowS, colS, w2b, e_b2, wlast, bnS + 0,
                                         bnSh + 0, t, statS + 1 * NSLOT * 128,
                                         statQ + 1 * NSLOT * 128);
  k_fin<<<1, 128, 0, stream>>>(statS + 1 * NSLOT * 128, statQ + 1 * NSLOT * 128, e_g2, e_be2,
                               1.f / En, bnS + 128, bnSh + 128);

  // node aggregation from contiguous t2 rows (no atomics)
  k_agg<<<(Nn + 3) / 4, 256, 0, stream>>>(t, startp, cnt, bnS + 128, bnSh + 128, nodeA);

  // bn3 stats WITHOUT materializing t3: second moment of y = relu(bn2(t2))
  hipMemsetAsync(SyG, 0, 128 * 4, stream);  // after radS is dead, before k_moment
  k_moment<<<MGRID, 512, 0, stream>>>(t, bnS + 128, bnSh + 128, Mpart, SyG);
  k_msum<<<256, 256, 0, stream>>>(Mpart, Mg);
  k_fin3<<<128, 128, 0, stream>>>(Mg, SyG, c_w1, c_g1, c_be1, 1.f / En, bnS + 256, bnSh + 256);

  // coord GEMM with fused bn3+relu+c_w2 epilogue -> per-edge scale (no t3 store, no scale pass)
  k_cgemm<<<En / 128, 256, 0, stream>>>(t, c1b, bnS + 128, bnSh + 128, bnS + 256, bnSh + 256,
                                        c_w2, scaleE);

  float* hout = (float*)d_out;
  float* cout = hout + (size_t)Nn * 128;
  k_coord<<<(Nn + 3) / 4, 256, 0, stream>>>(coord, colS, startp, cnt, scaleE, cout);

  // node MLP: l1 (stats slot 3) -> t4 in t (t2 dead after k_cgemm); l2 fp32 out
  k_gemmW<8, false, true, false, true><<<gridN, 256, 0, stream>>>(
      nodeA, 256, n1b, n_b1, nullptr, nullptr, t, statS + 3 * NSLOT * 128,
      statQ + 3 * NSLOT * 128, nullptr, nullptr, Nn);
  k_fin<<<1, 128, 0, stream>>>(statS + 3 * NSLOT * 128, statQ + 3 * NSLOT * 128, n_g1, n_be1,
                               1.f / Nn, bnS + 384, bnSh + 384);
  k_gemmW<4, true, false, true, true><<<gridN, 256, 0, stream>>>(
      t, 128, n2b, n_b2, bnS + 384, bnSh + 384, nullptr, nullptr, nullptr, h, hout, Nn);
}